// Round 9
// baseline (927.619 us; speedup 1.0000x reference)
//
#include <hip/hip_runtime.h>
#include <hip/hip_bf16.h>
#include <math.h>

#define HIDDEN   2560
#define NUM_HEADS 80
#define HEAD_DIM 64
#define STATE    128
#define CONV_K   4
#define CHUNK    256
#define INTER    (2*HIDDEN)                 // 5120
#define CONV_DIM (INTER + 2*STATE)          // 5376
#define PROJ     (INTER + CONV_DIM + NUM_HEADS) // 10576
#define PROJ_PAD 10752                      // 42*256
#define NBC      336                        // B,C (256) + dt (80) columns
#define EPS      1e-5f

#define BATCH 2
#define SEQ   2048
#define TOK   (BATCH*SEQ)                   // 4096
#define NC    (SEQ/CHUNK)                   // 8
#define KSPLIT 16
#define KCH   (HIDDEN/KSPLIT)               // 160

typedef __attribute__((ext_vector_type(8))) short bf16x8;
typedef __attribute__((ext_vector_type(4))) float f32x4;

#define MFMA16(a,b,c) __builtin_amdgcn_mfma_f32_16x16x32_bf16((a),(b),(c),0,0,0)

__device__ __forceinline__ unsigned short f2bf(float f){
    union{float f;unsigned u;}v; v.f=f;
    unsigned r = v.u + 0x7fffu + ((v.u>>16)&1u);
    return (unsigned short)(r>>16);
}
__device__ __forceinline__ float bf2f(unsigned short s){
    union{unsigned u;float f;}v; v.u = ((unsigned)s)<<16; return v.f;
}
__device__ __forceinline__ void unpack8(uint4 u, float* e){
    e[0]=bf2f((unsigned short)(u.x&0xffff)); e[1]=bf2f((unsigned short)(u.x>>16));
    e[2]=bf2f((unsigned short)(u.y&0xffff)); e[3]=bf2f((unsigned short)(u.y>>16));
    e[4]=bf2f((unsigned short)(u.z&0xffff)); e[5]=bf2f((unsigned short)(u.z>>16));
    e[6]=bf2f((unsigned short)(u.w&0xffff)); e[7]=bf2f((unsigned short)(u.w>>16));
}

__device__ __forceinline__ void gld16(const void* g, void* l){
    __builtin_amdgcn_global_load_lds((const __attribute__((address_space(1))) void*)g,
                                     (__attribute__((address_space(3))) void*)l, 16, 0, 0);
}

// =============== 256x256 deep-pipelined bf16 MFMA GEMM (NT), bf16 out ==============
// BK=32, 4 LDS slots (128 KiB), prefetch depth 3, counted vmcnt (never 0 in loop),
// raw s_barrier, setprio around MFMA cluster. 512 threads = 8 waves (2M x 4N).
// M multiple of 256 with (M/256)%8==0 assumed for XCD swizzle; N multiple of 256;
// K multiple of 32 with K/32 >= 4.
__global__ __launch_bounds__(512, 2) void gemm_bf16_256(const unsigned short* __restrict__ A, int lda,
                                                        const unsigned short* __restrict__ B, int ldb,
                                                        unsigned short* __restrict__ C, int ldc, int K) {
    __shared__ unsigned short LA[4][256][32];
    __shared__ unsigned short LB[4][256][32];
    int tid = threadIdx.x, lane = tid & 63, wid = tid >> 6;
    int wm = wid >> 2, wn = wid & 3;

    // XCD swizzle: xcd owns (gridDim.y/8) consecutive m-supertiles, m fastest
    int bid   = blockIdx.y * gridDim.x + blockIdx.x;
    int xcd   = bid & 7;
    int local = bid >> 3;
    int mrows = gridDim.y >> 3;
    int bm = (xcd * mrows + (local % mrows)) * 256;
    int bn = (local / mrows) * 256;

    f32x4 acc[8][4];
    #pragma unroll
    for (int i=0;i<8;i++)
        #pragma unroll
        for (int j=0;j<4;j++) acc[i][j] = (f32x4){0.f,0.f,0.f,0.f};

    // staging: chunk = 16 rows x 32 bf16 (64B rows); 16 chunks per matrix;
    // wave handles chunks wid*2+q. lane -> row brow+(lane>>2), phys slot lane&3,
    // global source slot (lane&3) ^ ((row>>1)&3)  [involution with read swizzle]
    int srow  = lane >> 2;
    int sslot = lane & 3;
    int NT = K >> 5;

    #define STAGE256(t_, s_) { int k0 = (t_)*32;                                         \
        _Pragma("unroll")                                                                \
        for (int q=0;q<2;q++){                                                           \
            int brow = (wid*2+q)*16;                                                     \
            int row  = brow + srow;                                                      \
            int sl   = sslot ^ ((row>>1)&3);                                             \
            gld16(A + (size_t)(bm + row)*lda + k0 + sl*8, &LA[s_][brow][0]);             \
            gld16(B + (size_t)(bn + row)*ldb + k0 + sl*8, &LB[s_][brow][0]);             \
        } }

    // prologue: 3 tiles in flight, wait only the first
    STAGE256(0, 0);
    STAGE256(1, 1);
    STAGE256(2, 2);
    asm volatile("s_waitcnt vmcnt(8)" ::: "memory");
    __builtin_amdgcn_s_barrier();

    for (int t = 0; t < NT; ++t) {
        int slot = t & 3;
        if (t + 3 < NT) STAGE256(t+3, (t+3)&3);
        bf16x8 bfr[4];
        #pragma unroll
        for (int j=0;j<4;j++){
            int row = wn*64 + j*16 + (lane&15);
            int sl  = (lane>>4) ^ ((row>>1)&3);
            bfr[j] = *(const bf16x8*)&LB[slot][row][sl*8];
        }
        __builtin_amdgcn_s_setprio(1);
        #pragma unroll
        for (int i=0;i<8;i++){
            int row = wm*128 + i*16 + (lane&15);
            int sl  = (lane>>4) ^ ((row>>1)&3);
            bf16x8 afr = *(const bf16x8*)&LA[slot][row][sl*8];
            #pragma unroll
            for (int j=0;j<4;j++)
                acc[i][j] = MFMA16(afr, bfr[j], acc[i][j]);
        }
        __builtin_amdgcn_s_setprio(0);
        // counted drain: keep 8 loads in flight in steady state; tail 8->4->0
        if (t < NT-3)       asm volatile("s_waitcnt vmcnt(8)" ::: "memory");
        else if (t == NT-3) asm volatile("s_waitcnt vmcnt(4)" ::: "memory");
        else                asm volatile("s_waitcnt vmcnt(0)" ::: "memory");
        __builtin_amdgcn_s_barrier();
    }
    #undef STAGE256

    // C/D layout: col = lane&15, row = (lane>>4)*4 + reg
    #pragma unroll
    for (int i=0;i<8;i++){
        int row0 = bm + wm*128 + i*16 + (lane>>4)*4;
        #pragma unroll
        for (int j=0;j<4;j++){
            int col = bn + wn*64 + j*16 + (lane&15);
            #pragma unroll
            for (int r=0;r<4;r++)
                C[(size_t)(row0+r)*ldc + col] = f2bf(acc[i][j][r]);
        }
    }
}

// =============== 128x128 bf16 MFMA GEMM (NT) — kept for GEMM2 ======================
template<bool BF16OUT>
__global__ __launch_bounds__(256) void gemm_bf16(const unsigned short* __restrict__ A, int lda,
                                                 const unsigned short* __restrict__ B, int ldb,
                                                 void* __restrict__ Cv, int ldc, int K) {
    __shared__ unsigned short As[128][64];
    __shared__ unsigned short Bs[128][64];
    int tid = threadIdx.x;
    int lane = tid & 63, wid = tid >> 6;
    int wr = wid >> 1, wc = wid & 1;

    int bm, bn;
    if ((gridDim.y & 7) == 0) {
        int bid   = blockIdx.y * gridDim.x + blockIdx.x;
        int xcd   = bid & 7;
        int local = bid >> 3;
        int mrows = gridDim.y >> 3;
        bm = (xcd * mrows + (local % mrows)) * 128;
        bn = (local / mrows) * 128;
    } else {
        bm = blockIdx.y * 128;
        bn = blockIdx.x * 128;
    }

    f32x4 acc[4][4];
    #pragma unroll
    for (int i=0;i<4;i++)
        #pragma unroll
        for (int j=0;j<4;j++) acc[i][j] = (f32x4){0.f,0.f,0.f,0.f};

    int srow_off = lane >> 3;
    int sslot    = lane & 7;

    for (int k0 = 0; k0 < K; k0 += 64) {
        #pragma unroll
        for (int q=0;q<4;q++){
            int brow = (wid*4+q)*8;
            int row  = brow + srow_off;
            int sl   = sslot ^ (row & 7);
            gld16(A + (size_t)(bm + row)*lda + k0 + sl*8, &As[brow][0]);
            gld16(B + (size_t)(bn + row)*ldb + k0 + sl*8, &Bs[brow][0]);
        }
        __syncthreads();
        #pragma unroll
        for (int kk=0; kk<64; kk+=32){
            bf16x8 a[4], b[4];
            #pragma unroll
            for (int i=0;i<4;i++){
                int row = wr*64 + i*16 + (lane&15);
                int slot = ((kk>>3) + (lane>>4)) ^ (row & 7);
                a[i] = *(const bf16x8*)&As[row][slot*8];
            }
            #pragma unroll
            for (int j=0;j<4;j++){
                int row = wc*64 + j*16 + (lane&15);
                int slot = ((kk>>3) + (lane>>4)) ^ (row & 7);
                b[j] = *(const bf16x8*)&Bs[row][slot*8];
            }
            #pragma unroll
            for (int i=0;i<4;i++)
                #pragma unroll
                for (int j=0;j<4;j++)
                    acc[i][j] = MFMA16(a[i], b[j], acc[i][j]);
        }
        __syncthreads();
    }
    #pragma unroll
    for (int i=0;i<4;i++){
        int row0 = bm + wr*64 + i*16 + (lane>>4)*4;
        #pragma unroll
        for (int j=0;j<4;j++){
            int col = bn + wc*64 + j*16 + (lane&15);
            #pragma unroll
            for (int r=0;r<4;r++){
                if (BF16OUT)
                    ((unsigned short*)Cv)[(size_t)(row0+r)*ldc + col] = f2bf(acc[i][j][r]);
                else
                    ((float*)Cv)[(size_t)(row0+r)*ldc + col] = acc[i][j][r];
            }
        }
    }
}

// ---------------- fp32→bf16 conversion kernels --------------------------------------
__global__ __launch_bounds__(256) void cvt_bf16(const float* __restrict__ in,
                                                unsigned short* __restrict__ out, size_t n4){
    size_t i4 = (size_t)blockIdx.x*256 + threadIdx.x;
    if (i4 >= n4) return;
    size_t i = i4*4;
    float4 v = *(const float4*)(in+i);
    ushort4 o; o.x=f2bf(v.x); o.y=f2bf(v.y); o.z=f2bf(v.z); o.w=f2bf(v.w);
    *(ushort4*)(out+i) = o;
}
__global__ __launch_bounds__(256) void cvt_w1(const float* __restrict__ in,
                                              unsigned short* __restrict__ out){
    size_t i4 = (size_t)blockIdx.x*256 + threadIdx.x;
    if (i4 >= (size_t)PROJ_PAD*HIDDEN/4) return;
    size_t i = i4*4;
    int row = (int)(i / HIDDEN);
    ushort4 o;
    if (row < PROJ){
        float4 v = *(const float4*)(in+i);
        o.x=f2bf(v.x); o.y=f2bf(v.y); o.z=f2bf(v.z); o.w=f2bf(v.w);
    } else { o.x=o.y=o.z=o.w=0; }
    *(ushort4*)(out+i) = o;
}

// ---------------- split-K fp32 GEMM for the 336 B/C/dt columns ----------------------
#define BM 128
#define BN 128
#define BKK 16
__global__ __launch_bounds__(256) void gemm_bc_splitk(const float* __restrict__ A, int lda,
                                                      const float* __restrict__ B, int ldb,
                                                      float* __restrict__ Cpart) {
    __shared__ float As[BKK][BM];
    __shared__ float Bs[BKK][BN];
    int tid = threadIdx.x;
    int bm = blockIdx.y * BM, bn = blockIdx.x * BN;
    int z  = blockIdx.z;
    int ty = tid >> 4, tx = tid & 15;
    float acc[8][8];
    #pragma unroll
    for (int i=0;i<8;i++)
        #pragma unroll
        for (int j=0;j<8;j++) acc[i][j]=0.f;
    int lr = tid >> 1, lk = (tid & 1) * 8;
    for (int k0 = z*KCH; k0 < (z+1)*KCH; k0 += BKK) {
        #pragma unroll
        for (int u=0;u<8;u++)
            As[lk+u][lr] = A[(size_t)(bm+lr)*lda + k0 + lk + u];
        int ncol = bn + lr;
        if (ncol < NBC) {
            #pragma unroll
            for (int u=0;u<8;u++)
                Bs[lk+u][lr] = B[(size_t)ncol*ldb + k0 + lk + u];
        } else {
            #pragma unroll
            for (int u=0;u<8;u++) Bs[lk+u][lr] = 0.f;
        }
        __syncthreads();
        #pragma unroll
        for (int k=0;k<BKK;k++){
            float a[8], bb[8];
            #pragma unroll
            for (int i=0;i<8;i++) a[i] = As[k][ty*8+i];
            #pragma unroll
            for (int j=0;j<8;j++) bb[j] = Bs[k][tx*8+j];
            #pragma unroll
            for (int i=0;i<8;i++)
                #pragma unroll
                for (int j=0;j<8;j++) acc[i][j] += a[i]*bb[j];
        }
        __syncthreads();
    }
    float* Cz = Cpart + (size_t)z*TOK*NBC;
    #pragma unroll
    for (int i=0;i<8;i++){
        int m = bm + ty*8 + i;
        #pragma unroll
        for (int j=0;j<8;j++){
            int n = bn + tx*8 + j;
            if (n < NBC) Cz[(size_t)m*NBC + n] = acc[i][j];
        }
    }
}

// fixed-order reduce + fused dt softplus
__global__ __launch_bounds__(256) void reduce_bc(const float* __restrict__ part,
                                                 const float* __restrict__ dt_bias,
                                                 float* __restrict__ outBC,
                                                 float* __restrict__ dtbuf) {
    size_t i4 = (size_t)blockIdx.x*256 + threadIdx.x;
    if (i4 >= (size_t)TOK*NBC/4) return;
    size_t i = i4*4;
    float4 s = *(const float4*)(part + i);
    #pragma unroll
    for (int z=1; z<KSPLIT; z++){
        float4 v = *(const float4*)(part + (size_t)z*TOK*NBC + i);
        s.x += v.x; s.y += v.y; s.z += v.z; s.w += v.w;
    }
    int col = (int)(i % NBC);
    int t   = (int)(i / NBC);
    if (col < 256) {
        *(float4*)(outBC + i) = s;
    } else {
        int h = col - 256;
        float e[4] = {s.x, s.y, s.z, s.w};
        #pragma unroll
        for (int u=0;u<4;u++){
            float xv = e[u] + dt_bias[h+u];
            float sp = (xv > 20.f) ? xv : log1pf(expf(xv));
            e[u] = fminf(fmaxf(sp, 0.f), 100.f);
        }
        float4 o; o.x=e[0]; o.y=e[1]; o.z=e[2]; o.w=e[3];
        *(float4*)(dtbuf + (size_t)t*NUM_HEADS + h) = o;
    }
}

// ---------------- conv+SiLU X, transposed output XT[b][d][s] (bf16) -----------------
__global__ __launch_bounds__(256) void conv_xt_kernel(const unsigned short* __restrict__ projb,
                                                      const float* __restrict__ cw,
                                                      const float* __restrict__ cb,
                                                      unsigned short* __restrict__ XT) {
    int t0 = blockIdx.x * 64;
    int d0 = blockIdx.y * 64;
    int b  = t0 / SEQ;
    int s0 = t0 % SEQ;
    __shared__ unsigned short raw[68][66];
    int tid = threadIdx.x;
    for (int f = tid; f < 67*8; f += 256){
        int r = f >> 3, g = f & 7;
        int sp = s0 - 3 + r;
        uint4 v;
        if (sp >= 0) v = *(const uint4*)(projb + ((size_t)(b*SEQ+sp))*PROJ_PAD + INTER + d0 + g*8);
        else { v.x=0u; v.y=0u; v.z=0u; v.w=0u; }
        unsigned int* dst = (unsigned int*)&raw[r][g*8];
        dst[0]=v.x; dst[1]=v.y; dst[2]=v.z; dst[3]=v.w;
    }
    __syncthreads();
    int t = tid & 63, dg = tid >> 6;
    #pragma unroll
    for (int dd = 0; dd < 16; dd++){
        int d = dg*16 + dd;
        float acc = cb[d0+d];
        #pragma unroll
        for (int j=0;j<CONV_K;j++)
            acc += cw[(d0+d)*CONV_K+j] * bf2f(raw[t+j][d]);
        float val = acc/(1.f+expf(-acc));
        XT[((size_t)(b*INTER + d0 + d))*SEQ + s0 + t] = f2bf(val);
    }
}

// ---------------- conv+SiLU B/C (fp32 out) + bf16 BT[b][n][s] -----------------------
__global__ __launch_bounds__(256) void conv_bc_kernel(const float* __restrict__ projBC,
                                                      const float* __restrict__ cw,
                                                      const float* __restrict__ cb,
                                                      float* __restrict__ xBC_BC,
                                                      unsigned short* __restrict__ BT) {
    int idx = blockIdx.x*256 + threadIdx.x;
    if (idx >= TOK*256) return;
    int d = idx & 255;
    int t = idx >> 8;
    int b = t / SEQ, sl = t % SEQ;
    int dc = INTER + d;
    float acc = cb[dc];
    #pragma unroll
    for (int j=0;j<CONV_K;j++){
        int sp = sl - (CONV_K-1) + j;
        if (sp >= 0)
            acc += cw[dc*CONV_K+j] * projBC[((size_t)(b*SEQ+sp))*NBC + d];
    }
    float val = acc / (1.f + expf(-acc));
    xBC_BC[(size_t)t*256 + d] = val;
    if (d < 128)
        BT[((size_t)(b*128 + d))*SEQ + sl] = f2bf(val);
}

// ---------------- per-chunk inclusive cumsum of dA = A*dt ---------------------------
__global__ __launch_bounds__(256) void cumsum_kernel(const float* __restrict__ dtbuf,
                                                     const float* __restrict__ A_log,
                                                     float* __restrict__ A_cum) {
    int c = blockIdx.x, h = blockIdx.y, b = blockIdx.z;
    int l = threadIdx.x;
    float A = -expf(A_log[h]);
    float v = A * dtbuf[(size_t)(b*SEQ + c*CHUNK + l)*NUM_HEADS + h];
    __shared__ float buf[CHUNK];
    buf[l] = v;
    __syncthreads();
    for (int off=1; off<CHUNK; off<<=1){
        float t = (l>=off) ? buf[l-off] : 0.f;
        __syncthreads();
        buf[l] += t;
        __syncthreads();
    }
    A_cum[((size_t)b*NUM_HEADS + h)*SEQ + c*CHUNK + l] = buf[l];
}

// ---------------- G[l][s] = C[l] . B[s]  (head-shared), bf16, l-major ---------------
__global__ __launch_bounds__(256) void g_kernel(const float* __restrict__ xBC_BC,
                                                unsigned short* __restrict__ G) {
    int p = blockIdx.x, c = blockIdx.y, b = blockIdx.z;
    int lt = 0, a0 = 0;
    while (a0 + lt + 1 <= p) { a0 += lt + 1; lt++; }
    int st = p - a0;
    int l0 = lt*64, s0 = st*64;
    __shared__ float Cs[64][68];
    __shared__ float Bs[64][68];
    int tid = threadIdx.x, ty = tid >> 4, tx = tid & 15;
    float acc[4][4];
    #pragma unroll
    for (int i=0;i<4;i++)
        #pragma unroll
        for (int j=0;j<4;j++) acc[i][j]=0.f;

    size_t rowC = ((size_t)(b*SEQ + c*CHUNK + l0))*256 + 128;
    size_t rowB = ((size_t)(b*SEQ + c*CHUNK + s0))*256;
    for (int kc=0; kc<2; kc++){
        #pragma unroll
        for (int it=0; it<4; it++){
            int f = tid + it*256;
            int r = f >> 4, c4 = f & 15;
            float4 cv = *(const float4*)(xBC_BC + rowC + (size_t)r*256 + kc*64 + c4*4);
            float4 bv = *(const float4*)(xBC_BC + rowB + (size_t)r*256 + kc*64 + c4*4);
            *(float4*)&Cs[r][c4*4] = cv;
            *(float4*)&Bs[r][c4*4] = bv;
        }
        __syncthreads();
        #pragma unroll 8
        for (int k=0;k<64;k++){
            float a[4], bb[4];
            #pragma unroll
            for (int i=0;i<4;i++) a[i] = Cs[ty*4+i][k];
            #pragma unroll
            for (int j=0;j<4;j++) bb[j] = Bs[tx*4+j][k];
            #pragma unroll
            for (int i=0;i<4;i++)
                #pragma unroll
                for (int j=0;j<4;j++) acc[i][j] += a[i]*bb[j];
        }
        __syncthreads();
    }
    size_t Gb = ((size_t)(b*NC + c)) << 16;
    #pragma unroll
    for (int i=0;i<4;i++){
        ushort4 g4;
        g4.x = f2bf(acc[i][0]); g4.y = f2bf(acc[i][1]);
        g4.z = f2bf(acc[i][2]); g4.w = f2bf(acc[i][3]);
        *(ushort4*)(G + Gb + (size_t)(l0 + ty*4 + i)*256 + s0 + tx*4) = g4;
    }
}

// ---------------- statesT[p][n] = sum_l XT[p][l] * (BT[n][l]*w[l])  (MFMA) ----------
__global__ __launch_bounds__(256) void states_mfma(const unsigned short* __restrict__ XT,
                                                   const unsigned short* __restrict__ BT,
                                                   const float* __restrict__ dtbuf,
                                                   const float* __restrict__ A_cum,
                                                   float* __restrict__ statesT) {
    int c = blockIdx.x, h = blockIdx.y, b = blockIdx.z;
    __shared__ unsigned short Asx[64][64];
    __shared__ unsigned short Bsw[128][64];
    __shared__ float wl[CHUNK];
    int tid = threadIdx.x, lane = tid & 63, wid = tid >> 6;
    {
        const float* ac = A_cum + ((size_t)(b*NUM_HEADS+h))*SEQ + c*CHUNK;
        float Alast = ac[CHUNK-1];
        wl[tid] = expf(Alast - ac[tid]) * dtbuf[((size_t)(b*SEQ + c*CHUNK + tid))*NUM_HEADS + h];
    }
    __syncthreads();
    f32x4 acc[4][2];
    #pragma unroll
    for (int i=0;i<4;i++)
        #pragma unroll
        for (int j=0;j<2;j++) acc[i][j] = (f32x4){0.f,0.f,0.f,0.f};

    for (int kc = 0; kc < 4; kc++){
        int lbase = kc*64;
        #pragma unroll
        for (int q=0;q<2;q++){
            int brow = (wid*2+q)*8;
            int row  = brow + (lane>>3);
            int sl   = (lane&7) ^ (row & 7);
            gld16(XT + ((size_t)(b*INTER + h*HEAD_DIM + row))*SEQ + c*CHUNK + lbase + sl*8,
                  &Asx[brow][0]);
        }
        #pragma unroll
        for (int it=0; it<4; it++){
            int f = tid + it*256;
            int r = f >> 3, g = f & 7;
            uint4 v = *(const uint4*)(BT + ((size_t)(b*128 + r))*SEQ + c*CHUNK + lbase + g*8);
            float e[8]; unpack8(v, e);
            unsigned short o[8];
            #pragma unroll
            for (int u=0;u<8;u++) o[u] = f2bf(e[u] * wl[lbase + g*8 + u]);
            int slot = g ^ (r & 7);
            *(ushort4*)&Bsw[r][slot*8]   = *(ushort4*)&o[0];
            *(ushort4*)&Bsw[r][slot*8+4] = *(ushort4*)&o[4];
        }
        __syncthreads();
        #pragma unroll
        for (int kk=0; kk<64; kk+=32){
            bf16x8 a[4], bb[2];
            #pragma unroll
            for (int i=0;i<4;i++){
                int row = i*16 + (lane&15);
                int slot = ((kk>>3)+(lane>>4)) ^ (row&7);
                a[i] = *(const bf16x8*)&Asx[row][slot*8];
            }
            #pragma unroll
            for (int j=0;j<2;j++){
                int row = wid*32 + j*16 + (lane&15);
                int slot = ((kk>>3)+(lane>>4)) ^ (row&7);
                bb[j] = *(const bf16x8*)&Bsw[row][slot*8];
            }
            #pragma unroll
            for (int i=0;i<4;i++)
                #pragma unroll
                for (int j=0;j<2;j++)
                    acc[i][j] = MFMA16(a[i], bb[j], acc[i][j]);
        }
        __syncthreads();
    }
    size_t sb = ((size_t)((b*NC + c)*NUM_HEADS + h))*(HEAD_DIM*STATE);
    #pragma unroll
    for (int i=0;i<4;i++){
        #pragma unroll
        for (int j=0;j<2;j++){
            int n = wid*32 + j*16 + (lane&15);
            int p0 = i*16 + (lane>>4)*4;
            #pragma unroll
            for (int r=0;r<4;r++)
                statesT[sb + (size_t)(p0+r)*128 + n] = acc[i][j][r];
        }
    }
}

// ---------------- inter-chunk recurrence (in place, layout-agnostic) ----------------
__global__ __launch_bounds__(256) void recur_kernel(const float* __restrict__ A_cum,
                                                    float* __restrict__ states) {
    int h = blockIdx.x, b = blockIdx.y;
    int tid = threadIdx.x;
    float Srun[32];
    #pragma unroll
    for (int i=0;i<32;i++) Srun[i]=0.f;
    const float* acum = A_cum + ((size_t)b*NUM_HEADS + h)*SEQ;
    for (int c=0;c<NC;c++){
        float alast = acum[c*CHUNK + CHUNK-1];
        float dec = expf(alast);
        size_t base = ((size_t)((b*NC + c)*NUM_HEADS + h))*(HEAD_DIM*STATE);
        #pragma unroll
        for (int i=0;i<32;i++){
            size_t idx = base + (size_t)tid + (size_t)i*256;
            float raw = states[idx];
            states[idx] = Srun[i];
            Srun[i] = Srun[i]*dec + raw;
        }
    }
}

// ---------------- Y = e_l*(Cs @ St^T) + Gw @ Xs^T + D*X   (MFMA) --------------------
__global__ __launch_bounds__(256) void yscan_mfma(const unsigned short* __restrict__ G,
                                                  const float* __restrict__ xBC_BC,
                                                  const unsigned short* __restrict__ XT,
                                                  const float* __restrict__ dtbuf,
                                                  const float* __restrict__ A_cum,
                                                  const float* __restrict__ statesT,
                                                  const float* __restrict__ Dvec,
                                                  unsigned short* __restrict__ projb) {
    int xb = blockIdx.x;
    int c = xb >> 2, lt = xb & 3;
    int h = blockIdx.y, b = blockIdx.z;
    int l0 = lt*64;
    __shared__ __align__(16) char pool[32768];
    unsigned short (*Cs)[128] = (unsigned short(*)[128])pool;
    unsigned short (*St)[128] = (unsigned short(*)[128])(pool + 16384);
    unsigned short (*Gw)[64]  = (unsigned short(*)[64])pool;
    unsigned short (*Xs)[64]  = (unsigned short(*)[64])(pool + 8192);
    float (*Ot)[68]           = (float(*)[68])pool;
    __shared__ float ac[CHUNK], dts[CHUNK];
    int tid = threadIdx.x, lane = tid & 63, wid = tid >> 6;
    ac[tid]  = A_cum[((size_t)(b*NUM_HEADS + h))*SEQ + c*CHUNK + tid];
    dts[tid] = dtbuf[((size_t)(b*SEQ + c*CHUNK + tid))*NUM_HEADS + h];
    __syncthreads();

    size_t stb = ((size_t)((b*NC + c)*NUM_HEADS + h))*(HEAD_DIM*STATE);
    #pragma unroll
    for (int it=0; it<8; it++){
        int f = tid + it*256;
        int r = f >> 5, c4 = f & 31;
        float4 v = *(const float4*)(xBC_BC + ((size_t)(b*SEQ + c*CHUNK + l0 + r))*256 + 128 + c4*4);
        unsigned short o[4] = {f2bf(v.x),f2bf(v.y),f2bf(v.z),f2bf(v.w)};
        int col = c4*4;
        int slot = (col>>3) ^ (r&7);
        *(ushort4*)&Cs[r][slot*8 + (col&7)] = *(ushort4*)o;
        float4 w = *(const float4*)(statesT + stb + (size_t)r*128 + c4*4);
        unsigned short o2[4] = {f2bf(w.x),f2bf(w.y),f2bf(w.z),f2bf(w.w)};
        *(ushort4*)&St[r][slot*8 + (col&7)] = *(ushort4*)o2;
    }
    __syncthreads();

    f32x4 acc1[4];
    #pragma unroll
    for (int j=0;j<4;j++) acc1[j] = (f32x4){0.f,0.f,0.f,0.f};
    #pragma unroll
    for (int kk=0; kk<128; kk+=32){
        int arow = wid*16 + (lane&15);
        int aslot = ((kk>>3)+(lane>>4)) ^ (arow&7);
        bf16x8 a = *(const bf16x8*)&Cs[arow][aslot*8];
        #pragma unroll
        for (int j=0;j<4;j++){
            int brow = j*16 + (lane&15);
            int bslot = ((kk>>3)+(lane>>4)) ^ (brow&7);
            bf16x8 bb = *(const bf16x8*)&St[brow][bslot*8];
            acc1[j] = MFMA16(a, bb, acc1[j]);
        }
    }
    float el[4];
    #pragma unroll
    for (int r=0;r<4;r++) el[r] = expf(ac[l0 + wid*16 + (lane>>4)*4 + r]);
    float master[4][4];
    #pragma unroll
    for (int j=0;j<4;j++)
        #pragma unroll
        for (int r=0;r<4;r++) master[j][r] = acc1[j][r]*el[r];
    __syncthreads();

    size_t Gb = ((size_t)(b*NC + c)) << 16;
    f32x4 acc2[4];
    #pragma unroll
    for (int j=0;j<4;j++) acc2[j] = (f32x4){0.f,0.f,0.f,0.f};
    for (int st=0; st<=lt; st++){
        int s0 = st*64;
        #pragma unroll
        for (int it=0; it<2; it++){
            int f = tid + it*256;
            int r = f >> 3, g = f & 7;
            uint4 v = *(const uint4*)(G + Gb + (size_t)(l0 + r)*256 + s0 + g*8);
            float e[8]; unpack8(v, e);
            float acl = ac[l0 + r];
            unsigned short o[8];
            #pragma unroll
            for (int u=0;u<8;u++){
                int s = s0 + g*8 + u;
                float w = (s <= l0 + r) ? expf(acl - ac[s])*dts[s] : 0.f;
                o[u] = f2bf(e[u]*w);
            }
            int slot = g ^ (r&7);
            *(ushort4*)&Gw[r][slot*8]   = *(ushort4*)&o[0];
            *(ushort4*)&Gw[r][slot*8+4] = *(ushort4*)&o[4];
        }
        #pragma unroll
        for (int q=0;q<2;q++){
            int brow = (wid*2+q)*8;
            int row  = brow + (lane>>3);
            int sl   = (lane&7) ^ (row&7);
            gld16(XT + ((size_t)(b*INTER + h*HEAD_DIM + row))*SEQ + c*CHUNK + s0 + sl*8,
                  &Xs[brow][0]);
        }
        __syncthreads();
        #pragma unroll
        for (int kk=0; kk<64; kk+=32){
            int arow = wid*16 + (lane&15);
            int aslot = ((kk>>3)+(lane>>4)) ^ (arow&7);
            bf16x8 a = *(const bf16x8*)&Gw[arow][aslot*8];
            #pragma unroll
            for (int j=0;j<4;j++){
                int brow = j*16 + (lane&15);
                int bslot = ((kk>>3)+(lane>>4)) ^ (brow&7);
                bf16x8 bb = *(const bf16x8*)&Xs[brow][bslot*8];
                acc2[j] = MFMA16(a, bb, acc2[j]);
            }
        }
        if (st < lt) __syncthreads();
    }

    float Dh = Dvec[h];
    #pragma unroll
    for (int j=0;j<4;j++){
        int p = j*16 + (lane&15);
        #pragma unroll
        for (int r=0;r<4;r++){
            int sl_ = wid*16 + (lane>>4)*4 + r;
            int slot = (sl_>>3) ^ (p&7);
            float xv = bf2f(Xs[p][slot*8 + (sl_&7)]);
            master[j][r] += acc2[j][r] + Dh*xv;
        }
    }
    __syncthreads();

    #pragma unroll
    for (int j=0;j<4;j++){
        int p = j*16 + (lane&15);
        #pragma unroll
        for (int r=0;r<4;r++)
            Ot[wid*16 + (lane>>4)*4 + r][p] = master[j][r];
    }
    __syncthreads();
    #pragma unroll
    for (int it=0; it<4; it++){
        int f = tid + it*256;
        int r = f >> 4, c4 = f & 15;
        ushort4 o;
        o.x = f2bf(Ot[r][c4*4+0]); o.y = f2bf(Ot[r][c4*4+1]);
        o.z = f2bf(Ot[r][c4*4+2]); o.w = f2bf(Ot[r][c4*4+3]);
        *(ushort4*)(projb + ((size_t)(b*SEQ + c*CHUNK + l0 + r))*PROJ_PAD + INTER + h*HEAD_DIM + c4*4) = o;
    }
}

// ---------------- gate * silu + RMSNorm -> packed bf16 y ----------------------------
__global__ __launch_bounds__(256) void gate_norm_kernel(const unsigned short* __restrict__ projb,
                                                        const float* __restrict__ normw,
                                                        unsigned short* __restrict__ yb) {
    int t = blockIdx.x;
    int tid = threadIdx.x;
    const unsigned short* row = projb + (size_t)t*PROJ_PAD;
    __shared__ float red[4];
    float vals[20];
    float ss = 0.f;
    #pragma unroll
    for (int i=0;i<5;i++){
        int j = (tid + i*256)*4;
        ushort4 g4 = *(const ushort4*)(row + j);
        ushort4 y4 = *(const ushort4*)(row + INTER + j);
        #pragma unroll
        for (int u=0;u<4;u++){
            float g = bf2f(((const unsigned short*)&g4)[u]);
            float y = bf2f(((const unsigned short*)&y4)[u]);
            float gv = g / (1.f + expf(-g));
            float v = y * gv;
            vals[i*4+u] = v;
            ss += v*v;
        }
    }
    #pragma unroll
    for (int off=32; off; off>>=1) ss += __shfl_xor(ss, off);
    if ((tid&63)==0) red[tid>>6] = ss;
    __syncthreads();
    float tot = red[0]+red[1]+red[2]+red[3];
    float inv = rsqrtf(tot/(float)INTER + EPS);
    #pragma unroll
    for (int i=0;i<5;i++){
        int j = (tid + i*256)*4;
        ushort4 o;
        o.x = f2bf(vals[i*4+0] * inv * normw[j+0]);
        o.y = f2bf(vals[i*4+1] * inv * normw[j+1]);
        o.z = f2bf(vals[i*4+2] * inv * normw[j+2]);
        o.w = f2bf(vals[i*4+3] * inv * normw[j+3]);
        *(ushort4*)(yb + (size_t)t*INTER + j) = o;
    }
}

// ------------------------------------------------------------------------------------
extern "C" void kernel_launch(void* const* d_in, const int* in_sizes, int n_in,
                              void* d_out, int out_size, void* d_ws, size_t ws_size,
                              hipStream_t stream) {
    const float* x        = (const float*)d_in[0];
    const float* in_w     = (const float*)d_in[1];
    const float* conv_w   = (const float*)d_in[2];
    const float* conv_b   = (const float*)d_in[3];
    const float* A_log    = (const float*)d_in[4];
    const float* Dvec     = (const float*)d_in[5];
    const float* dt_bias  = (const float*)d_in[6];
    const float* norm_w   = (const float*)d_in[7];
    const float* out_w    = (const float*)d_in[8];
    float* out = (float*)d_out;
    (void)ws_size; (void)n_in; (void)in_sizes; (void)out_size;

    // ---- workspace layout (bytes), total ~277 MB ----
    const size_t PROJB   = (size_t)TOK*PROJ_PAD*2;          // 88.1 MB
    const size_t PROJBCB = (size_t)TOK*NBC*4;               //  5.5 MB
    const size_t XTB     = (size_t)TOK*INTER*2;             // 41.9 MB (transposed X)
    const size_t XBCBCB  = (size_t)TOK*256*4;               //  4.2 MB
    const size_t BTB     = (size_t)BATCH*128*SEQ*2;         //  1.0 MB
    const size_t GBYTES  = (size_t)BATCH*NC*CHUNK*CHUNK*2;  //  2.1 MB
    const size_t DTB     = (size_t)TOK*NUM_HEADS*4;         //  1.3 MB
    const size_t ACUMB   = DTB;
    const size_t STB     = (size_t)BATCH*NC*NUM_HEADS*HEAD_DIM*STATE*4; // 41.9 MB
    const size_t XB      = (size_t)TOK*HIDDEN*2;
    const size_t YB      = (size_t)TOK*INTER*2;

    char* base = (char*)d_ws;
    size_t off = 0;
    unsigned short* projb  = (unsigned short*)(base + off); off += PROJB;
    float* projBC          = (float*)(base + off);          off += PROJBCB;
    unsigned short* XTp    = (unsigned short*)(base + off); off += XTB;
    float* xBC_BC          = (float*)(base + off);          off += XBCBCB;
    unsigned short* BTp    = (unsigned short*)(base + off); off += BTB;
    unsigned short* Gp     = (unsigned short*)(base + off); off += GBYTES;
    float* dtbuf           = (float*)(base + off);          off += DTB;
    float* A_cum           = (float*)(base + off);          off += ACUMB;
    float* statesT         = (float*)(base + off);          off += STB;
    char*  T               = base + off;
    unsigned short* xb  = (unsigned short*)T;
    unsigned short* w1b = (unsigned short*)(T + XB);
    float* bcpart       = (float*)T;                   // split-K partials (88 MB)
    unsigned short* yb  = (unsigned short*)T;
    unsigned short* w2b = (unsigned short*)(T + YB);

    const size_t XB_E = (size_t)TOK*HIDDEN;
    const size_t W1_E = (size_t)PROJ_PAD*HIDDEN;
    const size_t W2_E = (size_t)HIDDEN*INTER;

    // 0. conversions for GEMM1
    cvt_bf16<<<(unsigned)((XB_E/4+255)/256), 256, 0, stream>>>(x, xb, XB_E/4);
    cvt_w1<<<(unsigned)((W1_E/4+255)/256), 256, 0, stream>>>(in_w, w1b);

    // 1. proj = x @ in_w^T  (256x256 deep-pipelined bf16 MFMA, bf16 out)
    gemm_bf16_256<<<dim3(PROJ_PAD/256, TOK/256), 512, 0, stream>>>(xb, HIDDEN, w1b, HIDDEN,
                                                                   projb, PROJ_PAD, HIDDEN);
    // 1b. B/C/dt columns in fp32 via split-K
    gemm_bc_splitk<<<dim3((NBC+BN-1)/BN, TOK/BM, KSPLIT), 256, 0, stream>>>(
        x, HIDDEN, in_w + (size_t)(INTER+INTER)*HIDDEN, HIDDEN, bcpart);
    reduce_bc<<<(unsigned)(((size_t)TOK*NBC/4+255)/256), 256, 0, stream>>>(bcpart, dt_bias, projBC, dtbuf);

    // 2. conv + silu
    conv_xt_kernel<<<dim3(TOK/64, INTER/64), 256, 0, stream>>>(projb, conv_w, conv_b, XTp);
    conv_bc_kernel<<<(TOK*256+255)/256, 256, 0, stream>>>(projBC, conv_w, conv_b, xBC_BC, BTp);
    // 2b. w2 conversion (after reduce consumed partials)
    cvt_bf16<<<(unsigned)((W2_E/4+255)/256), 256, 0, stream>>>(out_w, w2b, W2_E/4);
    // 3. cumsum
    cumsum_kernel<<<dim3(NC, NUM_HEADS, BATCH), 256, 0, stream>>>(dtbuf, A_log, A_cum);
    // 4. G = C.B^T (head-shared), [l][s] layout
    g_kernel<<<dim3(10, NC, BATCH), 256, 0, stream>>>(xBC_BC, Gp);
    // 5. per-chunk states (MFMA) -> statesT[p][n]
    states_mfma<<<dim3(NC, NUM_HEADS, BATCH), 256, 0, stream>>>(XTp, BTp, dtbuf, A_cum, statesT);
    // 6. inter-chunk recurrence
    recur_kernel<<<dim3(NUM_HEADS, BATCH), 256, 0, stream>>>(A_cum, statesT);
    // 7. Y (MFMA) -> bf16 into projb
    yscan_mfma<<<dim3(NC*4, NUM_HEADS, BATCH), 256, 0, stream>>>(Gp, xBC_BC, XTp, dtbuf, A_cum,
                                                                 statesT, Dvec, projb);
    // 8. gate + RMSNorm -> bf16 y
    gate_norm_kernel<<<TOK, 256, 0, stream>>>(projb, norm_w, yb);
    // 9. out = y @ out_w^T  (128x128 bf16 MFMA, fp32 out, XCD swizzle)
    gemm_bf16<false><<<dim3(HIDDEN/128, TOK/128), 256, 0, stream>>>(yb, INTER, w2b, INTER,
                                                                    out, HIDDEN, INTER);
}

// Round 10
// 765.657 us; speedup vs baseline: 1.2115x; 1.2115x over previous
//
#include <hip/hip_runtime.h>
#include <hip/hip_bf16.h>
#include <math.h>

#define HIDDEN   2560
#define NUM_HEADS 80
#define HEAD_DIM 64
#define STATE    128
#define CONV_K   4
#define CHUNK    256
#define INTER    (2*HIDDEN)                 // 5120
#define CONV_DIM (INTER + 2*STATE)          // 5376
#define PROJ     (INTER + CONV_DIM + NUM_HEADS) // 10576
#define PROJ_PAD 10624                      // 83*128
#define NBC      336                        // B,C (256) + dt (80) columns
#define NBCP     384                        // padded to 3*128
#define EPS      1e-5f

#define BATCH 2
#define SEQ   2048
#define TOK   (BATCH*SEQ)                   // 4096
#define NC    (SEQ/CHUNK)                   // 8
#define KSPL2 8
#define KCH2  (HIDDEN/KSPL2)                // 320

typedef __attribute__((ext_vector_type(8))) short bf16x8;
typedef __attribute__((ext_vector_type(4))) float f32x4;

#define MFMA16(a,b,c) __builtin_amdgcn_mfma_f32_16x16x32_bf16((a),(b),(c),0,0,0)

__device__ __forceinline__ unsigned short f2bf(float f){
    union{float f;unsigned u;}v; v.f=f;
    unsigned r = v.u + 0x7fffu + ((v.u>>16)&1u);
    return (unsigned short)(r>>16);
}
__device__ __forceinline__ float bf2f(unsigned short s){
    union{unsigned u;float f;}v; v.u = ((unsigned)s)<<16; return v.f;
}
__device__ __forceinline__ void unpack8(uint4 u, float* e){
    e[0]=bf2f((unsigned short)(u.x&0xffff)); e[1]=bf2f((unsigned short)(u.x>>16));
    e[2]=bf2f((unsigned short)(u.y&0xffff)); e[3]=bf2f((unsigned short)(u.y>>16));
    e[4]=bf2f((unsigned short)(u.z&0xffff)); e[5]=bf2f((unsigned short)(u.z>>16));
    e[6]=bf2f((unsigned short)(u.w&0xffff)); e[7]=bf2f((unsigned short)(u.w>>16));
}

__device__ __forceinline__ void gld16(const void* g, void* l){
    __builtin_amdgcn_global_load_lds((const __attribute__((address_space(1))) void*)g,
                                     (__attribute__((address_space(3))) void*)l, 16, 0, 0);
}

// =============== 128x128 bf16 MFMA GEMM (NT) ==========================================
template<bool BF16OUT>
__global__ __launch_bounds__(256) void gemm_bf16(const unsigned short* __restrict__ A, int lda,
                                                 const unsigned short* __restrict__ B, int ldb,
                                                 void* __restrict__ Cv, int ldc, int K) {
    __shared__ unsigned short As[128][64];
    __shared__ unsigned short Bs[128][64];
    int tid = threadIdx.x;
    int lane = tid & 63, wid = tid >> 6;
    int wr = wid >> 1, wc = wid & 1;

    int bm, bn;
    if ((gridDim.y & 7) == 0) {
        int bid   = blockIdx.y * gridDim.x + blockIdx.x;
        int xcd   = bid & 7;
        int local = bid >> 3;
        int mrows = gridDim.y >> 3;
        bm = (xcd * mrows + (local % mrows)) * 128;
        bn = (local / mrows) * 128;
    } else {
        bm = blockIdx.y * 128;
        bn = blockIdx.x * 128;
    }

    f32x4 acc[4][4];
    #pragma unroll
    for (int i=0;i<4;i++)
        #pragma unroll
        for (int j=0;j<4;j++) acc[i][j] = (f32x4){0.f,0.f,0.f,0.f};

    int srow_off = lane >> 3;
    int sslot    = lane & 7;

    for (int k0 = 0; k0 < K; k0 += 64) {
        #pragma unroll
        for (int q=0;q<4;q++){
            int brow = (wid*4+q)*8;
            int row  = brow + srow_off;
            int sl   = sslot ^ (row & 7);
            gld16(A + (size_t)(bm + row)*lda + k0 + sl*8, &As[brow][0]);
            gld16(B + (size_t)(bn + row)*ldb + k0 + sl*8, &Bs[brow][0]);
        }
        __syncthreads();
        #pragma unroll
        for (int kk=0; kk<64; kk+=32){
            bf16x8 a[4], b[4];
            #pragma unroll
            for (int i=0;i<4;i++){
                int row = wr*64 + i*16 + (lane&15);
                int slot = ((kk>>3) + (lane>>4)) ^ (row & 7);
                a[i] = *(const bf16x8*)&As[row][slot*8];
            }
            #pragma unroll
            for (int j=0;j<4;j++){
                int row = wc*64 + j*16 + (lane&15);
                int slot = ((kk>>3) + (lane>>4)) ^ (row & 7);
                b[j] = *(const bf16x8*)&Bs[row][slot*8];
            }
            #pragma unroll
            for (int i=0;i<4;i++)
                #pragma unroll
                for (int j=0;j<4;j++)
                    acc[i][j] = MFMA16(a[i], b[j], acc[i][j]);
        }
        __syncthreads();
    }
    #pragma unroll
    for (int i=0;i<4;i++){
        int row0 = bm + wr*64 + i*16 + (lane>>4)*4;
        #pragma unroll
        for (int j=0;j<4;j++){
            int col = bn + wc*64 + j*16 + (lane&15);
            #pragma unroll
            for (int r=0;r<4;r++){
                if (BF16OUT)
                    ((unsigned short*)Cv)[(size_t)(row0+r)*ldc + col] = f2bf(acc[i][j][r]);
                else
                    ((float*)Cv)[(size_t)(row0+r)*ldc + col] = acc[i][j][r];
            }
        }
    }
}

// =============== bf16 hi/lo split-K MFMA for B/C/dt (fp32-quality) ====================
// out[m][n] = sum_k (xhi+xlo)[m][k]*(whi+wlo)[n][k], terms: xhi*wlo + xhi*whi + xlo*whi.
// grid (NBCP/128=3, TOK/128=32, KSPL2); fp32 partials [z][TOK][NBCP].
__global__ __launch_bounds__(256) void bc_splitk_mfma(const unsigned short* __restrict__ xhi,
                                                      const unsigned short* __restrict__ xlo,
                                                      const unsigned short* __restrict__ whi,
                                                      const unsigned short* __restrict__ wlo,
                                                      float* __restrict__ Cpart) {
    __shared__ unsigned short As[128][64];
    __shared__ unsigned short Bs[128][64];
    int tid = threadIdx.x;
    int lane = tid & 63, wid = tid >> 6;
    int wr = wid >> 1, wc = wid & 1;
    int bn = blockIdx.x * 128, bm = blockIdx.y * 128, z = blockIdx.z;

    f32x4 acc[4][4];
    #pragma unroll
    for (int i=0;i<4;i++)
        #pragma unroll
        for (int j=0;j<4;j++) acc[i][j] = (f32x4){0.f,0.f,0.f,0.f};

    int srow_off = lane >> 3;
    int sslot    = lane & 7;

    for (int term = 0; term < 3; ++term){
        const unsigned short* A = (term==2) ? xlo : xhi;
        const unsigned short* B = (term==0) ? wlo : whi;
        for (int k0 = z*KCH2; k0 < z*KCH2 + KCH2; k0 += 64) {
            #pragma unroll
            for (int q=0;q<4;q++){
                int brow = (wid*4+q)*8;
                int row  = brow + srow_off;
                int sl   = sslot ^ (row & 7);
                gld16(A + (size_t)(bm + row)*HIDDEN + k0 + sl*8, &As[brow][0]);
                gld16(B + (size_t)(bn + row)*HIDDEN + k0 + sl*8, &Bs[brow][0]);
            }
            __syncthreads();
            #pragma unroll
            for (int kk=0; kk<64; kk+=32){
                bf16x8 a[4], b[4];
                #pragma unroll
                for (int i=0;i<4;i++){
                    int row = wr*64 + i*16 + (lane&15);
                    int slot = ((kk>>3) + (lane>>4)) ^ (row & 7);
                    a[i] = *(const bf16x8*)&As[row][slot*8];
                }
                #pragma unroll
                for (int j=0;j<4;j++){
                    int row = wc*64 + j*16 + (lane&15);
                    int slot = ((kk>>3) + (lane>>4)) ^ (row & 7);
                    b[j] = *(const bf16x8*)&Bs[row][slot*8];
                }
                #pragma unroll
                for (int i=0;i<4;i++)
                    #pragma unroll
                    for (int j=0;j<4;j++)
                        acc[i][j] = MFMA16(a[i], b[j], acc[i][j]);
            }
            __syncthreads();
        }
    }
    float* Cz = Cpart + (size_t)z*TOK*NBCP;
    #pragma unroll
    for (int i=0;i<4;i++){
        int row0 = bm + wr*64 + i*16 + (lane>>4)*4;
        #pragma unroll
        for (int j=0;j<4;j++){
            int col = bn + wc*64 + j*16 + (lane&15);
            #pragma unroll
            for (int r=0;r<4;r++)
                Cz[(size_t)(row0+r)*NBCP + col] = acc[i][j][r];
        }
    }
}

// fixed-order reduce over KSPL2 partials + fused dt softplus
__global__ __launch_bounds__(256) void reduce_bc2(const float* __restrict__ part,
                                                  const float* __restrict__ dt_bias,
                                                  float* __restrict__ outBC,
                                                  float* __restrict__ dtbuf) {
    size_t i4 = (size_t)blockIdx.x*256 + threadIdx.x;
    if (i4 >= (size_t)TOK*NBCP/4) return;
    size_t i = i4*4;
    float4 s = *(const float4*)(part + i);
    #pragma unroll
    for (int z=1; z<KSPL2; z++){
        float4 v = *(const float4*)(part + (size_t)z*TOK*NBCP + i);
        s.x += v.x; s.y += v.y; s.z += v.z; s.w += v.w;
    }
    int col = (int)(i % NBCP);
    int t   = (int)(i / NBCP);
    if (col < 256) {
        *(float4*)(outBC + (size_t)t*NBC + col) = s;
    } else if (col < NBC) {
        int h = col - 256;
        float e[4] = {s.x, s.y, s.z, s.w};
        #pragma unroll
        for (int u=0;u<4;u++){
            float xv = e[u] + dt_bias[h+u];
            float sp = (xv > 20.f) ? xv : log1pf(expf(xv));
            e[u] = fminf(fmaxf(sp, 0.f), 100.f);
        }
        float4 o; o.x=e[0]; o.y=e[1]; o.z=e[2]; o.w=e[3];
        *(float4*)(dtbuf + (size_t)t*NUM_HEADS + h) = o;
    }
}

// ---------------- fused prep: x->(xhi,xlo), w1->bf16(padded), wbc->(hi,lo) ----------
#define N4A ((size_t)TOK*HIDDEN/4)
#define N4B ((size_t)PROJ_PAD*HIDDEN/4)
#define N4C ((size_t)NBCP*HIDDEN/4)
__global__ __launch_bounds__(256) void prep_kernel(const float* __restrict__ x,
                                                   const float* __restrict__ in_w,
                                                   unsigned short* __restrict__ xhi,
                                                   unsigned short* __restrict__ xlo,
                                                   unsigned short* __restrict__ w1b,
                                                   unsigned short* __restrict__ wbc_hi,
                                                   unsigned short* __restrict__ wbc_lo) {
    size_t gid = (size_t)blockIdx.x*256 + threadIdx.x;
    if (gid < N4A) {
        size_t i = gid*4;
        float4 v = *(const float4*)(x + i);
        float e[4] = {v.x, v.y, v.z, v.w};
        ushort4 h, l;
        unsigned short* hp = (unsigned short*)&h;
        unsigned short* lp = (unsigned short*)&l;
        #pragma unroll
        for (int u=0;u<4;u++){
            unsigned short hv = f2bf(e[u]);
            hp[u] = hv;
            lp[u] = f2bf(e[u] - bf2f(hv));
        }
        *(ushort4*)(xhi + i) = h;
        *(ushort4*)(xlo + i) = l;
    } else if (gid < N4A + N4B) {
        size_t j = gid - N4A;
        size_t i = j*4;
        int row = (int)(i / HIDDEN);
        ushort4 o;
        if (row < PROJ){
            float4 v = *(const float4*)(in_w + i);
            o.x=f2bf(v.x); o.y=f2bf(v.y); o.z=f2bf(v.z); o.w=f2bf(v.w);
        } else { o.x=o.y=o.z=o.w=0; }
        *(ushort4*)(w1b + i) = o;
    } else {
        size_t j = gid - N4A - N4B;
        size_t i = j*4;
        int row = (int)(i / HIDDEN);
        int kk  = (int)(i % HIDDEN);
        ushort4 h, l;
        h.x=h.y=h.z=h.w=0; l.x=l.y=l.z=l.w=0;
        if (row < NBC){
            float4 v = *(const float4*)(in_w + (size_t)(2*INTER + row)*HIDDEN + kk);
            float e[4] = {v.x, v.y, v.z, v.w};
            unsigned short* hp = (unsigned short*)&h;
            unsigned short* lp = (unsigned short*)&l;
            #pragma unroll
            for (int u=0;u<4;u++){
                unsigned short hv = f2bf(e[u]);
                hp[u] = hv;
                lp[u] = f2bf(e[u] - bf2f(hv));
            }
        }
        *(ushort4*)(wbc_hi + i) = h;
        *(ushort4*)(wbc_lo + i) = l;
    }
}

// ---------------- cvt for w2 --------------------------------------------------------
__global__ __launch_bounds__(256) void cvt_bf16(const float* __restrict__ in,
                                                unsigned short* __restrict__ out, size_t n4){
    size_t i4 = (size_t)blockIdx.x*256 + threadIdx.x;
    if (i4 >= n4) return;
    size_t i = i4*4;
    float4 v = *(const float4*)(in+i);
    ushort4 o; o.x=f2bf(v.x); o.y=f2bf(v.y); o.z=f2bf(v.z); o.w=f2bf(v.w);
    *(ushort4*)(out+i) = o;
}

// ---------------- fused conv: XT part + B/C part ------------------------------------
__global__ __launch_bounds__(256) void conv_fused(const unsigned short* __restrict__ projb,
                                                  const float* __restrict__ projBC,
                                                  const float* __restrict__ cw,
                                                  const float* __restrict__ cb,
                                                  unsigned short* __restrict__ XT,
                                                  float* __restrict__ xBC_BC,
                                                  unsigned short* __restrict__ BT) {
    __shared__ unsigned short raw[68][66];
    int bid = blockIdx.x;
    int tid = threadIdx.x;
    if (bid < (TOK/64)*(INTER/64)) {
        // ---- conv_xt: 64 tokens x 64 dims, LDS transpose ----
        int bx = bid & 63, by = bid >> 6;
        int t0 = bx * 64, d0 = by * 64;
        int b  = t0 / SEQ;
        int s0 = t0 % SEQ;
        for (int f = tid; f < 67*8; f += 256){
            int r = f >> 3, g = f & 7;
            int sp = s0 - 3 + r;
            uint4 v;
            if (sp >= 0) v = *(const uint4*)(projb + ((size_t)(b*SEQ+sp))*PROJ_PAD + INTER + d0 + g*8);
            else { v.x=0u; v.y=0u; v.z=0u; v.w=0u; }
            unsigned int* dst = (unsigned int*)&raw[r][g*8];
            dst[0]=v.x; dst[1]=v.y; dst[2]=v.z; dst[3]=v.w;
        }
        __syncthreads();
        int t = tid & 63, dg = tid >> 6;
        #pragma unroll
        for (int dd = 0; dd < 16; dd++){
            int d = dg*16 + dd;
            float acc = cb[d0+d];
            #pragma unroll
            for (int j=0;j<CONV_K;j++)
                acc += cw[(d0+d)*CONV_K+j] * bf2f(raw[t+j][d]);
            float val = acc/(1.f+expf(-acc));
            XT[((size_t)(b*INTER + d0 + d))*SEQ + s0 + t] = f2bf(val);
        }
    } else {
        // ---- conv_bc: fp32 B/C + bf16 BT ----
        int idx = (bid - (TOK/64)*(INTER/64))*256 + tid;
        if (idx >= TOK*256) return;
        int d = idx & 255;
        int t = idx >> 8;
        int b = t / SEQ, sl = t % SEQ;
        int dc = INTER + d;
        float acc = cb[dc];
        #pragma unroll
        for (int j=0;j<CONV_K;j++){
            int sp = sl - (CONV_K-1) + j;
            if (sp >= 0)
                acc += cw[dc*CONV_K+j] * projBC[((size_t)(b*SEQ+sp))*NBC + d];
        }
        float val = acc / (1.f + expf(-acc));
        xBC_BC[(size_t)t*256 + d] = val;
        if (d < 128)
            BT[((size_t)(b*128 + d))*SEQ + sl] = f2bf(val);
    }
}

// ---------------- per-chunk inclusive cumsum of dA = A*dt ---------------------------
__global__ __launch_bounds__(256) void cumsum_kernel(const float* __restrict__ dtbuf,
                                                     const float* __restrict__ A_log,
                                                     float* __restrict__ A_cum) {
    int c = blockIdx.x, h = blockIdx.y, b = blockIdx.z;
    int l = threadIdx.x;
    float A = -expf(A_log[h]);
    float v = A * dtbuf[(size_t)(b*SEQ + c*CHUNK + l)*NUM_HEADS + h];
    __shared__ float buf[CHUNK];
    buf[l] = v;
    __syncthreads();
    for (int off=1; off<CHUNK; off<<=1){
        float t = (l>=off) ? buf[l-off] : 0.f;
        __syncthreads();
        buf[l] += t;
        __syncthreads();
    }
    A_cum[((size_t)b*NUM_HEADS + h)*SEQ + c*CHUNK + l] = buf[l];
}

// ---------------- G[l][s] = C[l] . B[s]  (head-shared), bf16, l-major ---------------
__global__ __launch_bounds__(256) void g_kernel(const float* __restrict__ xBC_BC,
                                                unsigned short* __restrict__ G) {
    int p = blockIdx.x, c = blockIdx.y, b = blockIdx.z;
    int lt = 0, a0 = 0;
    while (a0 + lt + 1 <= p) { a0 += lt + 1; lt++; }
    int st = p - a0;
    int l0 = lt*64, s0 = st*64;
    __shared__ float Cs[64][68];
    __shared__ float Bs[64][68];
    int tid = threadIdx.x, ty = tid >> 4, tx = tid & 15;
    float acc[4][4];
    #pragma unroll
    for (int i=0;i<4;i++)
        #pragma unroll
        for (int j=0;j<4;j++) acc[i][j]=0.f;

    size_t rowC = ((size_t)(b*SEQ + c*CHUNK + l0))*256 + 128;
    size_t rowB = ((size_t)(b*SEQ + c*CHUNK + s0))*256;
    for (int kc=0; kc<2; kc++){
        #pragma unroll
        for (int it=0; it<4; it++){
            int f = tid + it*256;
            int r = f >> 4, c4 = f & 15;
            float4 cv = *(const float4*)(xBC_BC + rowC + (size_t)r*256 + kc*64 + c4*4);
            float4 bv = *(const float4*)(xBC_BC + rowB + (size_t)r*256 + kc*64 + c4*4);
            *(float4*)&Cs[r][c4*4] = cv;
            *(float4*)&Bs[r][c4*4] = bv;
        }
        __syncthreads();
        #pragma unroll 8
        for (int k=0;k<64;k++){
            float a[4], bb[4];
            #pragma unroll
            for (int i=0;i<4;i++) a[i] = Cs[ty*4+i][k];
            #pragma unroll
            for (int j=0;j<4;j++) bb[j] = Bs[tx*4+j][k];
            #pragma unroll
            for (int i=0;i<4;i++)
                #pragma unroll
                for (int j=0;j<4;j++) acc[i][j] += a[i]*bb[j];
        }
        __syncthreads();
    }
    size_t Gb = ((size_t)(b*NC + c)) << 16;
    #pragma unroll
    for (int i=0;i<4;i++){
        ushort4 g4;
        g4.x = f2bf(acc[i][0]); g4.y = f2bf(acc[i][1]);
        g4.z = f2bf(acc[i][2]); g4.w = f2bf(acc[i][3]);
        *(ushort4*)(G + Gb + (size_t)(l0 + ty*4 + i)*256 + s0 + tx*4) = g4;
    }
}

// ---------------- statesT[p][n] = sum_l XT[p][l] * (BT[n][l]*w[l])  (MFMA) ----------
__global__ __launch_bounds__(256) void states_mfma(const unsigned short* __restrict__ XT,
                                                   const unsigned short* __restrict__ BT,
                                                   const float* __restrict__ dtbuf,
                                                   const float* __restrict__ A_cum,
                                                   float* __restrict__ statesT) {
    int c = blockIdx.x, h = blockIdx.y, b = blockIdx.z;
    __shared__ unsigned short Asx[64][64];
    __shared__ unsigned short Bsw[128][64];
    __shared__ float wl[CHUNK];
    int tid = threadIdx.x, lane = tid & 63, wid = tid >> 6;
    {
        const float* ac = A_cum + ((size_t)(b*NUM_HEADS+h))*SEQ + c*CHUNK;
        float Alast = ac[CHUNK-1];
        wl[tid] = expf(Alast - ac[tid]) * dtbuf[((size_t)(b*SEQ + c*CHUNK + tid))*NUM_HEADS + h];
    }
    __syncthreads();
    f32x4 acc[4][2];
    #pragma unroll
    for (int i=0;i<4;i++)
        #pragma unroll
        for (int j=0;j<2;j++) acc[i][j] = (f32x4){0.f,0.f,0.f,0.f};

    for (int kc = 0; kc < 4; kc++){
        int lbase = kc*64;
        #pragma unroll
        for (int q=0;q<2;q++){
            int brow = (wid*2+q)*8;
            int row  = brow + (lane>>3);
            int sl   = (lane&7) ^ (row & 7);
            gld16(XT + ((size_t)(b*INTER + h*HEAD_DIM + row))*SEQ + c*CHUNK + lbase + sl*8,
                  &Asx[brow][0]);
        }
        #pragma unroll
        for (int it=0; it<4; it++){
            int f = tid + it*256;
            int r = f >> 3, g = f & 7;
            uint4 v = *(const uint4*)(BT + ((size_t)(b*128 + r))*SEQ + c*CHUNK + lbase + g*8);
            float e[8]; unpack8(v, e);
            unsigned short o[8];
            #pragma unroll
            for (int u=0;u<8;u++) o[u] = f2bf(e[u] * wl[lbase + g*8 + u]);
            int slot = g ^ (r & 7);
            *(ushort4*)&Bsw[r][slot*8]   = *(ushort4*)&o[0];
            *(ushort4*)&Bsw[r][slot*8+4] = *(ushort4*)&o[4];
        }
        __syncthreads();
        #pragma unroll
        for (int kk=0; kk<64; kk+=32){
            bf16x8 a[4], bb[2];
            #pragma unroll
            for (int i=0;i<4;i++){
                int row = i*16 + (lane&15);
                int slot = ((kk>>3)+(lane>>4)) ^ (row&7);
                a[i] = *(const bf16x8*)&Asx[row][slot*8];
            }
            #pragma unroll
            for (int j=0;j<2;j++){
                int row = wid*32 + j*16 + (lane&15);
                int slot = ((kk>>3)+(lane>>4)) ^ (row&7);
                bb[j] = *(const bf16x8*)&Bsw[row][slot*8];
            }
            #pragma unroll
            for (int i=0;i<4;i++)
                #pragma unroll
                for (int j=0;j<2;j++)
                    acc[i][j] = MFMA16(a[i], bb[j], acc[i][j]);
        }
        __syncthreads();
    }
    size_t sb = ((size_t)((b*NC + c)*NUM_HEADS + h))*(HEAD_DIM*STATE);
    #pragma unroll
    for (int i=0;i<4;i++){
        #pragma unroll
        for (int j=0;j<2;j++){
            int n = wid*32 + j*16 + (lane&15);
            int p0 = i*16 + (lane>>4)*4;
            #pragma unroll
            for (int r=0;r<4;r++)
                statesT[sb + (size_t)(p0+r)*128 + n] = acc[i][j][r];
        }
    }
}

// ---------------- inter-chunk recurrence (in place) ---------------------------------
__global__ __launch_bounds__(256) void recur_kernel(const float* __restrict__ A_cum,
                                                    float* __restrict__ states) {
    int h = blockIdx.x, b = blockIdx.y;
    int tid = threadIdx.x;
    float Srun[32];
    #pragma unroll
    for (int i=0;i<32;i++) Srun[i]=0.f;
    const float* acum = A_cum + ((size_t)b*NUM_HEADS + h)*SEQ;
    for (int c=0;c<NC;c++){
        float alast = acum[c*CHUNK + CHUNK-1];
        float dec = expf(alast);
        size_t base = ((size_t)((b*NC + c)*NUM_HEADS + h))*(HEAD_DIM*STATE);
        #pragma unroll
        for (int i=0;i<32;i++){
            size_t idx = base + (size_t)tid + (size_t)i*256;
            float raw = states[idx];
            states[idx] = Srun[i];
            Srun[i] = Srun[i]*dec + raw;
        }
    }
}

// ---------------- Y = e_l*(Cs @ St^T) + Gw @ Xs^T + D*X   (MFMA) --------------------
__global__ __launch_bounds__(256) void yscan_mfma(const unsigned short* __restrict__ G,
                                                  const float* __restrict__ xBC_BC,
                                                  const unsigned short* __restrict__ XT,
                                                  const float* __restrict__ dtbuf,
                                                  const float* __restrict__ A_cum,
                                                  const float* __restrict__ statesT,
                                                  const float* __restrict__ Dvec,
                                                  unsigned short* __restrict__ projb) {
    int xb = blockIdx.x;
    int c = xb >> 2, lt = xb & 3;
    int h = blockIdx.y, b = blockIdx.z;
    int l0 = lt*64;
    __shared__ __align__(16) char pool[32768];
    unsigned short (*Cs)[128] = (unsigned short(*)[128])pool;
    unsigned short (*St)[128] = (unsigned short(*)[128])(pool + 16384);
    unsigned short (*Gw)[64]  = (unsigned short(*)[64])pool;
    unsigned short (*Xs)[64]  = (unsigned short(*)[64])(pool + 8192);
    float (*Ot)[68]           = (float(*)[68])pool;
    __shared__ float ac[CHUNK], dts[CHUNK];
    int tid = threadIdx.x, lane = tid & 63, wid = tid >> 6;
    ac[tid]  = A_cum[((size_t)(b*NUM_HEADS + h))*SEQ + c*CHUNK + tid];
    dts[tid] = dtbuf[((size_t)(b*SEQ + c*CHUNK + tid))*NUM_HEADS + h];
    __syncthreads();

    size_t stb = ((size_t)((b*NC + c)*NUM_HEADS + h))*(HEAD_DIM*STATE);
    #pragma unroll
    for (int it=0; it<8; it++){
        int f = tid + it*256;
        int r = f >> 5, c4 = f & 31;
        float4 v = *(const float4*)(xBC_BC + ((size_t)(b*SEQ + c*CHUNK + l0 + r))*256 + 128 + c4*4);
        unsigned short o[4] = {f2bf(v.x),f2bf(v.y),f2bf(v.z),f2bf(v.w)};
        int col = c4*4;
        int slot = (col>>3) ^ (r&7);
        *(ushort4*)&Cs[r][slot*8 + (col&7)] = *(ushort4*)o;
        float4 w = *(const float4*)(statesT + stb + (size_t)r*128 + c4*4);
        unsigned short o2[4] = {f2bf(w.x),f2bf(w.y),f2bf(w.z),f2bf(w.w)};
        *(ushort4*)&St[r][slot*8 + (col&7)] = *(ushort4*)o2;
    }
    __syncthreads();

    f32x4 acc1[4];
    #pragma unroll
    for (int j=0;j<4;j++) acc1[j] = (f32x4){0.f,0.f,0.f,0.f};
    #pragma unroll
    for (int kk=0; kk<128; kk+=32){
        int arow = wid*16 + (lane&15);
        int aslot = ((kk>>3)+(lane>>4)) ^ (arow&7);
        bf16x8 a = *(const bf16x8*)&Cs[arow][aslot*8];
        #pragma unroll
        for (int j=0;j<4;j++){
            int brow = j*16 + (lane&15);
            int bslot = ((kk>>3)+(lane>>4)) ^ (brow&7);
            bf16x8 bb = *(const bf16x8*)&St[brow][bslot*8];
            acc1[j] = MFMA16(a, bb, acc1[j]);
        }
    }
    float el[4];
    #pragma unroll
    for (int r=0;r<4;r++) el[r] = expf(ac[l0 + wid*16 + (lane>>4)*4 + r]);
    float master[4][4];
    #pragma unroll
    for (int j=0;j<4;j++)
        #pragma unroll
        for (int r=0;r<4;r++) master[j][r] = acc1[j][r]*el[r];
    __syncthreads();

    size_t Gb = ((size_t)(b*NC + c)) << 16;
    f32x4 acc2[4];
    #pragma unroll
    for (int j=0;j<4;j++) acc2[j] = (f32x4){0.f,0.f,0.f,0.f};
    for (int st=0; st<=lt; st++){
        int s0 = st*64;
        #pragma unroll
        for (int it=0; it<2; it++){
            int f = tid + it*256;
            int r = f >> 3, g = f & 7;
            uint4 v = *(const uint4*)(G + Gb + (size_t)(l0 + r)*256 + s0 + g*8);
            float e[8]; unpack8(v, e);
            float acl = ac[l0 + r];
            unsigned short o[8];
            #pragma unroll
            for (int u=0;u<8;u++){
                int s = s0 + g*8 + u;
                float w = (s <= l0 + r) ? expf(acl - ac[s])*dts[s] : 0.f;
                o[u] = f2bf(e[u]*w);
            }
            int slot = g ^ (r&7);
            *(ushort4*)&Gw[r][slot*8]   = *(ushort4*)&o[0];
            *(ushort4*)&Gw[r][slot*8+4] = *(ushort4*)&o[4];
        }
        #pragma unroll
        for (int q=0;q<2;q++){
            int brow = (wid*2+q)*8;
            int row  = brow + (lane>>3);
            int sl   = (lane&7) ^ (row&7);
            gld16(XT + ((size_t)(b*INTER + h*HEAD_DIM + row))*SEQ + c*CHUNK + s0 + sl*8,
                  &Xs[brow][0]);
        }
        __syncthreads();
        #pragma unroll
        for (int kk=0; kk<64; kk+=32){
            int arow = wid*16 + (lane&15);
            int aslot = ((kk>>3)+(lane>>4)) ^ (arow&7);
            bf16x8 a = *(const bf16x8*)&Gw[arow][aslot*8];
            #pragma unroll
            for (int j=0;j<4;j++){
                int brow = j*16 + (lane&15);
                int bslot = ((kk>>3)+(lane>>4)) ^ (brow&7);
                bf16x8 bb = *(const bf16x8*)&Xs[brow][bslot*8];
                acc2[j] = MFMA16(a, bb, acc2[j]);
            }
        }
        if (st < lt) __syncthreads();
    }

    float Dh = Dvec[h];
    #pragma unroll
    for (int j=0;j<4;j++){
        int p = j*16 + (lane&15);
        #pragma unroll
        for (int r=0;r<4;r++){
            int sl_ = wid*16 + (lane>>4)*4 + r;
            int slot = (sl_>>3) ^ (p&7);
            float xv = bf2f(Xs[p][slot*8 + (sl_&7)]);
            master[j][r] += acc2[j][r] + Dh*xv;
        }
    }
    __syncthreads();

    #pragma unroll
    for (int j=0;j<4;j++){
        int p = j*16 + (lane&15);
        #pragma unroll
        for (int r=0;r<4;r++)
            Ot[wid*16 + (lane>>4)*4 + r][p] = master[j][r];
    }
    __syncthreads();
    #pragma unroll
    for (int it=0; it<4; it++){
        int f = tid + it*256;
        int r = f >> 4, c4 = f & 15;
        ushort4 o;
        o.x = f2bf(Ot[r][c4*4+0]); o.y = f2bf(Ot[r][c4*4+1]);
        o.z = f2bf(Ot[r][c4*4+2]); o.w = f2bf(Ot[r][c4*4+3]);
        *(ushort4*)(projb + ((size_t)(b*SEQ + c*CHUNK + l0 + r))*PROJ_PAD + INTER + h*HEAD_DIM + c4*4) = o;
    }
}

// ---------------- gate * silu + RMSNorm -> packed bf16 y ----------------------------
__global__ __launch_bounds__(256) void gate_norm_kernel(const unsigned short* __restrict__ projb,
                                                        const float* __restrict__ normw,
                                                        unsigned short* __restrict__ yb) {
    int t = blockIdx.x;
    int tid = threadIdx.x;
    const unsigned short* row = projb + (size_t)t*PROJ_PAD;
    __shared__ float red[4];
    float vals[20];
    float ss = 0.f;
    #pragma unroll
    for (int i=0;i<5;i++){
        int j = (tid + i*256)*4;
        ushort4 g4 = *(const ushort4*)(row + j);
        ushort4 y4 = *(const ushort4*)(row + INTER + j);
        #pragma unroll
        for (int u=0;u<4;u++){
            float g = bf2f(((const unsigned short*)&g4)[u]);
            float y = bf2f(((const unsigned short*)&y4)[u]);
            float gv = g / (1.f + expf(-g));
            float v = y * gv;
            vals[i*4+u] = v;
            ss += v*v;
        }
    }
    #pragma unroll
    for (int off=32; off; off>>=1) ss += __shfl_xor(ss, off);
    if ((tid&63)==0) red[tid>>6] = ss;
    __syncthreads();
    float tot = red[0]+red[1]+red[2]+red[3];
    float inv = rsqrtf(tot/(float)INTER + EPS);
    #pragma unroll
    for (int i=0;i<5;i++){
        int j = (tid + i*256)*4;
        ushort4 o;
        o.x = f2bf(vals[i*4+0] * inv * normw[j+0]);
        o.y = f2bf(vals[i*4+1] * inv * normw[j+1]);
        o.z = f2bf(vals[i*4+2] * inv * normw[j+2]);
        o.w = f2bf(vals[i*4+3] * inv * normw[j+3]);
        *(ushort4*)(yb + (size_t)t*INTER + j) = o;
    }
}

// ------------------------------------------------------------------------------------
extern "C" void kernel_launch(void* const* d_in, const int* in_sizes, int n_in,
                              void* d_out, int out_size, void* d_ws, size_t ws_size,
                              hipStream_t stream) {
    const float* x        = (const float*)d_in[0];
    const float* in_w     = (const float*)d_in[1];
    const float* conv_w   = (const float*)d_in[2];
    const float* conv_b   = (const float*)d_in[3];
    const float* A_log    = (const float*)d_in[4];
    const float* Dvec     = (const float*)d_in[5];
    const float* dt_bias  = (const float*)d_in[6];
    const float* norm_w   = (const float*)d_in[7];
    const float* out_w    = (const float*)d_in[8];
    float* out = (float*)d_out;
    (void)ws_size; (void)n_in; (void)in_sizes; (void)out_size;

    // ---- fixed workspace (bytes) ~186 MB ----
    const size_t PROJB   = (size_t)TOK*PROJ_PAD*2;          // 87.0 MB
    const size_t PROJBCB = (size_t)TOK*NBC*4;               //  5.5 MB
    const size_t XTB     = (size_t)TOK*INTER*2;             // 41.9 MB
    const size_t XBCBCB  = (size_t)TOK*256*4;               //  4.2 MB
    const size_t BTB     = (size_t)BATCH*128*SEQ*2;         //  1.0 MB
    const size_t GBYTES  = (size_t)BATCH*NC*CHUNK*CHUNK*2;  //  2.1 MB
    const size_t DTB     = (size_t)TOK*NUM_HEADS*4;         //  1.3 MB
    const size_t ACUMB   = DTB;
    const size_t STB     = (size_t)BATCH*NC*NUM_HEADS*HEAD_DIM*STATE*4; // 41.9 MB
    // ---- transient region (aliased phases) ~98 MB ----
    const size_t XHB   = (size_t)TOK*HIDDEN*2;              // 21.0 MB
    const size_t WBCB  = (size_t)NBCP*HIDDEN*2;             //  1.9 MB
    const size_t YBB   = (size_t)TOK*INTER*2;               // 41.9 MB

    char* base = (char*)d_ws;
    size_t off = 0;
    unsigned short* projb  = (unsigned short*)(base + off); off += PROJB;
    float* projBC          = (float*)(base + off);          off += PROJBCB;
    unsigned short* XTp    = (unsigned short*)(base + off); off += XTB;
    float* xBC_BC          = (float*)(base + off);          off += XBCBCB;
    unsigned short* BTp    = (unsigned short*)(base + off); off += BTB;
    unsigned short* Gp     = (unsigned short*)(base + off); off += GBYTES;
    float* dtbuf           = (float*)(base + off);          off += DTB;
    float* A_cum           = (float*)(base + off);          off += ACUMB;
    float* statesT         = (float*)(base + off);          off += STB;
    char*  T               = base + off;
    // phase A (prep/GEMM1/bc): [xhi | xlo | wbc_hi | wbc_lo | w1b(=bcpart alias)]
    unsigned short* xhi    = (unsigned short*)T;
    unsigned short* xlo    = (unsigned short*)(T + XHB);
    unsigned short* wbc_hi = (unsigned short*)(T + 2*XHB);
    unsigned short* wbc_lo = (unsigned short*)(T + 2*XHB + WBCB);
    unsigned short* w1b    = (unsigned short*)(T + 2*XHB + 2*WBCB);
    float* bcpart          = (float*)w1b;               // 50.3 MB <= w1b's 54.4 MB
    // phase B (GEMM2): yb aliases [xhi|xlo]; w2b aliases [wbc.., w1b head]
    unsigned short* yb     = (unsigned short*)T;
    unsigned short* w2b    = (unsigned short*)(T + YBB);

    const size_t W2_E = (size_t)HIDDEN*INTER;

    // 1. fused prep: xhi/xlo, w1b (padded), wbc hi/lo
    {
        unsigned total_blocks = (unsigned)((N4A + N4B + N4C) / 256);
        prep_kernel<<<total_blocks, 256, 0, stream>>>(x, in_w, xhi, xlo, w1b, wbc_hi, wbc_lo);
    }
    // 2. proj = x @ in_w^T  (128x128 bf16 MFMA, bf16 out, XCD swizzle)
    gemm_bf16<true><<<dim3(PROJ_PAD/128, TOK/128), 256, 0, stream>>>(xhi, HIDDEN, w1b, HIDDEN,
                                                                     projb, PROJ_PAD, HIDDEN);
    // 3. B/C/dt columns via bf16 hi/lo split-K MFMA (fp32-quality); partials alias w1b
    bc_splitk_mfma<<<dim3(NBCP/128, TOK/128, KSPL2), 256, 0, stream>>>(xhi, xlo, wbc_hi, wbc_lo, bcpart);
    reduce_bc2<<<(unsigned)(((size_t)TOK*NBCP/4)/256), 256, 0, stream>>>(bcpart, dt_bias, projBC, dtbuf);
    // 4. fused conv (XT + B/C)
    conv_fused<<<(TOK/64)*(INTER/64) + TOK, 256, 0, stream>>>(projb, projBC, conv_w, conv_b,
                                                              XTp, xBC_BC, BTp);
    // 5. w2 conversion (partials dead after reduce)
    cvt_bf16<<<(unsigned)((W2_E/4+255)/256), 256, 0, stream>>>(out_w, w2b, W2_E/4);
    // 6. cumsum
    cumsum_kernel<<<dim3(NC, NUM_HEADS, BATCH), 256, 0, stream>>>(dtbuf, A_log, A_cum);
    // 7. G = C.B^T (head-shared), [l][s]
    g_kernel<<<dim3(10, NC, BATCH), 256, 0, stream>>>(xBC_BC, Gp);
    // 8. per-chunk states (MFMA)
    states_mfma<<<dim3(NC, NUM_HEADS, BATCH), 256, 0, stream>>>(XTp, BTp, dtbuf, A_cum, statesT);
    // 9. inter-chunk recurrence
    recur_kernel<<<dim3(NUM_HEADS, BATCH), 256, 0, stream>>>(A_cum, statesT);
    // 10. Y (MFMA) -> bf16 into projb
    yscan_mfma<<<dim3(NC*4, NUM_HEADS, BATCH), 256, 0, stream>>>(Gp, xBC_BC, XTp, dtbuf, A_cum,
                                                                 statesT, Dvec, projb);
    // 11. gate + RMSNorm -> bf16 y (aliases xhi/xlo, dead after step 3)
    gate_norm_kernel<<<TOK, 256, 0, stream>>>(projb, norm_w, yb);
    // 12. out = y @ out_w^T  (128x128 bf16 MFMA, fp32 out, XCD swizzle)
    gemm_bf16<false><<<dim3(HIDDEN/128, TOK/128), 256, 0, stream>>>(yb, INTER, w2b, INTER,
                                                                    out, HIDDEN, INTER);
}

// Round 11
// 726.776 us; speedup vs baseline: 1.2763x; 1.0535x over previous
//
#include <hip/hip_runtime.h>
#include <hip/hip_bf16.h>
#include <math.h>

#define HIDDEN   2560
#define NUM_HEADS 80
#define HEAD_DIM 64
#define STATE    128
#define CONV_K   4
#define CHUNK    256
#define INTER    (2*HIDDEN)                 // 5120
#define CONV_DIM (INTER + 2*STATE)          // 5376
#define PROJ     (INTER + CONV_DIM + NUM_HEADS) // 10576
#define PROJ_PAD 10240                      // gate + X only (80*128)
#define NBC      336                        // B,C (256) + dt (80) columns
#define NBCP     384                        // padded to 3*128
#define EPS      1e-5f

#define BATCH 2
#define SEQ   2048
#define TOK   (BATCH*SEQ)                   // 4096
#define NC    (SEQ/CHUNK)                   // 8
#define KSPL2 8
#define KCH2  (HIDDEN/KSPL2)                // 320

typedef __attribute__((ext_vector_type(8))) short bf16x8;
typedef __attribute__((ext_vector_type(4))) float f32x4;

#define MFMA16(a,b,c) __builtin_amdgcn_mfma_f32_16x16x32_bf16((a),(b),(c),0,0,0)

__device__ __forceinline__ unsigned short f2bf(float f){
    union{float f;unsigned u;}v; v.f=f;
    unsigned r = v.u + 0x7fffu + ((v.u>>16)&1u);
    return (unsigned short)(r>>16);
}
__device__ __forceinline__ float bf2f(unsigned short s){
    union{unsigned u;float f;}v; v.u = ((unsigned)s)<<16; return v.f;
}
__device__ __forceinline__ void unpack8(uint4 u, float* e){
    e[0]=bf2f((unsigned short)(u.x&0xffff)); e[1]=bf2f((unsigned short)(u.x>>16));
    e[2]=bf2f((unsigned short)(u.y&0xffff)); e[3]=bf2f((unsigned short)(u.y>>16));
    e[4]=bf2f((unsigned short)(u.z&0xffff)); e[5]=bf2f((unsigned short)(u.z>>16));
    e[6]=bf2f((unsigned short)(u.w&0xffff)); e[7]=bf2f((unsigned short)(u.w>>16));
}

__device__ __forceinline__ void gld16(const void* g, void* l){
    __builtin_amdgcn_global_load_lds((const __attribute__((address_space(1))) void*)g,
                                     (__attribute__((address_space(3))) void*)l, 16, 0, 0);
}

// =============== 128x128 bf16 MFMA GEMM (NT) ==========================================
template<bool BF16OUT>
__global__ __launch_bounds__(256) void gemm_bf16(const unsigned short* __restrict__ A, int lda,
                                                 const unsigned short* __restrict__ B, int ldb,
                                                 void* __restrict__ Cv, int ldc, int K) {
    __shared__ unsigned short As[128][64];
    __shared__ unsigned short Bs[128][64];
    int tid = threadIdx.x;
    int lane = tid & 63, wid = tid >> 6;
    int wr = wid >> 1, wc = wid & 1;

    int bm, bn;
    if ((gridDim.y & 7) == 0) {
        int bid   = blockIdx.y * gridDim.x + blockIdx.x;
        int xcd   = bid & 7;
        int local = bid >> 3;
        int mrows = gridDim.y >> 3;
        bm = (xcd * mrows + (local % mrows)) * 128;
        bn = (local / mrows) * 128;
    } else {
        bm = blockIdx.y * 128;
        bn = blockIdx.x * 128;
    }

    f32x4 acc[4][4];
    #pragma unroll
    for (int i=0;i<4;i++)
        #pragma unroll
        for (int j=0;j<4;j++) acc[i][j] = (f32x4){0.f,0.f,0.f,0.f};

    int srow_off = lane >> 3;
    int sslot    = lane & 7;

    for (int k0 = 0; k0 < K; k0 += 64) {
        #pragma unroll
        for (int q=0;q<4;q++){
            int brow = (wid*4+q)*8;
            int row  = brow + srow_off;
            int sl   = sslot ^ (row & 7);
            gld16(A + (size_t)(bm + row)*lda + k0 + sl*8, &As[brow][0]);
            gld16(B + (size_t)(bn + row)*ldb + k0 + sl*8, &Bs[brow][0]);
        }
        __syncthreads();
        #pragma unroll
        for (int kk=0; kk<64; kk+=32){
            bf16x8 a[4], b[4];
            #pragma unroll
            for (int i=0;i<4;i++){
                int row = wr*64 + i*16 + (lane&15);
                int slot = ((kk>>3) + (lane>>4)) ^ (row & 7);
                a[i] = *(const bf16x8*)&As[row][slot*8];
            }
            #pragma unroll
            for (int j=0;j<4;j++){
                int row = wc*64 + j*16 + (lane&15);
                int slot = ((kk>>3) + (lane>>4)) ^ (row & 7);
                b[j] = *(const bf16x8*)&Bs[row][slot*8];
            }
            #pragma unroll
            for (int i=0;i<4;i++)
                #pragma unroll
                for (int j=0;j<4;j++)
                    acc[i][j] = MFMA16(a[i], b[j], acc[i][j]);
        }
        __syncthreads();
    }
    #pragma unroll
    for (int i=0;i<4;i++){
        int row0 = bm + wr*64 + i*16 + (lane>>4)*4;
        #pragma unroll
        for (int j=0;j<4;j++){
            int col = bn + wc*64 + j*16 + (lane&15);
            #pragma unroll
            for (int r=0;r<4;r++){
                if (BF16OUT)
                    ((unsigned short*)Cv)[(size_t)(row0+r)*ldc + col] = f2bf(acc[i][j][r]);
                else
                    ((float*)Cv)[(size_t)(row0+r)*ldc + col] = acc[i][j][r];
            }
        }
    }
}

// =============== bf16 hi/lo split-K MFMA for B/C/dt (fp32-quality) ====================
__global__ __launch_bounds__(256) void bc_splitk_mfma(const unsigned short* __restrict__ xhi,
                                                      const unsigned short* __restrict__ xlo,
                                                      const unsigned short* __restrict__ whi,
                                                      const unsigned short* __restrict__ wlo,
                                                      float* __restrict__ Cpart) {
    __shared__ unsigned short As[128][64];
    __shared__ unsigned short Bs[128][64];
    int tid = threadIdx.x;
    int lane = tid & 63, wid = tid >> 6;
    int wr = wid >> 1, wc = wid & 1;
    int bn = blockIdx.x * 128, bm = blockIdx.y * 128, z = blockIdx.z;

    f32x4 acc[4][4];
    #pragma unroll
    for (int i=0;i<4;i++)
        #pragma unroll
        for (int j=0;j<4;j++) acc[i][j] = (f32x4){0.f,0.f,0.f,0.f};

    int srow_off = lane >> 3;
    int sslot    = lane & 7;

    for (int term = 0; term < 3; ++term){
        const unsigned short* A = (term==2) ? xlo : xhi;
        const unsigned short* B = (term==0) ? wlo : whi;
        for (int k0 = z*KCH2; k0 < z*KCH2 + KCH2; k0 += 64) {
            #pragma unroll
            for (int q=0;q<4;q++){
                int brow = (wid*4+q)*8;
                int row  = brow + srow_off;
                int sl   = sslot ^ (row & 7);
                gld16(A + (size_t)(bm + row)*HIDDEN + k0 + sl*8, &As[brow][0]);
                gld16(B + (size_t)(bn + row)*HIDDEN + k0 + sl*8, &Bs[brow][0]);
            }
            __syncthreads();
            #pragma unroll
            for (int kk=0; kk<64; kk+=32){
                bf16x8 a[4], b[4];
                #pragma unroll
                for (int i=0;i<4;i++){
                    int row = wr*64 + i*16 + (lane&15);
                    int slot = ((kk>>3) + (lane>>4)) ^ (row & 7);
                    a[i] = *(const bf16x8*)&As[row][slot*8];
                }
                #pragma unroll
                for (int j=0;j<4;j++){
                    int row = wc*64 + j*16 + (lane&15);
                    int slot = ((kk>>3) + (lane>>4)) ^ (row & 7);
                    b[j] = *(const bf16x8*)&Bs[row][slot*8];
                }
                #pragma unroll
                for (int i=0;i<4;i++)
                    #pragma unroll
                    for (int j=0;j<4;j++)
                        acc[i][j] = MFMA16(a[i], b[j], acc[i][j]);
            }
            __syncthreads();
        }
    }
    float* Cz = Cpart + (size_t)z*TOK*NBCP;
    #pragma unroll
    for (int i=0;i<4;i++){
        int row0 = bm + wr*64 + i*16 + (lane>>4)*4;
        #pragma unroll
        for (int j=0;j<4;j++){
            int col = bn + wc*64 + j*16 + (lane&15);
            #pragma unroll
            for (int r=0;r<4;r++)
                Cz[(size_t)(row0+r)*NBCP + col] = acc[i][j][r];
        }
    }
}

// fixed-order reduce over KSPL2 partials + fused dt softplus
__global__ __launch_bounds__(256) void reduce_bc2(const float* __restrict__ part,
                                                  const float* __restrict__ dt_bias,
                                                  float* __restrict__ outBC,
                                                  float* __restrict__ dtbuf) {
    size_t i4 = (size_t)blockIdx.x*256 + threadIdx.x;
    if (i4 >= (size_t)TOK*NBCP/4) return;
    size_t i = i4*4;
    float4 s = *(const float4*)(part + i);
    #pragma unroll
    for (int z=1; z<KSPL2; z++){
        float4 v = *(const float4*)(part + (size_t)z*TOK*NBCP + i);
        s.x += v.x; s.y += v.y; s.z += v.z; s.w += v.w;
    }
    int col = (int)(i % NBCP);
    int t   = (int)(i / NBCP);
    if (col < 256) {
        *(float4*)(outBC + (size_t)t*NBC + col) = s;
    } else if (col < NBC) {
        int h = col - 256;
        float e[4] = {s.x, s.y, s.z, s.w};
        #pragma unroll
        for (int u=0;u<4;u++){
            float xv = e[u] + dt_bias[h+u];
            float sp = (xv > 20.f) ? xv : log1pf(expf(xv));
            e[u] = fminf(fmaxf(sp, 0.f), 100.f);
        }
        float4 o; o.x=e[0]; o.y=e[1]; o.z=e[2]; o.w=e[3];
        *(float4*)(dtbuf + (size_t)t*NUM_HEADS + h) = o;
    }
}

// ---------------- fused prep: x->(xhi,xlo), w1->bf16 (rows 0..10240), wbc->(hi,lo) --
#define N4A ((size_t)TOK*HIDDEN/4)
#define N4B ((size_t)PROJ_PAD*HIDDEN/4)
#define N4C ((size_t)NBCP*HIDDEN/4)
__global__ __launch_bounds__(256) void prep_kernel(const float* __restrict__ x,
                                                   const float* __restrict__ in_w,
                                                   unsigned short* __restrict__ xhi,
                                                   unsigned short* __restrict__ xlo,
                                                   unsigned short* __restrict__ w1b,
                                                   unsigned short* __restrict__ wbc_hi,
                                                   unsigned short* __restrict__ wbc_lo) {
    size_t gid = (size_t)blockIdx.x*256 + threadIdx.x;
    if (gid < N4A) {
        size_t i = gid*4;
        float4 v = *(const float4*)(x + i);
        float e[4] = {v.x, v.y, v.z, v.w};
        ushort4 h, l;
        unsigned short* hp = (unsigned short*)&h;
        unsigned short* lp = (unsigned short*)&l;
        #pragma unroll
        for (int u=0;u<4;u++){
            unsigned short hv = f2bf(e[u]);
            hp[u] = hv;
            lp[u] = f2bf(e[u] - bf2f(hv));
        }
        *(ushort4*)(xhi + i) = h;
        *(ushort4*)(xlo + i) = l;
    } else if (gid < N4A + N4B) {
        size_t i = (gid - N4A)*4;
        float4 v = *(const float4*)(in_w + i);
        ushort4 o;
        o.x=f2bf(v.x); o.y=f2bf(v.y); o.z=f2bf(v.z); o.w=f2bf(v.w);
        *(ushort4*)(w1b + i) = o;
    } else {
        size_t j = gid - N4A - N4B;
        size_t i = j*4;
        int row = (int)(i / HIDDEN);
        int kk  = (int)(i % HIDDEN);
        ushort4 h, l;
        h.x=h.y=h.z=h.w=0; l.x=l.y=l.z=l.w=0;
        if (row < NBC){
            float4 v = *(const float4*)(in_w + (size_t)(2*INTER + row)*HIDDEN + kk);
            float e[4] = {v.x, v.y, v.z, v.w};
            unsigned short* hp = (unsigned short*)&h;
            unsigned short* lp = (unsigned short*)&l;
            #pragma unroll
            for (int u=0;u<4;u++){
                unsigned short hv = f2bf(e[u]);
                hp[u] = hv;
                lp[u] = f2bf(e[u] - bf2f(hv));
            }
        }
        *(ushort4*)(wbc_hi + i) = h;
        *(ushort4*)(wbc_lo + i) = l;
    }
}

// ---------------- cvt for w2 --------------------------------------------------------
__global__ __launch_bounds__(256) void cvt_bf16(const float* __restrict__ in,
                                                unsigned short* __restrict__ out, size_t n4){
    size_t i4 = (size_t)blockIdx.x*256 + threadIdx.x;
    if (i4 >= n4) return;
    size_t i = i4*4;
    float4 v = *(const float4*)(in+i);
    ushort4 o; o.x=f2bf(v.x); o.y=f2bf(v.y); o.z=f2bf(v.z); o.w=f2bf(v.w);
    *(ushort4*)(out+i) = o;
}

// ---------------- fused conv: XT part + B/C part (BT, Cb, fp32 BC) ------------------
__global__ __launch_bounds__(256) void conv_fused(const unsigned short* __restrict__ projb,
                                                  const float* __restrict__ projBC,
                                                  const float* __restrict__ cw,
                                                  const float* __restrict__ cb,
                                                  unsigned short* __restrict__ XT,
                                                  float* __restrict__ xBC_BC,
                                                  unsigned short* __restrict__ BT,
                                                  unsigned short* __restrict__ Cb) {
    __shared__ unsigned short raw[68][66];
    int bid = blockIdx.x;
    int tid = threadIdx.x;
    if (bid < (TOK/64)*(INTER/64)) {
        int bx = bid & 63, by = bid >> 6;
        int t0 = bx * 64, d0 = by * 64;
        int b  = t0 / SEQ;
        int s0 = t0 % SEQ;
        for (int f = tid; f < 67*8; f += 256){
            int r = f >> 3, g = f & 7;
            int sp = s0 - 3 + r;
            uint4 v;
            if (sp >= 0) v = *(const uint4*)(projb + ((size_t)(b*SEQ+sp))*PROJ_PAD + INTER + d0 + g*8);
            else { v.x=0u; v.y=0u; v.z=0u; v.w=0u; }
            unsigned int* dst = (unsigned int*)&raw[r][g*8];
            dst[0]=v.x; dst[1]=v.y; dst[2]=v.z; dst[3]=v.w;
        }
        __syncthreads();
        int t = tid & 63, dg = tid >> 6;
        #pragma unroll
        for (int dd = 0; dd < 16; dd++){
            int d = dg*16 + dd;
            float acc = cb[d0+d];
            #pragma unroll
            for (int j=0;j<CONV_K;j++)
                acc += cw[(d0+d)*CONV_K+j] * bf2f(raw[t+j][d]);
            float val = acc/(1.f+expf(-acc));
            XT[((size_t)(b*INTER + d0 + d))*SEQ + s0 + t] = f2bf(val);
        }
    } else {
        int idx = (bid - (TOK/64)*(INTER/64))*256 + tid;
        if (idx >= TOK*256) return;
        int d = idx & 255;
        int t = idx >> 8;
        int b = t / SEQ, sl = t % SEQ;
        int dc = INTER + d;
        float acc = cb[dc];
        #pragma unroll
        for (int j=0;j<CONV_K;j++){
            int sp = sl - (CONV_K-1) + j;
            if (sp >= 0)
                acc += cw[dc*CONV_K+j] * projBC[((size_t)(b*SEQ+sp))*NBC + d];
        }
        float val = acc / (1.f + expf(-acc));
        xBC_BC[(size_t)t*256 + d] = val;
        if (d < 128)
            BT[((size_t)(b*128 + d))*SEQ + sl] = f2bf(val);
        else
            Cb[(size_t)t*128 + (d-128)] = f2bf(val);
    }
}

// ---------------- per-chunk inclusive cumsum of dA = A*dt ---------------------------
__global__ __launch_bounds__(256) void cumsum_kernel(const float* __restrict__ dtbuf,
                                                     const float* __restrict__ A_log,
                                                     float* __restrict__ A_cum) {
    int c = blockIdx.x, h = blockIdx.y, b = blockIdx.z;
    int l = threadIdx.x;
    float A = -expf(A_log[h]);
    float v = A * dtbuf[(size_t)(b*SEQ + c*CHUNK + l)*NUM_HEADS + h];
    __shared__ float buf[CHUNK];
    buf[l] = v;
    __syncthreads();
    for (int off=1; off<CHUNK; off<<=1){
        float t = (l>=off) ? buf[l-off] : 0.f;
        __syncthreads();
        buf[l] += t;
        __syncthreads();
    }
    A_cum[((size_t)b*NUM_HEADS + h)*SEQ + c*CHUNK + l] = buf[l];
}

// ---------------- G[l][s] = C[l] . B[s]  (head-shared), bf16, l-major ---------------
__global__ __launch_bounds__(256) void g_kernel(const float* __restrict__ xBC_BC,
                                                unsigned short* __restrict__ G) {
    int p = blockIdx.x, c = blockIdx.y, b = blockIdx.z;
    int lt = 0, a0 = 0;
    while (a0 + lt + 1 <= p) { a0 += lt + 1; lt++; }
    int st = p - a0;
    int l0 = lt*64, s0 = st*64;
    __shared__ float Cs[64][68];
    __shared__ float Bs[64][68];
    int tid = threadIdx.x, ty = tid >> 4, tx = tid & 15;
    float acc[4][4];
    #pragma unroll
    for (int i=0;i<4;i++)
        #pragma unroll
        for (int j=0;j<4;j++) acc[i][j]=0.f;

    size_t rowC = ((size_t)(b*SEQ + c*CHUNK + l0))*256 + 128;
    size_t rowB = ((size_t)(b*SEQ + c*CHUNK + s0))*256;
    for (int kc=0; kc<2; kc++){
        #pragma unroll
        for (int it=0; it<4; it++){
            int f = tid + it*256;
            int r = f >> 4, c4 = f & 15;
            float4 cv = *(const float4*)(xBC_BC + rowC + (size_t)r*256 + kc*64 + c4*4);
            float4 bv = *(const float4*)(xBC_BC + rowB + (size_t)r*256 + kc*64 + c4*4);
            *(float4*)&Cs[r][c4*4] = cv;
            *(float4*)&Bs[r][c4*4] = bv;
        }
        __syncthreads();
        #pragma unroll 8
        for (int k=0;k<64;k++){
            float a[4], bb[4];
            #pragma unroll
            for (int i=0;i<4;i++) a[i] = Cs[ty*4+i][k];
            #pragma unroll
            for (int j=0;j<4;j++) bb[j] = Bs[tx*4+j][k];
            #pragma unroll
            for (int i=0;i<4;i++)
                #pragma unroll
                for (int j=0;j<4;j++) acc[i][j] += a[i]*bb[j];
        }
        __syncthreads();
    }
    size_t Gb = ((size_t)(b*NC + c)) << 16;
    #pragma unroll
    for (int i=0;i<4;i++){
        ushort4 g4;
        g4.x = f2bf(acc[i][0]); g4.y = f2bf(acc[i][1]);
        g4.z = f2bf(acc[i][2]); g4.w = f2bf(acc[i][3]);
        *(ushort4*)(G + Gb + (size_t)(l0 + ty*4 + i)*256 + s0 + tx*4) = g4;
    }
}

// ---------------- statesT[p][n] = sum_l (XT[p][l]*w[l]) * BT[n][l]  (MFMA) ----------
// weight folded into the 64-row X operand (half the staging VALU); B via pure gld16.
// output bf16.
__global__ __launch_bounds__(256) void states_mfma(const unsigned short* __restrict__ XT,
                                                   const unsigned short* __restrict__ BT,
                                                   const float* __restrict__ dtbuf,
                                                   const float* __restrict__ A_cum,
                                                   unsigned short* __restrict__ statesT) {
    int c = blockIdx.x, h = blockIdx.y, b = blockIdx.z;
    __shared__ unsigned short Asx[64][64];   // Xw tile [p][l] (reg-staged, weighted)
    __shared__ unsigned short Bs[128][64];   // B tile  [n][l] (gld16, swizzled src)
    __shared__ float wl[CHUNK];
    int tid = threadIdx.x, lane = tid & 63, wid = tid >> 6;
    {
        const float* ac = A_cum + ((size_t)(b*NUM_HEADS+h))*SEQ + c*CHUNK;
        float Alast = ac[CHUNK-1];
        wl[tid] = expf(Alast - ac[tid]) * dtbuf[((size_t)(b*SEQ + c*CHUNK + tid))*NUM_HEADS + h];
    }
    __syncthreads();
    f32x4 acc[4][2];
    #pragma unroll
    for (int i=0;i<4;i++)
        #pragma unroll
        for (int j=0;j<2;j++) acc[i][j] = (f32x4){0.f,0.f,0.f,0.f};

    for (int kc = 0; kc < 4; kc++){
        int lbase = kc*64;
        // B: 128 rows via gld16 (4 waves x 4 chunks x 8 rows)
        #pragma unroll
        for (int q=0;q<4;q++){
            int brow = (wid*4+q)*8;
            int row  = brow + (lane>>3);
            int sl   = (lane&7) ^ (row & 7);
            gld16(BT + ((size_t)(b*128 + row))*SEQ + c*CHUNK + lbase + sl*8, &Bs[brow][0]);
        }
        // Xw: 64 rows x 64 cols reg-staged with weight
        #pragma unroll
        for (int it=0; it<2; it++){
            int f = tid + it*256;
            int r = f >> 3, g = f & 7;
            uint4 v = *(const uint4*)(XT + ((size_t)(b*INTER + h*HEAD_DIM + r))*SEQ + c*CHUNK + lbase + g*8);
            float e[8]; unpack8(v, e);
            unsigned short o[8];
            #pragma unroll
            for (int u=0;u<8;u++) o[u] = f2bf(e[u] * wl[lbase + g*8 + u]);
            int slot = g ^ (r & 7);
            *(ushort4*)&Asx[r][slot*8]   = *(ushort4*)&o[0];
            *(ushort4*)&Asx[r][slot*8+4] = *(ushort4*)&o[4];
        }
        __syncthreads();
        #pragma unroll
        for (int kk=0; kk<64; kk+=32){
            bf16x8 a[4], bb[2];
            #pragma unroll
            for (int i=0;i<4;i++){
                int row = i*16 + (lane&15);
                int slot = ((kk>>3)+(lane>>4)) ^ (row&7);
                a[i] = *(const bf16x8*)&Asx[row][slot*8];
            }
            #pragma unroll
            for (int j=0;j<2;j++){
                int row = wid*32 + j*16 + (lane&15);
                int slot = ((kk>>3)+(lane>>4)) ^ (row&7);
                bb[j] = *(const bf16x8*)&Bs[row][slot*8];
            }
            #pragma unroll
            for (int i=0;i<4;i++)
                #pragma unroll
                for (int j=0;j<2;j++)
                    acc[i][j] = MFMA16(a[i], bb[j], acc[i][j]);
        }
        __syncthreads();
    }
    size_t sb = ((size_t)((b*NC + c)*NUM_HEADS + h))*(HEAD_DIM*STATE);
    #pragma unroll
    for (int i=0;i<4;i++){
        #pragma unroll
        for (int j=0;j<2;j++){
            int n = wid*32 + j*16 + (lane&15);
            int p0 = i*16 + (lane>>4)*4;
            #pragma unroll
            for (int r=0;r<4;r++)
                statesT[sb + (size_t)(p0+r)*128 + n] = f2bf(acc[i][j][r]);
        }
    }
}

// ---------------- inter-chunk recurrence (in place, bf16) ---------------------------
__global__ __launch_bounds__(256) void recur_kernel(const float* __restrict__ A_cum,
                                                    unsigned short* __restrict__ states) {
    int h = blockIdx.x, b = blockIdx.y;
    int tid = threadIdx.x;
    float Srun[32];
    #pragma unroll
    for (int i=0;i<32;i++) Srun[i]=0.f;
    const float* acum = A_cum + ((size_t)b*NUM_HEADS + h)*SEQ;
    for (int c=0;c<NC;c++){
        float alast = acum[c*CHUNK + CHUNK-1];
        float dec = expf(alast);
        size_t base = ((size_t)((b*NC + c)*NUM_HEADS + h))*(HEAD_DIM*STATE);
        #pragma unroll
        for (int i=0;i<32;i++){
            size_t idx = base + (size_t)tid + (size_t)i*256;
            float raw = bf2f(states[idx]);
            states[idx] = f2bf(Srun[i]);
            Srun[i] = Srun[i]*dec + raw;
        }
    }
}

// ---------------- Y = e_l*(Cs @ St^T) + Gw @ Xs^T + D*X   (MFMA) --------------------
// Cs from bf16 Cb (gld16), St from bf16 statesT (gld16) — staging VALU-free.
__global__ __launch_bounds__(256) void yscan_mfma(const unsigned short* __restrict__ G,
                                                  const unsigned short* __restrict__ Cb,
                                                  const unsigned short* __restrict__ XT,
                                                  const float* __restrict__ dtbuf,
                                                  const float* __restrict__ A_cum,
                                                  const unsigned short* __restrict__ statesT,
                                                  const float* __restrict__ Dvec,
                                                  unsigned short* __restrict__ projb) {
    int xb = blockIdx.x;
    int c = xb >> 2, lt = xb & 3;
    int h = blockIdx.y, b = blockIdx.z;
    int l0 = lt*64;
    __shared__ __align__(16) char pool[32768];
    unsigned short (*Cs)[128] = (unsigned short(*)[128])pool;            // [l][n]
    unsigned short (*St)[128] = (unsigned short(*)[128])(pool + 16384);  // [p][n]
    unsigned short (*Gw)[64]  = (unsigned short(*)[64])pool;             // [l][s]
    unsigned short (*Xs)[64]  = (unsigned short(*)[64])(pool + 8192);    // [p][s]
    float (*Ot)[68]           = (float(*)[68])pool;
    __shared__ float ac[CHUNK], dts[CHUNK];
    int tid = threadIdx.x, lane = tid & 63, wid = tid >> 6;
    ac[tid]  = A_cum[((size_t)(b*NUM_HEADS + h))*SEQ + c*CHUNK + tid];
    dts[tid] = dtbuf[((size_t)(b*SEQ + c*CHUNK + tid))*NUM_HEADS + h];

    // ---- phase 1 staging: Cs (64 rows x 128) and St (64 rows x 128) via gld16 ----
    size_t stb = ((size_t)((b*NC + c)*NUM_HEADS + h))*(HEAD_DIM*STATE);
    #pragma unroll
    for (int q=0;q<4;q++){
        int brow = (wid*4+q)*4;
        int row  = brow + (lane>>4);
        int sl   = (lane&15) ^ (row & 7);
        gld16(Cb + ((size_t)(b*SEQ + c*CHUNK + l0 + row))*128 + sl*8, &Cs[brow][0]);
        gld16(statesT + stb + (size_t)row*128 + sl*8, &St[brow][0]);
    }
    __syncthreads();

    f32x4 acc1[4];
    #pragma unroll
    for (int j=0;j<4;j++) acc1[j] = (f32x4){0.f,0.f,0.f,0.f};
    #pragma unroll
    for (int kk=0; kk<128; kk+=32){
        int arow = wid*16 + (lane&15);
        int aslot = ((kk>>3)+(lane>>4)) ^ (arow&7);
        bf16x8 a = *(const bf16x8*)&Cs[arow][aslot*8];
        #pragma unroll
        for (int j=0;j<4;j++){
            int brow = j*16 + (lane&15);
            int bslot = ((kk>>3)+(lane>>4)) ^ (brow&7);
            bf16x8 bb = *(const bf16x8*)&St[brow][bslot*8];
            acc1[j] = MFMA16(a, bb, acc1[j]);
        }
    }
    float el[4];
    #pragma unroll
    for (int r=0;r<4;r++) el[r] = expf(ac[l0 + wid*16 + (lane>>4)*4 + r]);
    float master[4][4];
    #pragma unroll
    for (int j=0;j<4;j++)
        #pragma unroll
        for (int r=0;r<4;r++) master[j][r] = acc1[j][r]*el[r];
    __syncthreads();

    size_t Gb = ((size_t)(b*NC + c)) << 16;
    f32x4 acc2[4];
    #pragma unroll
    for (int j=0;j<4;j++) acc2[j] = (f32x4){0.f,0.f,0.f,0.f};
    for (int st=0; st<=lt; st++){
        int s0 = st*64;
        #pragma unroll
        for (int it=0; it<2; it++){
            int f = tid + it*256;
            int r = f >> 3, g = f & 7;
            uint4 v = *(const uint4*)(G + Gb + (size_t)(l0 + r)*256 + s0 + g*8);
            float e[8]; unpack8(v, e);
            float acl = ac[l0 + r];
            unsigned short o[8];
            #pragma unroll
            for (int u=0;u<8;u++){
                int s = s0 + g*8 + u;
                float w = (s <= l0 + r) ? expf(acl - ac[s])*dts[s] : 0.f;
                o[u] = f2bf(e[u]*w);
            }
            int slot = g ^ (r&7);
            *(ushort4*)&Gw[r][slot*8]   = *(ushort4*)&o[0];
            *(ushort4*)&Gw[r][slot*8+4] = *(ushort4*)&o[4];
        }
        #pragma unroll
        for (int q=0;q<2;q++){
            int brow = (wid*2+q)*8;
            int row  = brow + (lane>>3);
            int sl   = (lane&7) ^ (row&7);
            gld16(XT + ((size_t)(b*INTER + h*HEAD_DIM + row))*SEQ + c*CHUNK + s0 + sl*8,
                  &Xs[brow][0]);
        }
        __syncthreads();
        #pragma unroll
        for (int kk=0; kk<64; kk+=32){
            int arow = wid*16 + (lane&15);
            int aslot = ((kk>>3)+(lane>>4)) ^ (arow&7);
            bf16x8 a = *(const bf16x8*)&Gw[arow][aslot*8];
            #pragma unroll
            for (int j=0;j<4;j++){
                int brow = j*16 + (lane&15);
                int bslot = ((kk>>3)+(lane>>4)) ^ (brow&7);
                bf16x8 bb = *(const bf16x8*)&Xs[brow][bslot*8];
                acc2[j] = MFMA16(a, bb, acc2[j]);
            }
        }
        if (st < lt) __syncthreads();
    }

    float Dh = Dvec[h];
    #pragma unroll
    for (int j=0;j<4;j++){
        int p = j*16 + (lane&15);
        #pragma unroll
        for (int r=0;r<4;r++){
            int sl_ = wid*16 + (lane>>4)*4 + r;
            int slot = (sl_>>3) ^ (p&7);
            float xv = bf2f(Xs[p][slot*8 + (sl_&7)]);
            master[j][r] += acc2[j][r] + Dh*xv;
        }
    }
    __syncthreads();

    #pragma unroll
    for (int j=0;j<4;j++){
        int p = j*16 + (lane&15);
        #pragma unroll
        for (int r=0;r<4;r++)
            Ot[wid*16 + (lane>>4)*4 + r][p] = master[j][r];
    }
    __syncthreads();
    #pragma unroll
    for (int it=0; it<4; it++){
        int f = tid + it*256;
        int r = f >> 4, c4 = f & 15;
        ushort4 o;
        o.x = f2bf(Ot[r][c4*4+0]); o.y = f2bf(Ot[r][c4*4+1]);
        o.z = f2bf(Ot[r][c4*4+2]); o.w = f2bf(Ot[r][c4*4+3]);
        *(ushort4*)(projb + ((size_t)(b*SEQ + c*CHUNK + l0 + r))*PROJ_PAD + INTER + h*HEAD_DIM + c4*4) = o;
    }
}

// ---------------- gate * silu + RMSNorm -> packed bf16 y ----------------------------
__global__ __launch_bounds__(256) void gate_norm_kernel(const unsigned short* __restrict__ projb,
                                                        const float* __restrict__ normw,
                                                        unsigned short* __restrict__ yb) {
    int t = blockIdx.x;
    int tid = threadIdx.x;
    const unsigned short* row = projb + (size_t)t*PROJ_PAD;
    __shared__ float red[4];
    float vals[20];
    float ss = 0.f;
    #pragma unroll
    for (int i=0;i<5;i++){
        int j = (tid + i*256)*4;
        ushort4 g4 = *(const ushort4*)(row + j);
        ushort4 y4 = *(const ushort4*)(row + INTER + j);
        #pragma unroll
        for (int u=0;u<4;u++){
            float g = bf2f(((const unsigned short*)&g4)[u]);
            float y = bf2f(((const unsigned short*)&y4)[u]);
            float gv = g / (1.f + expf(-g));
            float v = y * gv;
            vals[i*4+u] = v;
            ss += v*v;
        }
    }
    #pragma unroll
    for (int off=32; off; off>>=1) ss += __shfl_xor(ss, off);
    if ((tid&63)==0) red[tid>>6] = ss;
    __syncthreads();
    float tot = red[0]+red[1]+red[2]+red[3];
    float inv = rsqrtf(tot/(float)INTER + EPS);
    #pragma unroll
    for (int i=0;i<5;i++){
        int j = (tid + i*256)*4;
        ushort4 o;
        o.x = f2bf(vals[i*4+0] * inv * normw[j+0]);
        o.y = f2bf(vals[i*4+1] * inv * normw[j+1]);
        o.z = f2bf(vals[i*4+2] * inv * normw[j+2]);
        o.w = f2bf(vals[i*4+3] * inv * normw[j+3]);
        *(ushort4*)(yb + (size_t)t*INTER + j) = o;
    }
}

// ------------------------------------------------------------------------------------
extern "C" void kernel_launch(void* const* d_in, const int* in_sizes, int n_in,
                              void* d_out, int out_size, void* d_ws, size_t ws_size,
                              hipStream_t stream) {
    const float* x        = (const float*)d_in[0];
    const float* in_w     = (const float*)d_in[1];
    const float* conv_w   = (const float*)d_in[2];
    const float* conv_b   = (const float*)d_in[3];
    const float* A_log    = (const float*)d_in[4];
    const float* Dvec     = (const float*)d_in[5];
    const float* dt_bias  = (const float*)d_in[6];
    const float* norm_w   = (const float*)d_in[7];
    const float* out_w    = (const float*)d_in[8];
    float* out = (float*)d_out;
    (void)ws_size; (void)n_in; (void)in_sizes; (void)out_size;

    // ---- fixed workspace (bytes) ~163 MB ----
    const size_t PROJB   = (size_t)TOK*PROJ_PAD*2;          // 83.9 MB
    const size_t PROJBCB = (size_t)TOK*NBC*4;               //  5.5 MB
    const size_t XTB     = (size_t)TOK*INTER*2;             // 41.9 MB
    const size_t XBCBCB  = (size_t)TOK*256*4;               //  4.2 MB
    const size_t BTB     = (size_t)BATCH*128*SEQ*2;         //  1.05 MB
    const size_t CBB     = (size_t)TOK*128*2;               //  1.05 MB
    const size_t GBYTES  = (size_t)BATCH*NC*CHUNK*CHUNK*2;  //  2.1 MB
    const size_t DTB     = (size_t)TOK*NUM_HEADS*4;         //  1.3 MB
    const size_t ACUMB   = DTB;
    const size_t STB     = (size_t)BATCH*NC*NUM_HEADS*HEAD_DIM*STATE*2; // 21.0 MB (bf16)
    // ---- transient region ----
    const size_t XHB   = (size_t)TOK*HIDDEN*2;              // 21.0 MB
    const size_t WBCB  = (size_t)NBCP*HIDDEN*2;             //  1.97 MB
    const size_t YBB   = (size_t)TOK*INTER*2;               // 41.9 MB

    char* base = (char*)d_ws;
    size_t off = 0;
    unsigned short* projb  = (unsigned short*)(base + off); off += PROJB;
    float* projBC          = (float*)(base + off);          off += PROJBCB;
    unsigned short* XTp    = (unsigned short*)(base + off); off += XTB;
    float* xBC_BC          = (float*)(base + off);          off += XBCBCB;
    unsigned short* BTp    = (unsigned short*)(base + off); off += BTB;
    unsigned short* Cbp    = (unsigned short*)(base + off); off += CBB;
    unsigned short* Gp     = (unsigned short*)(base + off); off += GBYTES;
    float* dtbuf           = (float*)(base + off);          off += DTB;
    float* A_cum           = (float*)(base + off);          off += ACUMB;
    unsigned short* statesT= (unsigned short*)(base + off); off += STB;
    char*  T               = base + off;
    // phase A: [xhi | xlo | wbc_hi | wbc_lo | w1b (bcpart aliases w1b)]
    unsigned short* xhi    = (unsigned short*)T;
    unsigned short* xlo    = (unsigned short*)(T + XHB);
    unsigned short* wbc_hi = (unsigned short*)(T + 2*XHB);
    unsigned short* wbc_lo = (unsigned short*)(T + 2*XHB + WBCB);
    unsigned short* w1b    = (unsigned short*)(T + 2*XHB + 2*WBCB);
    float* bcpart          = (float*)w1b;     // 50.3 MB <= w1b's 52.4 MB
    // phase B: yb aliases [xhi|xlo]; w2b aliases [wbc.., w1b head]
    unsigned short* yb     = (unsigned short*)T;
    unsigned short* w2b    = (unsigned short*)(T + YBB);

    const size_t W2_E = (size_t)HIDDEN*INTER;

    // 1. fused prep
    {
        unsigned total_blocks = (unsigned)((N4A + N4B + N4C) / 256);
        prep_kernel<<<total_blocks, 256, 0, stream>>>(x, in_w, xhi, xlo, w1b, wbc_hi, wbc_lo);
    }
    // 2. proj(gate,X) = x @ w1^T  (bf16 MFMA, bf16 out, XCD swizzle)
    gemm_bf16<true><<<dim3(PROJ_PAD/128, TOK/128), 256, 0, stream>>>(xhi, HIDDEN, w1b, HIDDEN,
                                                                     projb, PROJ_PAD, HIDDEN);
    // 3. B/C/dt via bf16 hi/lo split-K MFMA; partials alias w1b
    bc_splitk_mfma<<<dim3(NBCP/128, TOK/128, KSPL2), 256, 0, stream>>>(xhi, xlo, wbc_hi, wbc_lo, bcpart);
    reduce_bc2<<<(unsigned)(((size_t)TOK*NBCP/4)/256), 256, 0, stream>>>(bcpart, dt_bias, projBC, dtbuf);
    // 4. fused conv (XT + B/C -> fp32 BC, BT, Cb)
    conv_fused<<<(TOK/64)*(INTER/64) + TOK, 256, 0, stream>>>(projb, projBC, conv_w, conv_b,
                                                              XTp, xBC_BC, BTp, Cbp);
    // 5. w2 conversion (partials dead after reduce)
    cvt_bf16<<<(unsigned)((W2_E/4+255)/256), 256, 0, stream>>>(out_w, w2b, W2_E/4);
    // 6. cumsum
    cumsum_kernel<<<dim3(NC, NUM_HEADS, BATCH), 256, 0, stream>>>(dtbuf, A_log, A_cum);
    // 7. G = C.B^T (head-shared), [l][s]
    g_kernel<<<dim3(10, NC, BATCH), 256, 0, stream>>>(xBC_BC, Gp);
    // 8. per-chunk states (MFMA, weight-on-X, bf16 out)
    states_mfma<<<dim3(NC, NUM_HEADS, BATCH), 256, 0, stream>>>(XTp, BTp, dtbuf, A_cum, statesT);
    // 9. inter-chunk recurrence (bf16 in place)
    recur_kernel<<<dim3(NUM_HEADS, BATCH), 256, 0, stream>>>(A_cum, statesT);
    // 10. Y (MFMA, gld16-staged Cs/St) -> bf16 into projb
    yscan_mfma<<<dim3(NC*4, NUM_HEADS, BATCH), 256, 0, stream>>>(Gp, Cbp, XTp, dtbuf, A_cum,
                                                                 statesT, Dvec, projb);
    // 11. gate + RMSNorm -> bf16 y
    gate_norm_kernel<<<TOK, 256, 0, stream>>>(projb, norm_w, yb);
    // 12. out = y @ out_w^T  (bf16 MFMA, fp32 out, XCD swizzle)
    gemm_bf16<false><<<dim3(HIDDEN/128, TOK/128), 256, 0, stream>>>(yb, INTER, w2b, INTER,
                                                                    out, HIDDEN, INTER);
}

// Round 12
// 710.259 us; speedup vs baseline: 1.3060x; 1.0233x over previous
//
#include <hip/hip_runtime.h>
#include <hip/hip_bf16.h>
#include <math.h>

#define HIDDEN   2560
#define NUM_HEADS 80
#define HEAD_DIM 64
#define STATE    128
#define CONV_K   4
#define CHUNK    256
#define INTER    (2*HIDDEN)                 // 5120
#define CONV_DIM (INTER + 2*STATE)          // 5376
#define PROJ     (INTER + CONV_DIM + NUM_HEADS) // 10576
#define PROJ_PAD 10240                      // gate + X only (80*128)
#define NBC      336                        // B,C (256) + dt (80) columns
#define NBCP     384                        // padded to 3*128
#define EPS      1e-5f

#define BATCH 2
#define SEQ   2048
#define TOK   (BATCH*SEQ)                   // 4096
#define NC    (SEQ/CHUNK)                   // 8
#define KSPL2 8
#define KCH2  (HIDDEN/KSPL2)                // 320

typedef __attribute__((ext_vector_type(8))) short bf16x8;
typedef __attribute__((ext_vector_type(4))) float f32x4;

#define MFMA16(a,b,c) __builtin_amdgcn_mfma_f32_16x16x32_bf16((a),(b),(c),0,0,0)

__device__ __forceinline__ unsigned short f2bf(float f){
    union{float f;unsigned u;}v; v.f=f;
    unsigned r = v.u + 0x7fffu + ((v.u>>16)&1u);
    return (unsigned short)(r>>16);
}
__device__ __forceinline__ float bf2f(unsigned short s){
    union{unsigned u;float f;}v; v.u = ((unsigned)s)<<16; return v.f;
}
__device__ __forceinline__ void unpack8(uint4 u, float* e){
    e[0]=bf2f((unsigned short)(u.x&0xffff)); e[1]=bf2f((unsigned short)(u.x>>16));
    e[2]=bf2f((unsigned short)(u.y&0xffff)); e[3]=bf2f((unsigned short)(u.y>>16));
    e[4]=bf2f((unsigned short)(u.z&0xffff)); e[5]=bf2f((unsigned short)(u.z>>16));
    e[6]=bf2f((unsigned short)(u.w&0xffff)); e[7]=bf2f((unsigned short)(u.w>>16));
}

__device__ __forceinline__ void gld16(const void* g, void* l){
    __builtin_amdgcn_global_load_lds((const __attribute__((address_space(1))) void*)g,
                                     (__attribute__((address_space(3))) void*)l, 16, 0, 0);
}

// =============== 128x128 bf16 MFMA GEMM (NT) ==========================================
template<bool BF16OUT>
__global__ __launch_bounds__(256) void gemm_bf16(const unsigned short* __restrict__ A, int lda,
                                                 const unsigned short* __restrict__ B, int ldb,
                                                 void* __restrict__ Cv, int ldc, int K) {
    __shared__ unsigned short As[128][64];
    __shared__ unsigned short Bs[128][64];
    int tid = threadIdx.x;
    int lane = tid & 63, wid = tid >> 6;
    int wr = wid >> 1, wc = wid & 1;

    int bm, bn;
    if ((gridDim.y & 7) == 0) {
        int bid   = blockIdx.y * gridDim.x + blockIdx.x;
        int xcd   = bid & 7;
        int local = bid >> 3;
        int mrows = gridDim.y >> 3;
        bm = (xcd * mrows + (local % mrows)) * 128;
        bn = (local / mrows) * 128;
    } else {
        bm = blockIdx.y * 128;
        bn = blockIdx.x * 128;
    }

    f32x4 acc[4][4];
    #pragma unroll
    for (int i=0;i<4;i++)
        #pragma unroll
        for (int j=0;j<4;j++) acc[i][j] = (f32x4){0.f,0.f,0.f,0.f};

    int srow_off = lane >> 3;
    int sslot    = lane & 7;

    for (int k0 = 0; k0 < K; k0 += 64) {
        #pragma unroll
        for (int q=0;q<4;q++){
            int brow = (wid*4+q)*8;
            int row  = brow + srow_off;
            int sl   = sslot ^ (row & 7);
            gld16(A + (size_t)(bm + row)*lda + k0 + sl*8, &As[brow][0]);
            gld16(B + (size_t)(bn + row)*ldb + k0 + sl*8, &Bs[brow][0]);
        }
        __syncthreads();
        #pragma unroll
        for (int kk=0; kk<64; kk+=32){
            bf16x8 a[4], b[4];
            #pragma unroll
            for (int i=0;i<4;i++){
                int row = wr*64 + i*16 + (lane&15);
                int slot = ((kk>>3) + (lane>>4)) ^ (row & 7);
                a[i] = *(const bf16x8*)&As[row][slot*8];
            }
            #pragma unroll
            for (int j=0;j<4;j++){
                int row = wc*64 + j*16 + (lane&15);
                int slot = ((kk>>3) + (lane>>4)) ^ (row & 7);
                b[j] = *(const bf16x8*)&Bs[row][slot*8];
            }
            #pragma unroll
            for (int i=0;i<4;i++)
                #pragma unroll
                for (int j=0;j<4;j++)
                    acc[i][j] = MFMA16(a[i], b[j], acc[i][j]);
        }
        __syncthreads();
    }
    #pragma unroll
    for (int i=0;i<4;i++){
        int row0 = bm + wr*64 + i*16 + (lane>>4)*4;
        #pragma unroll
        for (int j=0;j<4;j++){
            int col = bn + wc*64 + j*16 + (lane&15);
            #pragma unroll
            for (int r=0;r<4;r++){
                if (BF16OUT)
                    ((unsigned short*)Cv)[(size_t)(row0+r)*ldc + col] = f2bf(acc[i][j][r]);
                else
                    ((float*)Cv)[(size_t)(row0+r)*ldc + col] = acc[i][j][r];
            }
        }
    }
}

// =============== bf16 hi/lo split-K MFMA for B/C/dt (fp32-quality) ====================
__global__ __launch_bounds__(256) void bc_splitk_mfma(const unsigned short* __restrict__ xhi,
                                                      const unsigned short* __restrict__ xlo,
                                                      const unsigned short* __restrict__ whi,
                                                      const unsigned short* __restrict__ wlo,
                                                      float* __restrict__ Cpart) {
    __shared__ unsigned short As[128][64];
    __shared__ unsigned short Bs[128][64];
    int tid = threadIdx.x;
    int lane = tid & 63, wid = tid >> 6;
    int wr = wid >> 1, wc = wid & 1;
    int bn = blockIdx.x * 128, bm = blockIdx.y * 128, z = blockIdx.z;

    f32x4 acc[4][4];
    #pragma unroll
    for (int i=0;i<4;i++)
        #pragma unroll
        for (int j=0;j<4;j++) acc[i][j] = (f32x4){0.f,0.f,0.f,0.f};

    int srow_off = lane >> 3;
    int sslot    = lane & 7;

    for (int term = 0; term < 3; ++term){
        const unsigned short* A = (term==2) ? xlo : xhi;
        const unsigned short* B = (term==0) ? wlo : whi;
        for (int k0 = z*KCH2; k0 < z*KCH2 + KCH2; k0 += 64) {
            #pragma unroll
            for (int q=0;q<4;q++){
                int brow = (wid*4+q)*8;
                int row  = brow + srow_off;
                int sl   = sslot ^ (row & 7);
                gld16(A + (size_t)(bm + row)*HIDDEN + k0 + sl*8, &As[brow][0]);
                gld16(B + (size_t)(bn + row)*HIDDEN + k0 + sl*8, &Bs[brow][0]);
            }
            __syncthreads();
            #pragma unroll
            for (int kk=0; kk<64; kk+=32){
                bf16x8 a[4], b[4];
                #pragma unroll
                for (int i=0;i<4;i++){
                    int row = wr*64 + i*16 + (lane&15);
                    int slot = ((kk>>3) + (lane>>4)) ^ (row & 7);
                    a[i] = *(const bf16x8*)&As[row][slot*8];
                }
                #pragma unroll
                for (int j=0;j<4;j++){
                    int row = wc*64 + j*16 + (lane&15);
                    int slot = ((kk>>3) + (lane>>4)) ^ (row & 7);
                    b[j] = *(const bf16x8*)&Bs[row][slot*8];
                }
                #pragma unroll
                for (int i=0;i<4;i++)
                    #pragma unroll
                    for (int j=0;j<4;j++)
                        acc[i][j] = MFMA16(a[i], b[j], acc[i][j]);
            }
            __syncthreads();
        }
    }
    float* Cz = Cpart + (size_t)z*TOK*NBCP;
    #pragma unroll
    for (int i=0;i<4;i++){
        int row0 = bm + wr*64 + i*16 + (lane>>4)*4;
        #pragma unroll
        for (int j=0;j<4;j++){
            int col = bn + wc*64 + j*16 + (lane&15);
            #pragma unroll
            for (int r=0;r<4;r++)
                Cz[(size_t)(row0+r)*NBCP + col] = acc[i][j][r];
        }
    }
}

// fixed-order reduce over KSPL2 partials + fused dt softplus
__global__ __launch_bounds__(256) void reduce_bc2(const float* __restrict__ part,
                                                  const float* __restrict__ dt_bias,
                                                  float* __restrict__ outBC,
                                                  float* __restrict__ dtbuf) {
    size_t i4 = (size_t)blockIdx.x*256 + threadIdx.x;
    if (i4 >= (size_t)TOK*NBCP/4) return;
    size_t i = i4*4;
    float4 s = *(const float4*)(part + i);
    #pragma unroll
    for (int z=1; z<KSPL2; z++){
        float4 v = *(const float4*)(part + (size_t)z*TOK*NBCP + i);
        s.x += v.x; s.y += v.y; s.z += v.z; s.w += v.w;
    }
    int col = (int)(i % NBCP);
    int t   = (int)(i / NBCP);
    if (col < 256) {
        *(float4*)(outBC + (size_t)t*NBC + col) = s;
    } else if (col < NBC) {
        int h = col - 256;
        float e[4] = {s.x, s.y, s.z, s.w};
        #pragma unroll
        for (int u=0;u<4;u++){
            float xv = e[u] + dt_bias[h+u];
            float sp = (xv > 20.f) ? xv : log1pf(expf(xv));
            e[u] = fminf(fmaxf(sp, 0.f), 100.f);
        }
        float4 o; o.x=e[0]; o.y=e[1]; o.z=e[2]; o.w=e[3];
        *(float4*)(dtbuf + (size_t)t*NUM_HEADS + h) = o;
    }
}

// ---------------- fused prep: x->(xhi,xlo), w1->bf16, wbc->(hi,lo) ------------------
#define N4A ((size_t)TOK*HIDDEN/4)
#define N4B ((size_t)PROJ_PAD*HIDDEN/4)
#define N4C ((size_t)NBCP*HIDDEN/4)
__global__ __launch_bounds__(256) void prep_kernel(const float* __restrict__ x,
                                                   const float* __restrict__ in_w,
                                                   unsigned short* __restrict__ xhi,
                                                   unsigned short* __restrict__ xlo,
                                                   unsigned short* __restrict__ w1b,
                                                   unsigned short* __restrict__ wbc_hi,
                                                   unsigned short* __restrict__ wbc_lo) {
    size_t gid = (size_t)blockIdx.x*256 + threadIdx.x;
    if (gid < N4A) {
        size_t i = gid*4;
        float4 v = *(const float4*)(x + i);
        float e[4] = {v.x, v.y, v.z, v.w};
        ushort4 h, l;
        unsigned short* hp = (unsigned short*)&h;
        unsigned short* lp = (unsigned short*)&l;
        #pragma unroll
        for (int u=0;u<4;u++){
            unsigned short hv = f2bf(e[u]);
            hp[u] = hv;
            lp[u] = f2bf(e[u] - bf2f(hv));
        }
        *(ushort4*)(xhi + i) = h;
        *(ushort4*)(xlo + i) = l;
    } else if (gid < N4A + N4B) {
        size_t i = (gid - N4A)*4;
        float4 v = *(const float4*)(in_w + i);
        ushort4 o;
        o.x=f2bf(v.x); o.y=f2bf(v.y); o.z=f2bf(v.z); o.w=f2bf(v.w);
        *(ushort4*)(w1b + i) = o;
    } else {
        size_t j = gid - N4A - N4B;
        size_t i = j*4;
        int row = (int)(i / HIDDEN);
        int kk  = (int)(i % HIDDEN);
        ushort4 h, l;
        h.x=h.y=h.z=h.w=0; l.x=l.y=l.z=l.w=0;
        if (row < NBC){
            float4 v = *(const float4*)(in_w + (size_t)(2*INTER + row)*HIDDEN + kk);
            float e[4] = {v.x, v.y, v.z, v.w};
            unsigned short* hp = (unsigned short*)&h;
            unsigned short* lp = (unsigned short*)&l;
            #pragma unroll
            for (int u=0;u<4;u++){
                unsigned short hv = f2bf(e[u]);
                hp[u] = hv;
                lp[u] = f2bf(e[u] - bf2f(hv));
            }
        }
        *(ushort4*)(wbc_hi + i) = h;
        *(ushort4*)(wbc_lo + i) = l;
    }
}

// ---------------- fused conv: XT part + B/C part + w2 conversion --------------------
#define XBLK ((TOK/64)*(INTER/64))
#define W2BLK ((int)(((size_t)HIDDEN*INTER/4)/256))
__global__ __launch_bounds__(256) void conv_fused(const unsigned short* __restrict__ projb,
                                                  const float* __restrict__ projBC,
                                                  const float* __restrict__ cw,
                                                  const float* __restrict__ cb,
                                                  const float* __restrict__ out_w,
                                                  unsigned short* __restrict__ XT,
                                                  float* __restrict__ xBC_BC,
                                                  unsigned short* __restrict__ BT,
                                                  unsigned short* __restrict__ Cb,
                                                  unsigned short* __restrict__ w2b) {
    __shared__ unsigned short raw[68][66];
    int bid = blockIdx.x;
    int tid = threadIdx.x;
    if (bid < XBLK) {
        int bx = bid & 63, by = bid >> 6;
        int t0 = bx * 64, d0 = by * 64;
        int b  = t0 / SEQ;
        int s0 = t0 % SEQ;
        for (int f = tid; f < 67*8; f += 256){
            int r = f >> 3, g = f & 7;
            int sp = s0 - 3 + r;
            uint4 v;
            if (sp >= 0) v = *(const uint4*)(projb + ((size_t)(b*SEQ+sp))*PROJ_PAD + INTER + d0 + g*8);
            else { v.x=0u; v.y=0u; v.z=0u; v.w=0u; }
            unsigned int* dst = (unsigned int*)&raw[r][g*8];
            dst[0]=v.x; dst[1]=v.y; dst[2]=v.z; dst[3]=v.w;
        }
        __syncthreads();
        int t = tid & 63, dg = tid >> 6;
        #pragma unroll
        for (int dd = 0; dd < 16; dd++){
            int d = dg*16 + dd;
            float acc = cb[d0+d];
            #pragma unroll
            for (int j=0;j<CONV_K;j++)
                acc += cw[(d0+d)*CONV_K+j] * bf2f(raw[t+j][d]);
            float val = acc/(1.f+expf(-acc));
            XT[((size_t)(b*INTER + d0 + d))*SEQ + s0 + t] = f2bf(val);
        }
    } else if (bid < XBLK + TOK) {
        int idx = (bid - XBLK)*256 + tid;
        int d = idx & 255;
        int t = idx >> 8;
        int b = t / SEQ, sl = t % SEQ;
        int dc = INTER + d;
        float acc = cb[dc];
        #pragma unroll
        for (int j=0;j<CONV_K;j++){
            int sp = sl - (CONV_K-1) + j;
            if (sp >= 0)
                acc += cw[dc*CONV_K+j] * projBC[((size_t)(b*SEQ+sp))*NBC + d];
        }
        float val = acc / (1.f + expf(-acc));
        xBC_BC[(size_t)t*256 + d] = val;
        if (d < 128)
            BT[((size_t)(b*128 + d))*SEQ + sl] = f2bf(val);
        else
            Cb[(size_t)t*128 + (d-128)] = f2bf(val);
    } else {
        size_t i4 = (size_t)(bid - XBLK - TOK)*256 + tid;
        size_t i = i4*4;
        float4 v = *(const float4*)(out_w + i);
        ushort4 o; o.x=f2bf(v.x); o.y=f2bf(v.y); o.z=f2bf(v.z); o.w=f2bf(v.w);
        *(ushort4*)(w2b + i) = o;
    }
}

// ---------------- per-chunk inclusive cumsum of dA = A*dt ---------------------------
__global__ __launch_bounds__(256) void cumsum_kernel(const float* __restrict__ dtbuf,
                                                     const float* __restrict__ A_log,
                                                     float* __restrict__ A_cum) {
    int c = blockIdx.x, h = blockIdx.y, b = blockIdx.z;
    int l = threadIdx.x;
    float A = -expf(A_log[h]);
    float v = A * dtbuf[(size_t)(b*SEQ + c*CHUNK + l)*NUM_HEADS + h];
    __shared__ float buf[CHUNK];
    buf[l] = v;
    __syncthreads();
    for (int off=1; off<CHUNK; off<<=1){
        float t = (l>=off) ? buf[l-off] : 0.f;
        __syncthreads();
        buf[l] += t;
        __syncthreads();
    }
    A_cum[((size_t)b*NUM_HEADS + h)*SEQ + c*CHUNK + l] = buf[l];
}

// ---------------- G[l][s] = C[l] . B[s]  (head-shared), bf16, 32x32 tiles -----------
// grid: (NC, 36 lower-tri 32-pairs, BATCH)  -> c-major for XCD co-location
__global__ __launch_bounds__(256) void g_kernel(const float* __restrict__ xBC_BC,
                                                unsigned short* __restrict__ G) {
    int c = blockIdx.x, p = blockIdx.y, b = blockIdx.z;
    int lt = 0, a0 = 0;
    while (a0 + lt + 1 <= p) { a0 += lt + 1; lt++; }
    int st = p - a0;
    int l0 = lt*32, s0 = st*32;
    __shared__ float Cs[32][132];
    __shared__ float Bs[32][132];
    int tid = threadIdx.x, ty = tid >> 4, tx = tid & 15;
    float acc[2][2];
    acc[0][0]=0.f; acc[0][1]=0.f; acc[1][0]=0.f; acc[1][1]=0.f;

    size_t rowC = ((size_t)(b*SEQ + c*CHUNK + l0))*256 + 128;
    size_t rowB = ((size_t)(b*SEQ + c*CHUNK + s0))*256;
    #pragma unroll
    for (int it=0; it<4; it++){
        int f = tid + it*256;          // 0..1023 = 32 rows x 32 f4-cols
        int r = f >> 5, c4 = f & 31;
        *(float4*)&Cs[r][c4*4] = *(const float4*)(xBC_BC + rowC + (size_t)r*256 + c4*4);
        *(float4*)&Bs[r][c4*4] = *(const float4*)(xBC_BC + rowB + (size_t)r*256 + c4*4);
    }
    __syncthreads();
    #pragma unroll 8
    for (int k=0;k<128;k++){
        float a0v = Cs[ty*2][k],   a1v = Cs[ty*2+1][k];
        float b0v = Bs[tx*2][k],   b1v = Bs[tx*2+1][k];
        acc[0][0] += a0v*b0v; acc[0][1] += a0v*b1v;
        acc[1][0] += a1v*b0v; acc[1][1] += a1v*b1v;
    }
    size_t Gb = ((size_t)(b*NC + c)) << 16;
    #pragma unroll
    for (int i=0;i<2;i++){
        ushort2 g2;
        g2.x = f2bf(acc[i][0]); g2.y = f2bf(acc[i][1]);
        *(ushort2*)(G + Gb + (size_t)(l0 + ty*2 + i)*256 + s0 + tx*2) = g2;
    }
}

// ---------------- statesT[p][n] = sum_l (XT[p][l]*w[l]) * BT[n][l]  (MFMA) ----------
__global__ __launch_bounds__(256) void states_mfma(const unsigned short* __restrict__ XT,
                                                   const unsigned short* __restrict__ BT,
                                                   const float* __restrict__ dtbuf,
                                                   const float* __restrict__ A_cum,
                                                   unsigned short* __restrict__ statesT) {
    int c = blockIdx.x, h = blockIdx.y, b = blockIdx.z;
    __shared__ unsigned short Asx[64][64];   // Xw tile [p][l]
    __shared__ unsigned short Bs[128][64];   // B tile  [n][l]
    __shared__ float wl[CHUNK];
    int tid = threadIdx.x, lane = tid & 63, wid = tid >> 6;
    {
        const float* ac = A_cum + ((size_t)(b*NUM_HEADS+h))*SEQ + c*CHUNK;
        float Alast = ac[CHUNK-1];
        wl[tid] = expf(Alast - ac[tid]) * dtbuf[((size_t)(b*SEQ + c*CHUNK + tid))*NUM_HEADS + h];
    }
    __syncthreads();
    f32x4 acc[4][2];
    #pragma unroll
    for (int i=0;i<4;i++)
        #pragma unroll
        for (int j=0;j<2;j++) acc[i][j] = (f32x4){0.f,0.f,0.f,0.f};

    for (int kc = 0; kc < 4; kc++){
        int lbase = kc*64;
        #pragma unroll
        for (int q=0;q<4;q++){
            int brow = (wid*4+q)*8;
            int row  = brow + (lane>>3);
            int sl   = (lane&7) ^ (row & 7);
            gld16(BT + ((size_t)(b*128 + row))*SEQ + c*CHUNK + lbase + sl*8, &Bs[brow][0]);
        }
        #pragma unroll
        for (int it=0; it<2; it++){
            int f = tid + it*256;
            int r = f >> 3, g = f & 7;
            uint4 v = *(const uint4*)(XT + ((size_t)(b*INTER + h*HEAD_DIM + r))*SEQ + c*CHUNK + lbase + g*8);
            float e[8]; unpack8(v, e);
            unsigned short o[8];
            #pragma unroll
            for (int u=0;u<8;u++) o[u] = f2bf(e[u] * wl[lbase + g*8 + u]);
            int slot = g ^ (r & 7);
            *(ushort4*)&Asx[r][slot*8]   = *(ushort4*)&o[0];
            *(ushort4*)&Asx[r][slot*8+4] = *(ushort4*)&o[4];
        }
        __syncthreads();
        #pragma unroll
        for (int kk=0; kk<64; kk+=32){
            bf16x8 a[4], bb[2];
            #pragma unroll
            for (int i=0;i<4;i++){
                int row = i*16 + (lane&15);
                int slot = ((kk>>3)+(lane>>4)) ^ (row&7);
                a[i] = *(const bf16x8*)&Asx[row][slot*8];
            }
            #pragma unroll
            for (int j=0;j<2;j++){
                int row = wid*32 + j*16 + (lane&15);
                int slot = ((kk>>3)+(lane>>4)) ^ (row&7);
                bb[j] = *(const bf16x8*)&Bs[row][slot*8];
            }
            #pragma unroll
            for (int i=0;i<4;i++)
                #pragma unroll
                for (int j=0;j<2;j++)
                    acc[i][j] = MFMA16(a[i], bb[j], acc[i][j]);
        }
        __syncthreads();
    }
    size_t sb = ((size_t)((b*NC + c)*NUM_HEADS + h))*(HEAD_DIM*STATE);
    #pragma unroll
    for (int i=0;i<4;i++){
        #pragma unroll
        for (int j=0;j<2;j++){
            int n = wid*32 + j*16 + (lane&15);
            int p0 = i*16 + (lane>>4)*4;
            #pragma unroll
            for (int r=0;r<4;r++)
                statesT[sb + (size_t)(p0+r)*128 + n] = f2bf(acc[i][j][r]);
        }
    }
}

// ---------------- inter-chunk recurrence (in place, bf16, 4-way split) --------------
__global__ __launch_bounds__(256) void recur_kernel(const float* __restrict__ A_cum,
                                                    unsigned short* __restrict__ states) {
    int h = blockIdx.x, b = blockIdx.y, z = blockIdx.z;
    int tid = threadIdx.x;
    float Srun[8];
    #pragma unroll
    for (int i=0;i<8;i++) Srun[i]=0.f;
    const float* acum = A_cum + ((size_t)b*NUM_HEADS + h)*SEQ;
    for (int c=0;c<NC;c++){
        float alast = acum[c*CHUNK + CHUNK-1];
        float dec = expf(alast);
        size_t base = ((size_t)((b*NC + c)*NUM_HEADS + h))*(HEAD_DIM*STATE);
        #pragma unroll
        for (int i=0;i<8;i++){
            size_t idx = base + (size_t)tid + (size_t)(z*8+i)*256;
            float raw = bf2f(states[idx]);
            states[idx] = f2bf(Srun[i]);
            Srun[i] = Srun[i]*dec + raw;
        }
    }
}

// ---------------- Y = e_l*(Cs @ St^T) + Gw @ Xs^T + D*X   (MFMA) --------------------
// block mapping: c = xb&7 (XCD co-location of all lt/h of one chunk), lt = xb>>3
__global__ __launch_bounds__(256) void yscan_mfma(const unsigned short* __restrict__ G,
                                                  const unsigned short* __restrict__ Cb,
                                                  const unsigned short* __restrict__ XT,
                                                  const float* __restrict__ dtbuf,
                                                  const float* __restrict__ A_cum,
                                                  const unsigned short* __restrict__ statesT,
                                                  const float* __restrict__ Dvec,
                                                  unsigned short* __restrict__ projb) {
    int xb = blockIdx.x;
    int c = xb & 7, lt = xb >> 3;
    int h = blockIdx.y, b = blockIdx.z;
    int l0 = lt*64;
    __shared__ __align__(16) char pool[32768];
    unsigned short (*Cs)[128] = (unsigned short(*)[128])pool;            // [l][n]
    unsigned short (*St)[128] = (unsigned short(*)[128])(pool + 16384);  // [p][n]
    unsigned short (*Gw)[64]  = (unsigned short(*)[64])pool;             // [l][s]
    unsigned short (*Xs)[64]  = (unsigned short(*)[64])(pool + 8192);    // [p][s]
    float (*Ot)[68]           = (float(*)[68])pool;
    __shared__ float ac[CHUNK], dts[CHUNK];
    int tid = threadIdx.x, lane = tid & 63, wid = tid >> 6;
    ac[tid]  = A_cum[((size_t)(b*NUM_HEADS + h))*SEQ + c*CHUNK + tid];
    dts[tid] = dtbuf[((size_t)(b*SEQ + c*CHUNK + tid))*NUM_HEADS + h];

    // ---- phase 1 staging: Cs and St via gld16 ----
    size_t stb = ((size_t)((b*NC + c)*NUM_HEADS + h))*(HEAD_DIM*STATE);
    #pragma unroll
    for (int q=0;q<4;q++){
        int brow = (wid*4+q)*4;
        int row  = brow + (lane>>4);
        int sl   = (lane&15) ^ (row & 7);
        gld16(Cb + ((size_t)(b*SEQ + c*CHUNK + l0 + row))*128 + sl*8, &Cs[brow][0]);
        gld16(statesT + stb + (size_t)row*128 + sl*8, &St[brow][0]);
    }
    __syncthreads();

    f32x4 acc1[4];
    #pragma unroll
    for (int j=0;j<4;j++) acc1[j] = (f32x4){0.f,0.f,0.f,0.f};
    #pragma unroll
    for (int kk=0; kk<128; kk+=32){
        int arow = wid*16 + (lane&15);
        int aslot = ((kk>>3)+(lane>>4)) ^ (arow&7);
        bf16x8 a = *(const bf16x8*)&Cs[arow][aslot*8];
        #pragma unroll
        for (int j=0;j<4;j++){
            int brow = j*16 + (lane&15);
            int bslot = ((kk>>3)+(lane>>4)) ^ (brow&7);
            bf16x8 bb = *(const bf16x8*)&St[brow][bslot*8];
            acc1[j] = MFMA16(a, bb, acc1[j]);
        }
    }
    float el[4];
    #pragma unroll
    for (int r=0;r<4;r++) el[r] = expf(ac[l0 + wid*16 + (lane>>4)*4 + r]);
    float master[4][4];
    #pragma unroll
    for (int j=0;j<4;j++)
        #pragma unroll
        for (int r=0;r<4;r++) master[j][r] = acc1[j][r]*el[r];
    __syncthreads();

    size_t Gb = ((size_t)(b*NC + c)) << 16;
    f32x4 acc2[4];
    #pragma unroll
    for (int j=0;j<4;j++) acc2[j] = (f32x4){0.f,0.f,0.f,0.f};
    for (int st=0; st<=lt; st++){
        int s0 = st*64;
        #pragma unroll
        for (int it=0; it<2; it++){
            int f = tid + it*256;
            int r = f >> 3, g = f & 7;
            uint4 v = *(const uint4*)(G + Gb + (size_t)(l0 + r)*256 + s0 + g*8);
            float e[8]; unpack8(v, e);
            float acl = ac[l0 + r];
            unsigned short o[8];
            #pragma unroll
            for (int u=0;u<8;u++){
                int s = s0 + g*8 + u;
                float w = (s <= l0 + r) ? expf(acl - ac[s])*dts[s] : 0.f;
                o[u] = f2bf(e[u]*w);
            }
            int slot = g ^ (r&7);
            *(ushort4*)&Gw[r][slot*8]   = *(ushort4*)&o[0];
            *(ushort4*)&Gw[r][slot*8+4] = *(ushort4*)&o[4];
        }
        #pragma unroll
        for (int q=0;q<2;q++){
            int brow = (wid*2+q)*8;
            int row  = brow + (lane>>3);
            int sl   = (lane&7) ^ (row&7);
            gld16(XT + ((size_t)(b*INTER + h*HEAD_DIM + row))*SEQ + c*CHUNK + s0 + sl*8,
                  &Xs[brow][0]);
        }
        __syncthreads();
        #pragma unroll
        for (int kk=0; kk<64; kk+=32){
            int arow = wid*16 + (lane&15);
            int aslot = ((kk>>3)+(lane>>4)) ^ (arow&7);
            bf16x8 a = *(const bf16x8*)&Gw[arow][aslot*8];
            #pragma unroll
            for (int j=0;j<4;j++){
                int brow = j*16 + (lane&15);
                int bslot = ((kk>>3)+(lane>>4)) ^ (brow&7);
                bf16x8 bb = *(const bf16x8*)&Xs[brow][bslot*8];
                acc2[j] = MFMA16(a, bb, acc2[j]);
            }
        }
        if (st < lt) __syncthreads();
    }

    float Dh = Dvec[h];
    #pragma unroll
    for (int j=0;j<4;j++){
        int p = j*16 + (lane&15);
        #pragma unroll
        for (int r=0;r<4;r++){
            int sl_ = wid*16 + (lane>>4)*4 + r;
            int slot = (sl_>>3) ^ (p&7);
            float xv = bf2f(Xs[p][slot*8 + (sl_&7)]);
            master[j][r] += acc2[j][r] + Dh*xv;
        }
    }
    __syncthreads();

    #pragma unroll
    for (int j=0;j<4;j++){
        int p = j*16 + (lane&15);
        #pragma unroll
        for (int r=0;r<4;r++)
            Ot[wid*16 + (lane>>4)*4 + r][p] = master[j][r];
    }
    __syncthreads();
    #pragma unroll
    for (int it=0; it<4; it++){
        int f = tid + it*256;
        int r = f >> 4, c4 = f & 15;
        ushort4 o;
        o.x = f2bf(Ot[r][c4*4+0]); o.y = f2bf(Ot[r][c4*4+1]);
        o.z = f2bf(Ot[r][c4*4+2]); o.w = f2bf(Ot[r][c4*4+3]);
        *(ushort4*)(projb + ((size_t)(b*SEQ + c*CHUNK + l0 + r))*PROJ_PAD + INTER + h*HEAD_DIM + c4*4) = o;
    }
}

// ---------------- gate * silu + RMSNorm -> packed bf16 y ----------------------------
__global__ __launch_bounds__(256) void gate_norm_kernel(const unsigned short* __restrict__ projb,
                                                        const float* __restrict__ normw,
                                                        unsigned short* __restrict__ yb) {
    int t = blockIdx.x;
    int tid = threadIdx.x;
    const unsigned short* row = projb + (size_t)t*PROJ_PAD;
    __shared__ float red[4];
    float vals[20];
    float ss = 0.f;
    #pragma unroll
    for (int i=0;i<5;i++){
        int j = (tid + i*256)*4;
        ushort4 g4 = *(const ushort4*)(row + j);
        ushort4 y4 = *(const ushort4*)(row + INTER + j);
        #pragma unroll
        for (int u=0;u<4;u++){
            float g = bf2f(((const unsigned short*)&g4)[u]);
            float y = bf2f(((const unsigned short*)&y4)[u]);
            float gv = g / (1.f + expf(-g));
            float v = y * gv;
            vals[i*4+u] = v;
            ss += v*v;
        }
    }
    #pragma unroll
    for (int off=32; off; off>>=1) ss += __shfl_xor(ss, off);
    if ((tid&63)==0) red[tid>>6] = ss;
    __syncthreads();
    float tot = red[0]+red[1]+red[2]+red[3];
    float inv = rsqrtf(tot/(float)INTER + EPS);
    #pragma unroll
    for (int i=0;i<5;i++){
        int j = (tid + i*256)*4;
        ushort4 o;
        o.x = f2bf(vals[i*4+0] * inv * normw[j+0]);
        o.y = f2bf(vals[i*4+1] * inv * normw[j+1]);
        o.z = f2bf(vals[i*4+2] * inv * normw[j+2]);
        o.w = f2bf(vals[i*4+3] * inv * normw[j+3]);
        *(ushort4*)(yb + (size_t)t*INTER + j) = o;
    }
}

// ------------------------------------------------------------------------------------
extern "C" void kernel_launch(void* const* d_in, const int* in_sizes, int n_in,
                              void* d_out, int out_size, void* d_ws, size_t ws_size,
                              hipStream_t stream) {
    const float* x        = (const float*)d_in[0];
    const float* in_w     = (const float*)d_in[1];
    const float* conv_w   = (const float*)d_in[2];
    const float* conv_b   = (const float*)d_in[3];
    const float* A_log    = (const float*)d_in[4];
    const float* Dvec     = (const float*)d_in[5];
    const float* dt_bias  = (const float*)d_in[6];
    const float* norm_w   = (const float*)d_in[7];
    const float* out_w    = (const float*)d_in[8];
    float* out = (float*)d_out;
    (void)ws_size; (void)n_in; (void)in_sizes; (void)out_size;

    // ---- fixed workspace ----
    const size_t PROJB   = (size_t)TOK*PROJ_PAD*2;
    const size_t PROJBCB = (size_t)TOK*NBC*4;
    const size_t XTB     = (size_t)TOK*INTER*2;
    const size_t XBCBCB  = (size_t)TOK*256*4;
    const size_t BTB     = (size_t)BATCH*128*SEQ*2;
    const size_t CBB     = (size_t)TOK*128*2;
    const size_t GBYTES  = (size_t)BATCH*NC*CHUNK*CHUNK*2;
    const size_t DTB     = (size_t)TOK*NUM_HEADS*4;
    const size_t ACUMB   = DTB;
    const size_t STB     = (size_t)BATCH*NC*NUM_HEADS*HEAD_DIM*STATE*2;
    // ---- transient region ----
    const size_t XHB   = (size_t)TOK*HIDDEN*2;
    const size_t WBCB  = (size_t)NBCP*HIDDEN*2;
    const size_t YBB   = (size_t)TOK*INTER*2;

    char* base = (char*)d_ws;
    size_t off = 0;
    unsigned short* projb  = (unsigned short*)(base + off); off += PROJB;
    float* projBC          = (float*)(base + off);          off += PROJBCB;
    unsigned short* XTp    = (unsigned short*)(base + off); off += XTB;
    float* xBC_BC          = (float*)(base + off);          off += XBCBCB;
    unsigned short* BTp    = (unsigned short*)(base + off); off += BTB;
    unsigned short* Cbp    = (unsigned short*)(base + off); off += CBB;
    unsigned short* Gp     = (unsigned short*)(base + off); off += GBYTES;
    float* dtbuf           = (float*)(base + off);          off += DTB;
    float* A_cum           = (float*)(base + off);          off += ACUMB;
    unsigned short* statesT= (unsigned short*)(base + off); off += STB;
    char*  T               = base + off;
    unsigned short* xhi    = (unsigned short*)T;
    unsigned short* xlo    = (unsigned short*)(T + XHB);
    unsigned short* wbc_hi = (unsigned short*)(T + 2*XHB);
    unsigned short* wbc_lo = (unsigned short*)(T + 2*XHB + WBCB);
    unsigned short* w1b    = (unsigned short*)(T + 2*XHB + 2*WBCB);
    float* bcpart          = (float*)w1b;
    unsigned short* yb     = (unsigned short*)T;
    unsigned short* w2b    = (unsigned short*)(T + YBB);

    // 1. fused prep
    {
        unsigned total_blocks = (unsigned)((N4A + N4B + N4C) / 256);
        prep_kernel<<<total_blocks, 256, 0, stream>>>(x, in_w, xhi, xlo, w1b, wbc_hi, wbc_lo);
    }
    // 2. proj(gate,X) = x @ w1^T
    gemm_bf16<true><<<dim3(PROJ_PAD/128, TOK/128), 256, 0, stream>>>(xhi, HIDDEN, w1b, HIDDEN,
                                                                     projb, PROJ_PAD, HIDDEN);
    // 3. B/C/dt via bf16 hi/lo split-K MFMA; partials alias w1b
    bc_splitk_mfma<<<dim3(NBCP/128, TOK/128, KSPL2), 256, 0, stream>>>(xhi, xlo, wbc_hi, wbc_lo, bcpart);
    reduce_bc2<<<(unsigned)(((size_t)TOK*NBCP/4)/256), 256, 0, stream>>>(bcpart, dt_bias, projBC, dtbuf);
    // 4. fused conv (XT + B/C) + w2 conversion
    conv_fused<<<XBLK + TOK + W2BLK, 256, 0, stream>>>(projb, projBC, conv_w, conv_b, out_w,
                                                       XTp, xBC_BC, BTp, Cbp, w2b);
    // 5. cumsum
    cumsum_kernel<<<dim3(NC, NUM_HEADS, BATCH), 256, 0, stream>>>(dtbuf, A_log, A_cum);
    // 6. G = C.B^T (32x32 tiles, c-major grid)
    g_kernel<<<dim3(NC, 36, BATCH), 256, 0, stream>>>(xBC_BC, Gp);
    // 7. per-chunk states (MFMA)
    states_mfma<<<dim3(NC, NUM_HEADS, BATCH), 256, 0, stream>>>(XTp, BTp, dtbuf, A_cum, statesT);
    // 8. inter-chunk recurrence (4-way split)
    recur_kernel<<<dim3(NUM_HEADS, BATCH, 4), 256, 0, stream>>>(A_cum, statesT);
    // 9. Y (MFMA, c-colocated blocks) -> bf16 into projb
    yscan_mfma<<<dim3(NC*4, NUM_HEADS, BATCH), 256, 0, stream>>>(Gp, Cbp, XTp, dtbuf, A_cum,
                                                                 statesT, Dvec, projb);
    // 10. gate + RMSNorm -> bf16 y
    gate_norm_kernel<<<TOK, 256, 0, stream>>>(projb, norm_w, yb);
    // 11. out = y @ out_w^T
    gemm_bf16<false><<<dim3(HIDDEN/128, TOK/128), 256, 0, stream>>>(yb, INTER, w2b, INTER,
                                                                    out, HIDDEN, INTER);
}

// Round 13
// 702.744 us; speedup vs baseline: 1.3200x; 1.0107x over previous
//
#include <hip/hip_runtime.h>
#include <hip/hip_bf16.h>
#include <math.h>

#define HIDDEN   2560
#define NUM_HEADS 80
#define HEAD_DIM 64
#define STATE    128
#define CONV_K   4
#define CHUNK    256
#define INTER    (2*HIDDEN)                 // 5120
#define CONV_DIM (INTER + 2*STATE)          // 5376
#define PROJ     (INTER + CONV_DIM + NUM_HEADS) // 10576
#define PROJ_PAD 10240                      // gate + X only
#define NBC      336
#define NBCP     384
#define EPS      1e-5f

#define BATCH 2
#define SEQ   2048
#define TOK   (BATCH*SEQ)                   // 4096
#define NC    (SEQ/CHUNK)                   // 8
#define KSPL2 8
#define KCH2  (HIDDEN/KSPL2)                // 320

#define G1_BLOCKS 2560                      // 80 n-tiles x 32 m-tiles
#define BC_BLOCKS 768                       // 3 x 32 x 8
#define RED_BLOCKS 1536                     // TOK*NBCP/4/256
#define CXT_BLOCKS 5120                     // 64 x 80
#define CBC_BLOCKS 4096
#define CUM_BLOCKS 1280                     // 8*80*2
#define W2_BLOCKS  12800                    // HIDDEN*INTER/4/256
#define ST_BLOCKS  1280
#define GK_BLOCKS  576                      // 8*36*2

typedef __attribute__((ext_vector_type(8))) short bf16x8;
typedef __attribute__((ext_vector_type(4))) float f32x4;
typedef unsigned short us;

#define MFMA16(a,b,c) __builtin_amdgcn_mfma_f32_16x16x32_bf16((a),(b),(c),0,0,0)

__device__ __forceinline__ us f2bf(float f){
    union{float f;unsigned u;}v; v.f=f;
    unsigned r = v.u + 0x7fffu + ((v.u>>16)&1u);
    return (us)(r>>16);
}
__device__ __forceinline__ float bf2f(us s){
    union{unsigned u;float f;}v; v.u = ((unsigned)s)<<16; return v.f;
}
__device__ __forceinline__ void unpack8(uint4 u, float* e){
    e[0]=bf2f((us)(u.x&0xffff)); e[1]=bf2f((us)(u.x>>16));
    e[2]=bf2f((us)(u.y&0xffff)); e[3]=bf2f((us)(u.y>>16));
    e[4]=bf2f((us)(u.z&0xffff)); e[5]=bf2f((us)(u.z>>16));
    e[6]=bf2f((us)(u.w&0xffff)); e[7]=bf2f((us)(u.w>>16));
}
__device__ __forceinline__ void gld16(const void* g, void* l){
    __builtin_amdgcn_global_load_lds((const __attribute__((address_space(1))) void*)g,
                                     (__attribute__((address_space(3))) void*)l, 16, 0, 0);
}

// =============== MERGED: GEMM1 (bf16 out, LDS epilogue) + bc split-K ================
__global__ __launch_bounds__(256) void mega_gemm1_bc(const us* __restrict__ xhi,
                                                     const us* __restrict__ xlo,
                                                     const us* __restrict__ w1b,
                                                     const us* __restrict__ wbc_hi,
                                                     const us* __restrict__ wbc_lo,
                                                     us* __restrict__ projb,
                                                     float* __restrict__ Cpart) {
    __shared__ __align__(16) char SH[32768];
    us (*As)[64] = (us(*)[64])SH;
    us (*Bs)[64] = (us(*)[64])(SH + 16384);
    int bid = blockIdx.x;
    int tid = threadIdx.x;
    int lane = tid & 63, wid = tid >> 6;
    int wr = wid >> 1, wc = wid & 1;
    int srow_off = lane >> 3;
    int sslot    = lane & 7;

    f32x4 acc[4][4];
    #pragma unroll
    for (int i=0;i<4;i++)
        #pragma unroll
        for (int j=0;j<4;j++) acc[i][j] = (f32x4){0.f,0.f,0.f,0.f};

    if (bid < G1_BLOCKS) {
        // ---- GEMM1: projb[m][n] = sum_k xhi[m][k]*w1b[n][k] ----
        int xcd = bid & 7, local = bid >> 3;
        int bm = (xcd*4 + (local & 3))*128;     // 32 m-tiles, mrows=4 per XCD
        int bn = (local >> 2)*128;              // 80 n-tiles
        for (int k0 = 0; k0 < HIDDEN; k0 += 64) {
            #pragma unroll
            for (int q=0;q<4;q++){
                int brow = (wid*4+q)*8;
                int row  = brow + srow_off;
                int sl   = sslot ^ (row & 7);
                gld16(xhi + (size_t)(bm + row)*HIDDEN + k0 + sl*8, &As[brow][0]);
                gld16(w1b + (size_t)(bn + row)*HIDDEN + k0 + sl*8, &Bs[brow][0]);
            }
            __syncthreads();
            #pragma unroll
            for (int kk=0; kk<64; kk+=32){
                bf16x8 a[4], b[4];
                #pragma unroll
                for (int i=0;i<4;i++){
                    int row = wr*64 + i*16 + (lane&15);
                    int slot = ((kk>>3) + (lane>>4)) ^ (row & 7);
                    a[i] = *(const bf16x8*)&As[row][slot*8];
                }
                #pragma unroll
                for (int j=0;j<4;j++){
                    int row = wc*64 + j*16 + (lane&15);
                    int slot = ((kk>>3) + (lane>>4)) ^ (row & 7);
                    b[j] = *(const bf16x8*)&Bs[row][slot*8];
                }
                #pragma unroll
                for (int i=0;i<4;i++)
                    #pragma unroll
                    for (int j=0;j<4;j++)
                        acc[i][j] = MFMA16(a[i], b[j], acc[i][j]);
            }
            __syncthreads();
        }
        // ---- coalesced epilogue: stage bf16 C-tile in LDS (exactly 32KB), write 16B ----
        us (*Ct)[128] = (us(*)[128])SH;
        #pragma unroll
        for (int i=0;i<4;i++){
            int r0 = wr*64 + i*16 + (lane>>4)*4;
            #pragma unroll
            for (int j=0;j<4;j++){
                int cc = wc*64 + j*16 + (lane&15);
                #pragma unroll
                for (int r=0;r<4;r++)
                    Ct[r0+r][cc] = f2bf(acc[i][j][r]);
            }
        }
        __syncthreads();
        #pragma unroll
        for (int it=0; it<8; it++){
            int f = tid + it*256;
            int row = f >> 4, ch = f & 15;
            *(uint4*)(projb + (size_t)(bm+row)*PROJ_PAD + bn + ch*8) = *(uint4*)&Ct[row][ch*8];
        }
    } else {
        // ---- bc split-K: hi/lo 3-term MFMA, fp32 partials ----
        int b2 = bid - G1_BLOCKS;
        int bn = (b2 % 3)*128;
        int bm = ((b2/3) & 31)*128;
        int z  = b2 / 96;
        for (int term = 0; term < 3; ++term){
            const us* A = (term==2) ? xlo : xhi;
            const us* B = (term==0) ? wbc_lo : wbc_hi;
            for (int k0 = z*KCH2; k0 < z*KCH2 + KCH2; k0 += 64) {
                #pragma unroll
                for (int q=0;q<4;q++){
                    int brow = (wid*4+q)*8;
                    int row  = brow + srow_off;
                    int sl   = sslot ^ (row & 7);
                    gld16(A + (size_t)(bm + row)*HIDDEN + k0 + sl*8, &As[brow][0]);
                    gld16(B + (size_t)(bn + row)*HIDDEN + k0 + sl*8, &Bs[brow][0]);
                }
                __syncthreads();
                #pragma unroll
                for (int kk=0; kk<64; kk+=32){
                    bf16x8 a[4], b[4];
                    #pragma unroll
                    for (int i=0;i<4;i++){
                        int row = wr*64 + i*16 + (lane&15);
                        int slot = ((kk>>3) + (lane>>4)) ^ (row & 7);
                        a[i] = *(const bf16x8*)&As[row][slot*8];
                    }
                    #pragma unroll
                    for (int j=0;j<4;j++){
                        int row = wc*64 + j*16 + (lane&15);
                        int slot = ((kk>>3) + (lane>>4)) ^ (row & 7);
                        b[j] = *(const bf16x8*)&Bs[row][slot*8];
                    }
                    #pragma unroll
                    for (int i=0;i<4;i++)
                        #pragma unroll
                        for (int j=0;j<4;j++)
                            acc[i][j] = MFMA16(a[i], b[j], acc[i][j]);
                }
                __syncthreads();
            }
        }
        float* Cz = Cpart + (size_t)z*TOK*NBCP;
        #pragma unroll
        for (int i=0;i<4;i++){
            int row0 = bm + wr*64 + i*16 + (lane>>4)*4;
            #pragma unroll
            for (int j=0;j<4;j++){
                int col = bn + wc*64 + j*16 + (lane&15);
                #pragma unroll
                for (int r=0;r<4;r++)
                    Cz[(size_t)(row0+r)*NBCP + col] = acc[i][j][r];
            }
        }
    }
}

// =============== 128x128 bf16 MFMA GEMM (NT) — GEMM2 ================================
template<bool BF16OUT>
__global__ __launch_bounds__(256) void gemm_bf16(const us* __restrict__ A, int lda,
                                                 const us* __restrict__ B, int ldb,
                                                 void* __restrict__ Cv, int ldc, int K) {
    __shared__ us As[128][64];
    __shared__ us Bs[128][64];
    int tid = threadIdx.x;
    int lane = tid & 63, wid = tid >> 6;
    int wr = wid >> 1, wc = wid & 1;

    int bm, bn;
    if ((gridDim.y & 7) == 0) {
        int bid   = blockIdx.y * gridDim.x + blockIdx.x;
        int xcd   = bid & 7;
        int local = bid >> 3;
        int mrows = gridDim.y >> 3;
        bm = (xcd * mrows + (local % mrows)) * 128;
        bn = (local / mrows) * 128;
    } else {
        bm = blockIdx.y * 128;
        bn = blockIdx.x * 128;
    }

    f32x4 acc[4][4];
    #pragma unroll
    for (int i=0;i<4;i++)
        #pragma unroll
        for (int j=0;j<4;j++) acc[i][j] = (f32x4){0.f,0.f,0.f,0.f};

    int srow_off = lane >> 3;
    int sslot    = lane & 7;

    for (int k0 = 0; k0 < K; k0 += 64) {
        #pragma unroll
        for (int q=0;q<4;q++){
            int brow = (wid*4+q)*8;
            int row  = brow + srow_off;
            int sl   = sslot ^ (row & 7);
            gld16(A + (size_t)(bm + row)*lda + k0 + sl*8, &As[brow][0]);
            gld16(B + (size_t)(bn + row)*ldb + k0 + sl*8, &Bs[brow][0]);
        }
        __syncthreads();
        #pragma unroll
        for (int kk=0; kk<64; kk+=32){
            bf16x8 a[4], b[4];
            #pragma unroll
            for (int i=0;i<4;i++){
                int row = wr*64 + i*16 + (lane&15);
                int slot = ((kk>>3) + (lane>>4)) ^ (row & 7);
                a[i] = *(const bf16x8*)&As[row][slot*8];
            }
            #pragma unroll
            for (int j=0;j<4;j++){
                int row = wc*64 + j*16 + (lane&15);
                int slot = ((kk>>3) + (lane>>4)) ^ (row & 7);
                b[j] = *(const bf16x8*)&Bs[row][slot*8];
            }
            #pragma unroll
            for (int i=0;i<4;i++)
                #pragma unroll
                for (int j=0;j<4;j++)
                    acc[i][j] = MFMA16(a[i], b[j], acc[i][j]);
        }
        __syncthreads();
    }
    #pragma unroll
    for (int i=0;i<4;i++){
        int row0 = bm + wr*64 + i*16 + (lane>>4)*4;
        #pragma unroll
        for (int j=0;j<4;j++){
            int col = bn + wc*64 + j*16 + (lane&15);
            #pragma unroll
            for (int r=0;r<4;r++){
                if (BF16OUT)
                    ((us*)Cv)[(size_t)(row0+r)*ldc + col] = f2bf(acc[i][j][r]);
                else
                    ((float*)Cv)[(size_t)(row0+r)*ldc + col] = acc[i][j][r];
            }
        }
    }
}

// ---------------- fused prep: x->(xhi,xlo), w1->bf16, wbc->(hi,lo) ------------------
#define N4A ((size_t)TOK*HIDDEN/4)
#define N4B ((size_t)PROJ_PAD*HIDDEN/4)
#define N4C ((size_t)NBCP*HIDDEN/4)
__global__ __launch_bounds__(256) void prep_kernel(const float* __restrict__ x,
                                                   const float* __restrict__ in_w,
                                                   us* __restrict__ xhi,
                                                   us* __restrict__ xlo,
                                                   us* __restrict__ w1b,
                                                   us* __restrict__ wbc_hi,
                                                   us* __restrict__ wbc_lo) {
    size_t gid = (size_t)blockIdx.x*256 + threadIdx.x;
    if (gid < N4A) {
        size_t i = gid*4;
        float4 v = *(const float4*)(x + i);
        float e[4] = {v.x, v.y, v.z, v.w};
        ushort4 h, l;
        us* hp = (us*)&h;
        us* lp = (us*)&l;
        #pragma unroll
        for (int u=0;u<4;u++){
            us hv = f2bf(e[u]);
            hp[u] = hv;
            lp[u] = f2bf(e[u] - bf2f(hv));
        }
        *(ushort4*)(xhi + i) = h;
        *(ushort4*)(xlo + i) = l;
    } else if (gid < N4A + N4B) {
        size_t i = (gid - N4A)*4;
        float4 v = *(const float4*)(in_w + i);
        ushort4 o;
        o.x=f2bf(v.x); o.y=f2bf(v.y); o.z=f2bf(v.z); o.w=f2bf(v.w);
        *(ushort4*)(w1b + i) = o;
    } else {
        size_t j = gid - N4A - N4B;
        size_t i = j*4;
        int row = (int)(i / HIDDEN);
        int kk  = (int)(i % HIDDEN);
        ushort4 h, l;
        h.x=h.y=h.z=h.w=0; l.x=l.y=l.z=l.w=0;
        if (row < NBC){
            float4 v = *(const float4*)(in_w + (size_t)(2*INTER + row)*HIDDEN + kk);
            float e[4] = {v.x, v.y, v.z, v.w};
            us* hp = (us*)&h;
            us* lp = (us*)&l;
            #pragma unroll
            for (int u=0;u<4;u++){
                us hv = f2bf(e[u]);
                hp[u] = hv;
                lp[u] = f2bf(e[u] - bf2f(hv));
            }
        }
        *(ushort4*)(wbc_hi + i) = h;
        *(ushort4*)(wbc_lo + i) = l;
    }
}

// =============== MERGED: reduce_bc2 + conv_xt =======================================
__global__ __launch_bounds__(256) void mega_red_convxt(const float* __restrict__ part,
                                                       const float* __restrict__ dt_bias,
                                                       const us* __restrict__ projb,
                                                       const float* __restrict__ cw,
                                                       const float* __restrict__ cb,
                                                       float* __restrict__ outBC,
                                                       float* __restrict__ dtbuf,
                                                       us* __restrict__ XT) {
    __shared__ us raw[68][66];
    int bid = blockIdx.x;
    int tid = threadIdx.x;
    if (bid < RED_BLOCKS) {
        size_t i4 = (size_t)bid*256 + tid;
        size_t i = i4*4;
        float4 s = *(const float4*)(part + i);
        #pragma unroll
        for (int z=1; z<KSPL2; z++){
            float4 v = *(const float4*)(part + (size_t)z*TOK*NBCP + i);
            s.x += v.x; s.y += v.y; s.z += v.z; s.w += v.w;
        }
        int col = (int)(i % NBCP);
        int t   = (int)(i / NBCP);
        if (col < 256) {
            *(float4*)(outBC + (size_t)t*NBC + col) = s;
        } else if (col < NBC) {
            int h = col - 256;
            float e[4] = {s.x, s.y, s.z, s.w};
            #pragma unroll
            for (int u=0;u<4;u++){
                float xv = e[u] + dt_bias[h+u];
                float sp = (xv > 20.f) ? xv : log1pf(expf(xv));
                e[u] = fminf(fmaxf(sp, 0.f), 100.f);
            }
            float4 o; o.x=e[0]; o.y=e[1]; o.z=e[2]; o.w=e[3];
            *(float4*)(dtbuf + (size_t)t*NUM_HEADS + h) = o;
        }
    } else {
        int b3 = bid - RED_BLOCKS;
        int bx = b3 & 63, by = b3 >> 6;
        int t0 = bx * 64, d0 = by * 64;
        int b  = t0 / SEQ;
        int s0 = t0 % SEQ;
        for (int f = tid; f < 67*8; f += 256){
            int r = f >> 3, g = f & 7;
            int sp = s0 - 3 + r;
            uint4 v;
            if (sp >= 0) v = *(const uint4*)(projb + ((size_t)(b*SEQ+sp))*PROJ_PAD + INTER + d0 + g*8);
            else { v.x=0u; v.y=0u; v.z=0u; v.w=0u; }
            unsigned int* dst = (unsigned int*)&raw[r][g*8];
            dst[0]=v.x; dst[1]=v.y; dst[2]=v.z; dst[3]=v.w;
        }
        __syncthreads();
        int t = tid & 63, dg = tid >> 6;
        #pragma unroll
        for (int dd = 0; dd < 16; dd++){
            int d = dg*16 + dd;
            float acc = cb[d0+d];
            #pragma unroll
            for (int j=0;j<CONV_K;j++)
                acc += cw[(d0+d)*CONV_K+j] * bf2f(raw[t+j][d]);
            float val = acc/(1.f+expf(-acc));
            XT[((size_t)(b*INTER + d0 + d))*SEQ + s0 + t] = f2bf(val);
        }
    }
}

// =============== MERGED: conv_bc + cumsum + w2 cvt ==================================
__global__ __launch_bounds__(256) void mega_convbc_cum_w2(const float* __restrict__ projBC,
                                                          const float* __restrict__ cw,
                                                          const float* __restrict__ cb,
                                                          const float* __restrict__ dtbuf,
                                                          const float* __restrict__ A_log,
                                                          const float* __restrict__ out_w,
                                                          float* __restrict__ xBC_BC,
                                                          us* __restrict__ BT,
                                                          us* __restrict__ Cb,
                                                          float* __restrict__ A_cum,
                                                          us* __restrict__ w2b) {
    __shared__ float buf[CHUNK];
    int bid = blockIdx.x;
    int tid = threadIdx.x;
    if (bid < CBC_BLOCKS) {
        int idx = bid*256 + tid;
        int d = idx & 255;
        int t = idx >> 8;
        int b = t / SEQ, sl = t % SEQ;
        int dc = INTER + d;
        float acc = cb[dc];
        #pragma unroll
        for (int j=0;j<CONV_K;j++){
            int sp = sl - (CONV_K-1) + j;
            if (sp >= 0)
                acc += cw[dc*CONV_K+j] * projBC[((size_t)(b*SEQ+sp))*NBC + d];
        }
        float val = acc / (1.f + expf(-acc));
        xBC_BC[(size_t)t*256 + d] = val;
        if (d < 128)
            BT[((size_t)(b*128 + d))*SEQ + sl] = f2bf(val);
        else
            Cb[(size_t)t*128 + (d-128)] = f2bf(val);
    } else if (bid < CBC_BLOCKS + CUM_BLOCKS) {
        int b4 = bid - CBC_BLOCKS;
        int c = b4 & 7, h = (b4 >> 3) % 80, b = b4 / 640;
        int l = tid;
        float A = -expf(A_log[h]);
        float v = A * dtbuf[(size_t)(b*SEQ + c*CHUNK + l)*NUM_HEADS + h];
        buf[l] = v;
        __syncthreads();
        for (int off=1; off<CHUNK; off<<=1){
            float t2 = (l>=off) ? buf[l-off] : 0.f;
            __syncthreads();
            buf[l] += t2;
            __syncthreads();
        }
        A_cum[((size_t)b*NUM_HEADS + h)*SEQ + c*CHUNK + l] = buf[l];
    } else {
        size_t i4 = (size_t)(bid - CBC_BLOCKS - CUM_BLOCKS)*256 + tid;
        size_t i = i4*4;
        float4 v = *(const float4*)(out_w + i);
        ushort4 o; o.x=f2bf(v.x); o.y=f2bf(v.y); o.z=f2bf(v.z); o.w=f2bf(v.w);
        *(ushort4*)(w2b + i) = o;
    }
}

// =============== MERGED: states_mfma + g_kernel =====================================
__global__ __launch_bounds__(256) void mega_states_g(const us* __restrict__ XT,
                                                     const us* __restrict__ BT,
                                                     const float* __restrict__ dtbuf,
                                                     const float* __restrict__ A_cum,
                                                     const float* __restrict__ xBC_BC,
                                                     us* __restrict__ statesT,
                                                     us* __restrict__ G) {
    __shared__ __align__(16) char SH[33792];
    int bid = blockIdx.x;
    int tid = threadIdx.x;
    if (bid < ST_BLOCKS) {
        // ---- states ----
        int c = bid & 7, h = (bid >> 3) % 80, b = bid / 640;
        us (*Asx)[64] = (us(*)[64])SH;               // 8KB
        us (*Bs)[64]  = (us(*)[64])(SH + 8192);      // 16KB
        float* wl     = (float*)(SH + 24576);        // 1KB
        int lane = tid & 63, wid = tid >> 6;
        {
            const float* ac = A_cum + ((size_t)(b*NUM_HEADS+h))*SEQ + c*CHUNK;
            float Alast = ac[CHUNK-1];
            wl[tid] = expf(Alast - ac[tid]) * dtbuf[((size_t)(b*SEQ + c*CHUNK + tid))*NUM_HEADS + h];
        }
        __syncthreads();
        f32x4 acc[4][2];
        #pragma unroll
        for (int i=0;i<4;i++)
            #pragma unroll
            for (int j=0;j<2;j++) acc[i][j] = (f32x4){0.f,0.f,0.f,0.f};

        for (int kc = 0; kc < 4; kc++){
            int lbase = kc*64;
            #pragma unroll
            for (int q=0;q<4;q++){
                int brow = (wid*4+q)*8;
                int row  = brow + (lane>>3);
                int sl   = (lane&7) ^ (row & 7);
                gld16(BT + ((size_t)(b*128 + row))*SEQ + c*CHUNK + lbase + sl*8, &Bs[brow][0]);
            }
            #pragma unroll
            for (int it=0; it<2; it++){
                int f = tid + it*256;
                int r = f >> 3, g = f & 7;
                uint4 v = *(const uint4*)(XT + ((size_t)(b*INTER + h*HEAD_DIM + r))*SEQ + c*CHUNK + lbase + g*8);
                float e[8]; unpack8(v, e);
                us o[8];
                #pragma unroll
                for (int u=0;u<8;u++) o[u] = f2bf(e[u] * wl[lbase + g*8 + u]);
                int slot = g ^ (r & 7);
                *(ushort4*)&Asx[r][slot*8]   = *(ushort4*)&o[0];
                *(ushort4*)&Asx[r][slot*8+4] = *(ushort4*)&o[4];
            }
            __syncthreads();
            #pragma unroll
            for (int kk=0; kk<64; kk+=32){
                bf16x8 a[4], bb[2];
                #pragma unroll
                for (int i=0;i<4;i++){
                    int row = i*16 + (lane&15);
                    int slot = ((kk>>3)+(lane>>4)) ^ (row&7);
                    a[i] = *(const bf16x8*)&Asx[row][slot*8];
                }
                #pragma unroll
                for (int j=0;j<2;j++){
                    int row = wid*32 + j*16 + (lane&15);
                    int slot = ((kk>>3)+(lane>>4)) ^ (row&7);
                    bb[j] = *(const bf16x8*)&Bs[row][slot*8];
                }
                #pragma unroll
                for (int i=0;i<4;i++)
                    #pragma unroll
                    for (int j=0;j<2;j++)
                        acc[i][j] = MFMA16(a[i], bb[j], acc[i][j]);
            }
            __syncthreads();
        }
        size_t sb = ((size_t)((b*NC + c)*NUM_HEADS + h))*(HEAD_DIM*STATE);
        #pragma unroll
        for (int i=0;i<4;i++){
            #pragma unroll
            for (int j=0;j<2;j++){
                int n = wid*32 + j*16 + (lane&15);
                int p0 = i*16 + (lane>>4)*4;
                #pragma unroll
                for (int r=0;r<4;r++)
                    statesT[sb + (size_t)(p0+r)*128 + n] = f2bf(acc[i][j][r]);
            }
        }
    } else {
        // ---- g: G[l][s] = C[l].B[s], 32x32 tiles ----
        int b5 = bid - ST_BLOCKS;
        int c = b5 & 7, p = (b5 >> 3) % 36, b = b5 / 288;
        int lt = 0, a0 = 0;
        while (a0 + lt + 1 <= p) { a0 += lt + 1; lt++; }
        int st = p - a0;
        int l0 = lt*32, s0 = st*32;
        float (*Cs)[132] = (float(*)[132])SH;
        float (*Bs2)[132] = (float(*)[132])(SH + 16896);
        int ty = tid >> 4, tx = tid & 15;
        float acc[2][2];
        acc[0][0]=0.f; acc[0][1]=0.f; acc[1][0]=0.f; acc[1][1]=0.f;

        size_t rowC = ((size_t)(b*SEQ + c*CHUNK + l0))*256 + 128;
        size_t rowB = ((size_t)(b*SEQ + c*CHUNK + s0))*256;
        #pragma unroll
        for (int it=0; it<4; it++){
            int f = tid + it*256;
            int r = f >> 5, c4 = f & 31;
            *(float4*)&Cs[r][c4*4]  = *(const float4*)(xBC_BC + rowC + (size_t)r*256 + c4*4);
            *(float4*)&Bs2[r][c4*4] = *(const float4*)(xBC_BC + rowB + (size_t)r*256 + c4*4);
        }
        __syncthreads();
        #pragma unroll 8
        for (int k=0;k<128;k++){
            float a0v = Cs[ty*2][k],   a1v = Cs[ty*2+1][k];
            float b0v = Bs2[tx*2][k],  b1v = Bs2[tx*2+1][k];
            acc[0][0] += a0v*b0v; acc[0][1] += a0v*b1v;
            acc[1][0] += a1v*b0v; acc[1][1] += a1v*b1v;
        }
        size_t Gb = ((size_t)(b*NC + c)) << 16;
        #pragma unroll
        for (int i=0;i<2;i++){
            ushort2 g2;
            g2.x = f2bf(acc[i][0]); g2.y = f2bf(acc[i][1]);
            *(ushort2*)(G + Gb + (size_t)(l0 + ty*2 + i)*256 + s0 + tx*2) = g2;
        }
    }
}

// ---------------- inter-chunk recurrence (in place, bf16, 4-way split) --------------
__global__ __launch_bounds__(256) void recur_kernel(const float* __restrict__ A_cum,
                                                    us* __restrict__ states) {
    int h = blockIdx.x, b = blockIdx.y, z = blockIdx.z;
    int tid = threadIdx.x;
    float Srun[8];
    #pragma unroll
    for (int i=0;i<8;i++) Srun[i]=0.f;
    const float* acum = A_cum + ((size_t)b*NUM_HEADS + h)*SEQ;
    for (int c=0;c<NC;c++){
        float alast = acum[c*CHUNK + CHUNK-1];
        float dec = expf(alast);
        size_t base = ((size_t)((b*NC + c)*NUM_HEADS + h))*(HEAD_DIM*STATE);
        #pragma unroll
        for (int i=0;i<8;i++){
            size_t idx = base + (size_t)tid + (size_t)(z*8+i)*256;
            float raw = bf2f(states[idx]);
            states[idx] = f2bf(Srun[i]);
            Srun[i] = Srun[i]*dec + raw;
        }
    }
}

// ---------------- Y = e_l*(Cs @ St^T) + Gw @ Xs^T + D*X   (MFMA) --------------------
__global__ __launch_bounds__(256) void yscan_mfma(const us* __restrict__ G,
                                                  const us* __restrict__ Cb,
                                                  const us* __restrict__ XT,
                                                  const float* __restrict__ dtbuf,
                                                  const float* __restrict__ A_cum,
                                                  const us* __restrict__ statesT,
                                                  const float* __restrict__ Dvec,
                                                  us* __restrict__ projb) {
    int xb = blockIdx.x;
    int c = xb & 7, lt = xb >> 3;
    int h = blockIdx.y, b = blockIdx.z;
    int l0 = lt*64;
    __shared__ __align__(16) char pool[32768];
    us (*Cs)[128] = (us(*)[128])pool;
    us (*St)[128] = (us(*)[128])(pool + 16384);
    us (*Gw)[64]  = (us(*)[64])pool;
    us (*Xs)[64]  = (us(*)[64])(pool + 8192);
    float (*Ot)[68] = (float(*)[68])pool;
    __shared__ float ac[CHUNK], dts[CHUNK];
    int tid = threadIdx.x, lane = tid & 63, wid = tid >> 6;
    ac[tid]  = A_cum[((size_t)(b*NUM_HEADS + h))*SEQ + c*CHUNK + tid];
    dts[tid] = dtbuf[((size_t)(b*SEQ + c*CHUNK + tid))*NUM_HEADS + h];

    size_t stb = ((size_t)((b*NC + c)*NUM_HEADS + h))*(HEAD_DIM*STATE);
    #pragma unroll
    for (int q=0;q<4;q++){
        int brow = (wid*4+q)*4;
        int row  = brow + (lane>>4);
        int sl   = (lane&15) ^ (row & 7);
        gld16(Cb + ((size_t)(b*SEQ + c*CHUNK + l0 + row))*128 + sl*8, &Cs[brow][0]);
        gld16(statesT + stb + (size_t)row*128 + sl*8, &St[brow][0]);
    }
    __syncthreads();

    f32x4 acc1[4];
    #pragma unroll
    for (int j=0;j<4;j++) acc1[j] = (f32x4){0.f,0.f,0.f,0.f};
    #pragma unroll
    for (int kk=0; kk<128; kk+=32){
        int arow = wid*16 + (lane&15);
        int aslot = ((kk>>3)+(lane>>4)) ^ (arow&7);
        bf16x8 a = *(const bf16x8*)&Cs[arow][aslot*8];
        #pragma unroll
        for (int j=0;j<4;j++){
            int brow = j*16 + (lane&15);
            int bslot = ((kk>>3)+(lane>>4)) ^ (brow&7);
            bf16x8 bb = *(const bf16x8*)&St[brow][bslot*8];
            acc1[j] = MFMA16(a, bb, acc1[j]);
        }
    }
    float el[4];
    #pragma unroll
    for (int r=0;r<4;r++) el[r] = expf(ac[l0 + wid*16 + (lane>>4)*4 + r]);
    float master[4][4];
    #pragma unroll
    for (int j=0;j<4;j++)
        #pragma unroll
        for (int r=0;r<4;r++) master[j][r] = acc1[j][r]*el[r];
    __syncthreads();

    size_t Gb = ((size_t)(b*NC + c)) << 16;
    f32x4 acc2[4];
    #pragma unroll
    for (int j=0;j<4;j++) acc2[j] = (f32x4){0.f,0.f,0.f,0.f};
    for (int st=0; st<=lt; st++){
        int s0 = st*64;
        #pragma unroll
        for (int it=0; it<2; it++){
            int f = tid + it*256;
            int r = f >> 3, g = f & 7;
            uint4 v = *(const uint4*)(G + Gb + (size_t)(l0 + r)*256 + s0 + g*8);
            float e[8]; unpack8(v, e);
            float acl = ac[l0 + r];
            us o[8];
            #pragma unroll
            for (int u=0;u<8;u++){
                int s = s0 + g*8 + u;
                float w = (s <= l0 + r) ? expf(acl - ac[s])*dts[s] : 0.f;
                o[u] = f2bf(e[u]*w);
            }
            int slot = g ^ (r&7);
            *(ushort4*)&Gw[r][slot*8]   = *(ushort4*)&o[0];
            *(ushort4*)&Gw[r][slot*8+4] = *(ushort4*)&o[4];
        }
        #pragma unroll
        for (int q=0;q<2;q++){
            int brow = (wid*2+q)*8;
            int row  = brow + (lane>>3);
            int sl   = (lane&7) ^ (row&7);
            gld16(XT + ((size_t)(b*INTER + h*HEAD_DIM + row))*SEQ + c*CHUNK + s0 + sl*8,
                  &Xs[brow][0]);
        }
        __syncthreads();
        #pragma unroll
        for (int kk=0; kk<64; kk+=32){
            int arow = wid*16 + (lane&15);
            int aslot = ((kk>>3)+(lane>>4)) ^ (arow&7);
            bf16x8 a = *(const bf16x8*)&Gw[arow][aslot*8];
            #pragma unroll
            for (int j=0;j<4;j++){
                int brow = j*16 + (lane&15);
                int bslot = ((kk>>3)+(lane>>4)) ^ (brow&7);
                bf16x8 bb = *(const bf16x8*)&Xs[brow][bslot*8];
                acc2[j] = MFMA16(a, bb, acc2[j]);
            }
        }
        if (st < lt) __syncthreads();
    }

    float Dh = Dvec[h];
    #pragma unroll
    for (int j=0;j<4;j++){
        int p = j*16 + (lane&15);
        #pragma unroll
        for (int r=0;r<4;r++){
            int sl_ = wid*16 + (lane>>4)*4 + r;
            int slot = (sl_>>3) ^ (p&7);
            float xv = bf2f(Xs[p][slot*8 + (sl_&7)]);
            master[j][r] += acc2[j][r] + Dh*xv;
        }
    }
    __syncthreads();

    #pragma unroll
    for (int j=0;j<4;j++){
        int p = j*16 + (lane&15);
        #pragma unroll
        for (int r=0;r<4;r++)
            Ot[wid*16 + (lane>>4)*4 + r][p] = master[j][r];
    }
    __syncthreads();
    #pragma unroll
    for (int it=0; it<4; it++){
        int f = tid + it*256;
        int r = f >> 4, c4 = f & 15;
        ushort4 o;
        o.x = f2bf(Ot[r][c4*4+0]); o.y = f2bf(Ot[r][c4*4+1]);
        o.z = f2bf(Ot[r][c4*4+2]); o.w = f2bf(Ot[r][c4*4+3]);
        *(ushort4*)(projb + ((size_t)(b*SEQ + c*CHUNK + l0 + r))*PROJ_PAD + INTER + h*HEAD_DIM + c4*4) = o;
    }
}

// ---------------- gate * silu + RMSNorm -> packed bf16 y ----------------------------
__global__ __launch_bounds__(256) void gate_norm_kernel(const us* __restrict__ projb,
                                                        const float* __restrict__ normw,
                                                        us* __restrict__ yb) {
    int t = blockIdx.x;
    int tid = threadIdx.x;
    const us* row = projb + (size_t)t*PROJ_PAD;
    __shared__ float red[4];
    float vals[20];
    float ss = 0.f;
    #pragma unroll
    for (int i=0;i<5;i++){
        int j = (tid + i*256)*4;
        ushort4 g4 = *(const ushort4*)(row + j);
        ushort4 y4 = *(const ushort4*)(row + INTER + j);
        #pragma unroll
        for (int u=0;u<4;u++){
            float g = bf2f(((const us*)&g4)[u]);
            float y = bf2f(((const us*)&y4)[u]);
            float gv = g / (1.f + expf(-g));
            float v = y * gv;
            vals[i*4+u] = v;
            ss += v*v;
        }
    }
    #pragma unroll
    for (int off=32; off; off>>=1) ss += __shfl_xor(ss, off);
    if ((tid&63)==0) red[tid>>6] = ss;
    __syncthreads();
    float tot = red[0]+red[1]+red[2]+red[3];
    float inv = rsqrtf(tot/(float)INTER + EPS);
    #pragma unroll
    for (int i=0;i<5;i++){
        int j = (tid + i*256)*4;
        ushort4 o;
        o.x = f2bf(vals[i*4+0] * inv * normw[j+0]);
        o.y = f2bf(vals[i*4+1] * inv * normw[j+1]);
        o.z = f2bf(vals[i*4+2] * inv * normw[j+2]);
        o.w = f2bf(vals[i*4+3] * inv * normw[j+3]);
        *(ushort4*)(yb + (size_t)t*INTER + j) = o;
    }
}

// ------------------------------------------------------------------------------------
extern "C" void kernel_launch(void* const* d_in, const int* in_sizes, int n_in,
                              void* d_out, int out_size, void* d_ws, size_t ws_size,
                              hipStream_t stream) {
    const float* x        = (const float*)d_in[0];
    const float* in_w     = (const float*)d_in[1];
    const float* conv_w   = (const float*)d_in[2];
    const float* conv_b   = (const float*)d_in[3];
    const float* A_log    = (const float*)d_in[4];
    const float* Dvec     = (const float*)d_in[5];
    const float* dt_bias  = (const float*)d_in[6];
    const float* norm_w   = (const float*)d_in[7];
    const float* out_w    = (const float*)d_in[8];
    float* out = (float*)d_out;
    (void)ws_size; (void)n_in; (void)in_sizes; (void)out_size;

    const size_t PROJB   = (size_t)TOK*PROJ_PAD*2;
    const size_t PROJBCB = (size_t)TOK*NBC*4;
    const size_t XTB     = (size_t)TOK*INTER*2;
    const size_t XBCBCB  = (size_t)TOK*256*4;
    const size_t BTB     = (size_t)BATCH*128*SEQ*2;
    const size_t CBB     = (size_t)TOK*128*2;
    const size_t GBYTES  = (size_t)BATCH*NC*CHUNK*CHUNK*2;
    const size_t DTB     = (size_t)TOK*NUM_HEADS*4;
    const size_t ACUMB   = DTB;
    const size_t STB     = (size_t)BATCH*NC*NUM_HEADS*HEAD_DIM*STATE*2;
    const size_t XHB   = (size_t)TOK*HIDDEN*2;
    const size_t WBCB  = (size_t)NBCP*HIDDEN*2;
    const size_t YBB   = (size_t)TOK*INTER*2;

    char* base = (char*)d_ws;
    size_t off = 0;
    us* projb  = (us*)(base + off); off += PROJB;
    float* projBC = (float*)(base + off); off += PROJBCB;
    us* XTp    = (us*)(base + off); off += XTB;
    float* xBC_BC = (float*)(base + off); off += XBCBCB;
    us* BTp    = (us*)(base + off); off += BTB;
    us* Cbp    = (us*)(base + off); off += CBB;
    us* Gp     = (us*)(base + off); off += GBYTES;
    float* dtbuf = (float*)(base + off); off += DTB;
    float* A_cum = (float*)(base + off); off += ACUMB;
    us* statesT = (us*)(base + off); off += STB;
    char*  T   = base + off;
    us* xhi    = (us*)T;
    us* xlo    = (us*)(T + XHB);
    us* wbc_hi = (us*)(T + 2*XHB);
    us* wbc_lo = (us*)(T + 2*XHB + WBCB);
    us* w1b    = (us*)(T + 2*XHB + 2*WBCB);
    float* bcpart = (float*)w1b;
    us* yb     = (us*)T;
    us* w2b    = (us*)(T + YBB);

    // 1. fused prep
    {
        unsigned total_blocks = (unsigned)((N4A + N4B + N4C) / 256);
        prep_kernel<<<total_blocks, 256, 0, stream>>>(x, in_w, xhi, xlo, w1b, wbc_hi, wbc_lo);
    }
    // 2. GEMM1 + bc split-K (merged; bc fills GEMM1's dispatch tail)
    mega_gemm1_bc<<<G1_BLOCKS + BC_BLOCKS, 256, 0, stream>>>(xhi, xlo, w1b, wbc_hi, wbc_lo,
                                                             projb, bcpart);
    // 3. reduce + conv_xt (merged)
    mega_red_convxt<<<RED_BLOCKS + CXT_BLOCKS, 256, 0, stream>>>(bcpart, dt_bias, projb,
                                                                 conv_w, conv_b,
                                                                 projBC, dtbuf, XTp);
    // 4. conv_bc + cumsum + w2 cvt (merged; bcpart dead -> w2b safe)
    mega_convbc_cum_w2<<<CBC_BLOCKS + CUM_BLOCKS + W2_BLOCKS, 256, 0, stream>>>(
        projBC, conv_w, conv_b, dtbuf, A_log, out_w, xBC_BC, BTp, Cbp, A_cum, w2b);
    // 5. states + g (merged)
    mega_states_g<<<ST_BLOCKS + GK_BLOCKS, 256, 0, stream>>>(XTp, BTp, dtbuf, A_cum, xBC_BC,
                                                             statesT, Gp);
    // 6. inter-chunk recurrence
    recur_kernel<<<dim3(NUM_HEADS, BATCH, 4), 256, 0, stream>>>(A_cum, statesT);
    // 7. Y (MFMA)
    yscan_mfma<<<dim3(NC*4, NUM_HEADS, BATCH), 256, 0, stream>>>(Gp, Cbp, XTp, dtbuf, A_cum,
                                                                 statesT, Dvec, projb);
    // 8. gate + RMSNorm
    gate_norm_kernel<<<TOK, 256, 0, stream>>>(projb, norm_w, yb);
    // 9. out = y @ out_w^T
    gemm_bf16<false><<<dim3(HIDDEN/128, TOK/128), 256, 0, stream>>>(yb, INTER, w2b, INTER,
                                                                    out, HIDDEN, INTER);
}